// Round 7
// baseline (474.351 us; speedup 1.0000x reference)
//
#include <hip/hip_runtime.h>
#include <hip/hip_cooperative_groups.h>
#include <hip/hip_bf16.h>
#include <math.h>

namespace cg = cooperative_groups;

// Problem constants
#define B_DIM 2
#define L_SEQ 2048
#define D_DIM 256
#define N_DIM 64
#define K_CONV 4
#define M_ROWS (B_DIM * L_SEQ)   // 4096
#define NC 128                    // number of scan chunks
#define CL (L_SEQ / NC)           // 16 steps per chunk
#define GRID_BLOCKS 512

typedef __attribute__((ext_vector_type(8))) short bf16x8;
typedef __attribute__((ext_vector_type(4))) float f32x4;
typedef unsigned short ushort_t;

static __device__ __forceinline__ unsigned short f2bf(float f) {
  unsigned int u = __float_as_uint(f);
  unsigned int r = u + 0x7FFF + ((u >> 16) & 1);   // round-to-nearest-even
  return (unsigned short)(r >> 16);
}
static __device__ __forceinline__ float bf2f(ushort_t s) {
  return __uint_as_float(((unsigned int)s) << 16);
}

struct MegaParams {
  const float *x, *W_in, *conv_w, *conv_b, *W_bc, *b_bc, *W_lam, *b_lam, *A, *W_out;
  float *out;
  float *ws;
};

// ---- 64x64 MFMA GEMM core: acc[2][2] over A[bm:bm+64, :K] @ W[bn-rows]^T --
static __device__ __forceinline__ void gemm64_core(
    const ushort_t* __restrict__ Ag, const ushort_t* __restrict__ Wg,
    int K, int bm, unsigned char* smem, f32x4 acc[2][2], int tid) {
  ushort_t (*As)[72] = (ushort_t(*)[72])smem;              // 64x72 shorts
  ushort_t (*Ws)[72] = (ushort_t(*)[72])(smem + 9216);     // 64x72 shorts
  const int lane = tid & 63;
  const int w = tid >> 6;
  const int wm = w >> 1;
  const int wn = w & 1;
  const int r0 = tid >> 3;         // 0..31
  const int c8 = (tid & 7) * 8;
  const int row16 = lane & 15;
  #pragma unroll
  for (int i = 0; i < 2; ++i)
    #pragma unroll
    for (int j = 0; j < 2; ++j)
      acc[i][j] = (f32x4){0.f, 0.f, 0.f, 0.f};
  for (int k0 = 0; k0 < K; k0 += 64) {
    #pragma unroll
    for (int p = 0; p < 2; ++p) {
      int r = r0 + p * 32;
      *reinterpret_cast<uint4*>(&As[r][c8]) =
          *reinterpret_cast<const uint4*>(&Ag[(size_t)(bm + r) * K + k0 + c8]);
      *reinterpret_cast<uint4*>(&Ws[r][c8]) =
          *reinterpret_cast<const uint4*>(&Wg[(size_t)r * K + k0 + c8]);
    }
    __syncthreads();
    #pragma unroll
    for (int ks = 0; ks < 2; ++ks) {
      const int ko = ks * 32 + (lane >> 4) * 8;
      bf16x8 af[2], bfr[2];
      #pragma unroll
      for (int i = 0; i < 2; ++i)
        af[i] = *reinterpret_cast<const bf16x8*>(&As[wm * 32 + i * 16 + row16][ko]);
      #pragma unroll
      for (int j = 0; j < 2; ++j)
        bfr[j] = *reinterpret_cast<const bf16x8*>(&Ws[wn * 32 + j * 16 + row16][ko]);
      #pragma unroll
      for (int i = 0; i < 2; ++i)
        #pragma unroll
        for (int j = 0; j < 2; ++j)
          acc[i][j] = __builtin_amdgcn_mfma_f32_16x16x32_bf16(af[i], bfr[j], acc[i][j], 0, 0, 0);
    }
    __syncthreads();
  }
}

// ---- passA single unit (b, c, dq) ----------------------------------------
static __device__ __forceinline__ void passA_unit(
    int b, int c, int dq, int tid,
    const float* __restrict__ lamb, const float* __restrict__ uwb,
    const float* __restrict__ bcb, float* __restrict__ Pc,
    ushort_t* __restrict__ Hc, float* __restrict__ ybuf,
    unsigned char* smem) {
  float (*bcs)[128] = (float(*)[128])smem;                 // 8 KB
  float (*lam_s)[64] = (float(*)[64])(smem + 8192);        // 4 KB
  float (*uw_s)[64] = (float(*)[64])(smem + 12288);        // 4 KB
  float (*ypar)[4][64] = (float(*)[4][64])(smem + 16384);  // 16 KB
  const int lane = tid & 63;
  const int ng = tid >> 6;
  const int dd = dq * 64 + lane;
  {
    const float4* src = reinterpret_cast<const float4*>(
        bcb + (size_t)(b * L_SEQ + c * CL) * 128);
    float4* dst = reinterpret_cast<float4*>(&bcs[0][0]);
    dst[tid] = src[tid];
    dst[tid + 256] = src[tid + 256];
    const int ts = tid >> 4, qs = tid & 15;
    size_t rowb = (size_t)(b * L_SEQ + c * CL + ts) * 256 + dq * 64 + qs * 4;
    *reinterpret_cast<float4*>(&lam_s[ts][qs * 4]) =
        *reinterpret_cast<const float4*>(&lamb[rowb]);
    *reinterpret_cast<float4*>(&uw_s[ts][qs * 4]) =
        *reinterpret_cast<const float4*>(&uwb[rowb]);
  }
  __syncthreads();
  float H[16];
  #pragma unroll
  for (int j = 0; j < 16; ++j) H[j] = 0.f;
  float P = 1.f;
  const size_t base0 = (size_t)(b * L_SEQ + c * CL) * 256 + dd;
  #pragma unroll 4
  for (int t = 0; t < CL; ++t) {
    float lam = lam_s[t][lane];
    float uw = uw_s[t][lane];
    P *= lam;
    float yp = 0.f;
    const float* bt = &bcs[t][ng * 16];
    const float* ct = &bcs[t][64 + ng * 16];
    #pragma unroll
    for (int j = 0; j < 16; ++j) {
      H[j] = lam * H[j] + bt[j] * uw;
      yp += ct[j] * H[j];
    }
    ypar[t][ng][lane] = yp;
  }
  if (ng == 0) Pc[(size_t)(b * NC + c) * 256 + dd] = P;
  #pragma unroll
  for (int j = 0; j < 16; ++j)
    Hc[((size_t)(b * NC + c) * 64 + ng * 16 + j) * 256 + dd] = f2bf(H[j]);
  __syncthreads();
  #pragma unroll
  for (int tt = 0; tt < 4; ++tt) {
    int t = ng * 4 + tt;
    float y = ypar[t][0][lane] + ypar[t][1][lane] +
              ypar[t][2][lane] + ypar[t][3][lane];
    ybuf[base0 + (size_t)t * 256] = y;
  }
  __syncthreads();
}

// ---- passB single unit (b, c, dq) ----------------------------------------
static __device__ __forceinline__ void passB_unit(
    int b, int c, int dq, int tid,
    const float* __restrict__ lamb, const float* __restrict__ bcb,
    const ushort_t* __restrict__ hin, const float* __restrict__ proj,
    const float* __restrict__ ybuf, ushort_t* __restrict__ gbf,
    unsigned char* smem) {
  float (*cs)[64] = (float(*)[64])smem;                    // 4 KB
  float (*lam_s)[64] = (float(*)[64])(smem + 4096);        // 4 KB
  float (*spar)[4][64] = (float(*)[4][64])(smem + 8192);   // 16 KB
  const int lane = tid & 63;
  const int ng = tid >> 6;
  const int dd = dq * 64 + lane;
  {
    int t0 = tid >> 4;
    int jq = tid & 15;
    *reinterpret_cast<float4*>(&cs[t0][jq * 4]) =
        *reinterpret_cast<const float4*>(
            bcb + (size_t)(b * L_SEQ + c * CL + t0) * 128 + 64 + jq * 4);
    size_t rowb = (size_t)(b * L_SEQ + c * CL + t0) * 256 + dq * 64 + jq * 4;
    *reinterpret_cast<float4*>(&lam_s[t0][jq * 4]) =
        *reinterpret_cast<const float4*>(&lamb[rowb]);
  }
  float h16[16];
  #pragma unroll
  for (int j = 0; j < 16; ++j)
    h16[j] = bf2f(hin[((size_t)(b * NC + c) * 64 + ng * 16 + j) * 256 + dd]);
  __syncthreads();
  const size_t base0 = (size_t)(b * L_SEQ + c * CL) * 256 + dd;
  const size_t pbase0 = (size_t)(b * L_SEQ + c * CL) * 512 + dd;
  #pragma unroll 4
  for (int t = 0; t < CL; ++t) {
    float S = 0.f;
    const float* ct = &cs[t][ng * 16];
    #pragma unroll
    for (int j = 0; j < 16; ++j) S += ct[j] * h16[j];
    spar[t][ng][lane] = S;
  }
  __syncthreads();
  float Pp = 1.f;
  #pragma unroll
  for (int tau = 0; tau < 12; ++tau)
    if (tau < ng * 4) Pp *= lam_s[tau][lane];
  #pragma unroll
  for (int tt = 0; tt < 4; ++tt) {
    int t = ng * 4 + tt;
    Pp *= lam_s[t][lane];
    float S4 = spar[t][0][lane] + spar[t][1][lane] +
               spar[t][2][lane] + spar[t][3][lane];
    float y = ybuf[base0 + (size_t)t * 256] + Pp * S4;
    float sk = proj[pbase0 + (size_t)t * 512];
    float g = 0.5f * sk * (1.f + erff(sk * 0.70710678118f));
    gbf[base0 + (size_t)t * 256] = f2bf(g * y);
  }
  __syncthreads();
}

// =================== the cooperative mega-kernel ===========================
__global__ __launch_bounds__(256, 2) void mega_kernel(MegaParams p) {
  __shared__ __align__(16) unsigned char smem[32768];
  cg::grid_group grid = cg::this_grid();
  const int bid = blockIdx.x;
  const int tid = threadIdx.x;

  float* ws = p.ws;
  float* proj = ws;                        // 2,097,152
  float* ubuf = ws + 2097152;              // 1,048,576
  float* lamb = ws + 3145728;              // 1,048,576
  float* uwb  = ws + 4194304;              // 1,048,576
  float* bcb  = ws + 5242880;              //   524,288
  float* ybuf = ws + 5767168;              // 1,048,576
  float* Pc   = ws + 6815744;              //    65,536
  ushort_t* Hc = (ushort_t*)(ws + 6881280);// 4,194,304 shorts (bf16)
  ushort_t* xbf  = (ushort_t*)(ws + 11075584);
  ushort_t* wib  = (ushort_t*)(ws + 11599872);
  ushort_t* wbcb = (ushort_t*)(ws + 11665408);
  ushort_t* wlb  = (ushort_t*)(ws + 11681792);
  ushort_t* wob  = (ushort_t*)(ws + 11714560);
  ushort_t* ubf  = (ushort_t*)(ws + 11747328);
  ushort_t* gbf  = (ushort_t*)(ws + 12271616);

  // ---------------- P0: f32 -> bf16 conversions ----------------
  for (int vb = bid; vb < 1312; vb += GRID_BLOCKS) {
    const float* src; ushort_t* dst; int off;
    if (vb < 1024)      { src = p.x;     dst = xbf;  off = vb; }
    else if (vb < 1152) { src = p.W_in;  dst = wib;  off = vb - 1024; }
    else if (vb < 1184) { src = p.W_bc;  dst = wbcb; off = vb - 1152; }
    else if (vb < 1248) { src = p.W_lam; dst = wlb;  off = vb - 1184; }
    else                { src = p.W_out; dst = wob;  off = vb - 1248; }
    size_t i = (size_t)off * 1024 + tid * 4;
    float4 v = *reinterpret_cast<const float4*>(&src[i]);
    ushort4 o;
    o.x = f2bf(v.x); o.y = f2bf(v.y); o.z = f2bf(v.z); o.w = f2bf(v.w);
    *reinterpret_cast<ushort4*>(&dst[i]) = o;
  }
  grid.sync();

  // ---------------- P1: proj = x @ W_in^T (512 tiles, 1:1) ----------------
  {
    const int tm = bid & 63;
    const int tn = bid >> 6;          // 0..7
    const int bm = tm * 64, bn = tn * 64;
    f32x4 acc[2][2];
    gemm64_core(xbf, wib + (size_t)bn * 256, 256, bm, smem, acc, tid);
    const int lane = tid & 63;
    const int w = tid >> 6, wm = w >> 1, wn = w & 1;
    const int cl = lane & 15, rg = lane >> 4;
    #pragma unroll
    for (int j = 0; j < 2; ++j) {
      const int col = bn + wn * 32 + j * 16 + cl;
      #pragma unroll
      for (int i = 0; i < 2; ++i) {
        const int rbase = bm + wm * 32 + i * 16 + rg * 4;
        #pragma unroll
        for (int r = 0; r < 4; ++r)
          proj[(size_t)(rbase + r) * 512 + col] = acc[i][j][r];
      }
    }
  }
  grid.sync();

  // ---------------- P2: depthwise causal conv (512 blocks, 1:1) -----------
  {
    float (*pst)[256] = (float(*)[256])smem;   // 11 rows x 256
    const int m0 = bid * 8;
    for (int i = tid; i < 704; i += 256) {
      int row = i >> 6;
      int q = i & 63;
      int gm = m0 - 3 + row;
      float4 v = {0.f, 0.f, 0.f, 0.f};
      if (gm >= 0 && (gm >> 11) == (m0 >> 11))
        v = *reinterpret_cast<const float4*>(&proj[(size_t)gm * 512 + 256 + q * 4]);
      *reinterpret_cast<float4*>(&pst[row][q * 4]) = v;
    }
    __syncthreads();
    const int d = tid;
    const float4 w4 = *reinterpret_cast<const float4*>(&p.conv_w[d * 4]);
    const float bias = p.conv_b[d];
    #pragma unroll
    for (int r = 0; r < 8; ++r) {
      float acc = bias + w4.x * pst[r][d] + w4.y * pst[r + 1][d] +
                  w4.z * pst[r + 2][d] + w4.w * pst[r + 3][d];
      size_t idx = (size_t)(m0 + r) * 256 + d;
      ubuf[idx] = acc;
      ubf[idx] = f2bf(acc);
    }
    __syncthreads();
  }
  grid.sync();

  // ---------------- P3: fused bc | lambda GEMM (384 tiles) ----------------
  if (bid < 384) {
    const int tm = bid & 63;
    const int tn = bid >> 6;          // 0..5
    const int bm = tm * 64, bn = tn * 64;
    const ushort_t* Wsrc = (bn < 128) ? (wbcb + (size_t)bn * 256)
                                      : (wlb + (size_t)(bn - 128) * 256);
    f32x4 acc[2][2];
    gemm64_core(ubf, Wsrc, 256, bm, smem, acc, tid);
    const int lane = tid & 63;
    const int w = tid >> 6, wm = w >> 1, wn = w & 1;
    const int cl = lane & 15, rg = lane >> 4;
    #pragma unroll
    for (int j = 0; j < 2; ++j) {
      const int col = bn + wn * 32 + j * 16 + cl;
      if (col < 128) {
        const float bv = p.b_bc[col];
        #pragma unroll
        for (int i = 0; i < 2; ++i) {
          const int rbase = bm + wm * 32 + i * 16 + rg * 4;
          #pragma unroll
          for (int r = 0; r < 4; ++r)
            bcb[(size_t)(rbase + r) * 128 + col] = acc[i][j][r] + bv;
        }
      } else {
        const int dd = col - 128;
        const float bv = p.b_lam[dd];
        const float adg = -8.f * log1pf(__expf(p.A[dd]));
        #pragma unroll
        for (int i = 0; i < 2; ++i) {
          const int rbase = bm + wm * 32 + i * 16 + rg * 4;
          #pragma unroll
          for (int r = 0; r < 4; ++r) {
            const int row = rbase + r;
            float v = acc[i][j][r] + bv;
            float s = 1.f / (1.f + __expf(-v));
            float lam = __expf(s * adg);
            float wq = sqrtf(1.f + 1e-6f - lam * lam);
            float u = ubuf[(size_t)row * 256 + dd];
            lamb[(size_t)row * 256 + dd] = lam;
            uwb[(size_t)row * 256 + dd] = u * wq;
          }
        }
      }
    }
  }
  grid.sync();

  // ---------------- P4: chunk-local scan (1024 units, 2/block) ------------
  for (int u = bid; u < B_DIM * NC * 4; u += GRID_BLOCKS) {
    const int dq = u & 3;
    const int c = (u >> 2) & (NC - 1);
    const int b = u >> 9;
    passA_unit(b, c, dq, tid, lamb, uwb, bcb, Pc, Hc, ybuf, smem);
  }
  grid.sync();

  // ---------------- P5: chunk-prefix scan (blocks 0..127) -----------------
  if (bid < 128) {
    int tg = bid * 256 + tid;       // 32768 = B*N*D
    int d = tg & 255;
    int j = (tg >> 8) & 63;
    int b = tg >> 14;
    const size_t hstride = (size_t)N_DIM * 256;
    const size_t ihb = ((size_t)(b * NC) * 64 + j) * 256 + d;
    const size_t ipb = (size_t)(b * NC) * 256 + d;
    float h = 0.f;
    float Hv[16], Pv[16];
    #pragma unroll
    for (int q = 0; q < 16; ++q) {
      Hv[q] = bf2f(Hc[ihb + (size_t)q * hstride]);
      Pv[q] = Pc[ipb + (size_t)q * 256];
    }
    #pragma unroll 1
    for (int c0 = 0; c0 < NC; c0 += 16) {
      float Hn[16], Pn[16];
      if (c0 + 16 < NC) {
        #pragma unroll
        for (int q = 0; q < 16; ++q) {
          Hn[q] = bf2f(Hc[ihb + (size_t)(c0 + 16 + q) * hstride]);
          Pn[q] = Pc[ipb + (size_t)(c0 + 16 + q) * 256];
        }
      }
      #pragma unroll
      for (int q = 0; q < 16; ++q) {
        Hc[ihb + (size_t)(c0 + q) * hstride] = f2bf(h);
        h = fmaf(Pv[q], h, Hv[q]);
      }
      #pragma unroll
      for (int q = 0; q < 16; ++q) { Hv[q] = Hn[q]; Pv[q] = Pn[q]; }
    }
  }
  grid.sync();

  // ---------------- P6: cross-chunk correction + gelu (1024 units) --------
  for (int u = bid; u < B_DIM * NC * 4; u += GRID_BLOCKS) {
    const int dq = u & 3;
    const int c = (u >> 2) & (NC - 1);
    const int b = u >> 9;
    passB_unit(b, c, dq, tid, lamb, bcb, Hc, proj, ybuf, gbf, smem);
  }
  grid.sync();

  // ---------------- P7: out = g @ W_out^T (256 tiles) ---------------------
  if (bid < 256) {
    const int tm = bid & 63;
    const int tn = bid >> 6;          // 0..3
    const int bm = tm * 64, bn = tn * 64;
    f32x4 acc[2][2];
    gemm64_core(gbf, wob + (size_t)bn * 256, 256, bm, smem, acc, tid);
    const int lane = tid & 63;
    const int w = tid >> 6, wm = w >> 1, wn = w & 1;
    const int cl = lane & 15, rg = lane >> 4;
    #pragma unroll
    for (int j = 0; j < 2; ++j) {
      const int col = bn + wn * 32 + j * 16 + cl;
      #pragma unroll
      for (int i = 0; i < 2; ++i) {
        const int rbase = bm + wm * 32 + i * 16 + rg * 4;
        #pragma unroll
        for (int r = 0; r < 4; ++r)
          p.out[(size_t)(rbase + r) * 256 + col] = acc[i][j][r];
      }
    }
  }
}

extern "C" void kernel_launch(void* const* d_in, const int* in_sizes, int n_in,
                              void* d_out, int out_size, void* d_ws, size_t ws_size,
                              hipStream_t stream) {
  MegaParams p;
  p.x      = (const float*)d_in[0];
  p.W_in   = (const float*)d_in[1];
  p.conv_w = (const float*)d_in[2];
  p.conv_b = (const float*)d_in[3];
  p.W_bc   = (const float*)d_in[4];
  p.b_bc   = (const float*)d_in[5];
  p.W_lam  = (const float*)d_in[6];
  p.b_lam  = (const float*)d_in[7];
  p.A      = (const float*)d_in[8];
  p.W_out  = (const float*)d_in[9];
  p.out    = (float*)d_out;
  p.ws     = (float*)d_ws;

  void* args[] = { &p };
  hipLaunchCooperativeKernel((const void*)mega_kernel, dim3(GRID_BLOCKS),
                             dim3(256), args, 0, stream);
}

// Round 8
// 81.691 us; speedup vs baseline: 5.8067x; 5.8067x over previous
//
#include <hip/hip_runtime.h>
#include <hip/hip_bf16.h>
#include <math.h>

// Problem constants
#define B_DIM 2
#define L_SEQ 2048
#define D_DIM 256
#define N_DIM 64
#define K_CONV 4
#define M_ROWS (B_DIM * L_SEQ)   // 4096
#define NC 128                    // number of scan chunks
#define CL (L_SEQ / NC)           // 16 steps per chunk

typedef __attribute__((ext_vector_type(8))) short bf16x8;
typedef __attribute__((ext_vector_type(4))) float f32x4;
typedef unsigned short ushort_t;

static __device__ __forceinline__ unsigned short f2bf(float f) {
  unsigned int u = __float_as_uint(f);
  unsigned int r = u + 0x7FFF + ((u >> 16) & 1);   // round-to-nearest-even
  return (unsigned short)(r >> 16);
}
static __device__ __forceinline__ float bf2f(ushort_t s) {
  return __uint_as_float(((unsigned int)s) << 16);
}

// ---------------- convert x + 4 weight matrices f32 -> bf16 ----------------
__global__ __launch_bounds__(256) void cvt5(
    const float* __restrict__ x, const float* __restrict__ wi,
    const float* __restrict__ wbc, const float* __restrict__ wl,
    const float* __restrict__ wo,
    ushort_t* __restrict__ xb, ushort_t* __restrict__ wib,
    ushort_t* __restrict__ wbcb, ushort_t* __restrict__ wlb,
    ushort_t* __restrict__ wob) {
  int bid = blockIdx.x;
  const float* src; ushort_t* dst; int off;
  if (bid < 1024)      { src = x;   dst = xb;   off = bid; }
  else if (bid < 1152) { src = wi;  dst = wib;  off = bid - 1024; }
  else if (bid < 1184) { src = wbc; dst = wbcb; off = bid - 1152; }
  else if (bid < 1248) { src = wl;  dst = wlb;  off = bid - 1184; }
  else                 { src = wo;  dst = wob;  off = bid - 1248; }
  size_t i = (size_t)off * 1024 + threadIdx.x * 4;
  float4 v = *reinterpret_cast<const float4*>(&src[i]);
  ushort4 o;
  o.x = f2bf(v.x); o.y = f2bf(v.y); o.z = f2bf(v.z); o.w = f2bf(v.w);
  *reinterpret_cast<ushort4*>(&dst[i]) = o;
}

// ====== 64x64-tile panel GEMM, K=256, BK=128 halves with reg prefetch ======
// MODE 0: plain C0[row*256+col] (out GEMM)
// MODE 1: bc|lambda fused epilogue (C0=bcb, C1=lamb, C2=uwb)
// MODE 2: proj split (C0=skipb cols 0-255, C1=praw cols 256-511)
template<int MODE>
__global__ __launch_bounds__(256) void pgemm(
    const ushort_t* __restrict__ Ag, const ushort_t* __restrict__ Wg,
    const ushort_t* __restrict__ Wg2,
    float* __restrict__ C0, float* __restrict__ C1, float* __restrict__ C2,
    const float* __restrict__ bias0, const float* __restrict__ bias1,
    const float* __restrict__ Avec, const ushort_t* __restrict__ ubf2) {
  __shared__ __align__(16) ushort_t As[64][136];
  __shared__ __align__(16) ushort_t Ws[64][136];
  const int tid = threadIdx.x;
  const int lane = tid & 63;
  const int wid = tid >> 6;
  const int wm = wid >> 1;
  const int wn = wid & 1;
  const int bm = blockIdx.y * 64;
  const int bn = blockIdx.x * 64;
  const int r = tid >> 2;
  const int cq = (tid & 3) * 32;

  const ushort_t* Wbase;
  if (MODE == 1) Wbase = (bn < 128) ? (Wg + (size_t)bn * 256)
                                    : (Wg2 + (size_t)(bn - 128) * 256);
  else Wbase = Wg + (size_t)bn * 256;
  const ushort_t* Arow = Ag + (size_t)(bm + r) * 256 + cq;
  const ushort_t* Wrow = Wbase + (size_t)r * 256 + cq;

  uint4 av[4], wv[4];
  #pragma unroll
  for (int q = 0; q < 4; ++q) {
    av[q] = *reinterpret_cast<const uint4*>(Arow + q * 8);
    wv[q] = *reinterpret_cast<const uint4*>(Wrow + q * 8);
  }
  #pragma unroll
  for (int q = 0; q < 4; ++q) {
    *reinterpret_cast<uint4*>(&As[r][cq + q * 8]) = av[q];
    *reinterpret_cast<uint4*>(&Ws[r][cq + q * 8]) = wv[q];
  }
  __syncthreads();
  // prefetch half 1 (k = 128..255) into registers while computing half 0
  #pragma unroll
  for (int q = 0; q < 4; ++q) {
    av[q] = *reinterpret_cast<const uint4*>(Arow + 128 + q * 8);
    wv[q] = *reinterpret_cast<const uint4*>(Wrow + 128 + q * 8);
  }

  f32x4 acc[2][2];
  #pragma unroll
  for (int i = 0; i < 2; ++i)
    #pragma unroll
    for (int j = 0; j < 2; ++j)
      acc[i][j] = (f32x4){0.f, 0.f, 0.f, 0.f};

  const int row16 = lane & 15;
  const int hi8 = (lane >> 4) * 8;

  #pragma unroll
  for (int ks = 0; ks < 4; ++ks) {
    const int ko = ks * 32 + hi8;
    bf16x8 af0 = *reinterpret_cast<const bf16x8*>(&As[wm * 32 + row16][ko]);
    bf16x8 af1 = *reinterpret_cast<const bf16x8*>(&As[wm * 32 + 16 + row16][ko]);
    bf16x8 bf0 = *reinterpret_cast<const bf16x8*>(&Ws[wn * 32 + row16][ko]);
    bf16x8 bf1 = *reinterpret_cast<const bf16x8*>(&Ws[wn * 32 + 16 + row16][ko]);
    acc[0][0] = __builtin_amdgcn_mfma_f32_16x16x32_bf16(af0, bf0, acc[0][0], 0, 0, 0);
    acc[0][1] = __builtin_amdgcn_mfma_f32_16x16x32_bf16(af0, bf1, acc[0][1], 0, 0, 0);
    acc[1][0] = __builtin_amdgcn_mfma_f32_16x16x32_bf16(af1, bf0, acc[1][0], 0, 0, 0);
    acc[1][1] = __builtin_amdgcn_mfma_f32_16x16x32_bf16(af1, bf1, acc[1][1], 0, 0, 0);
  }
  __syncthreads();
  #pragma unroll
  for (int q = 0; q < 4; ++q) {
    *reinterpret_cast<uint4*>(&As[r][cq + q * 8]) = av[q];
    *reinterpret_cast<uint4*>(&Ws[r][cq + q * 8]) = wv[q];
  }
  __syncthreads();
  #pragma unroll
  for (int ks = 0; ks < 4; ++ks) {
    const int ko = ks * 32 + hi8;
    bf16x8 af0 = *reinterpret_cast<const bf16x8*>(&As[wm * 32 + row16][ko]);
    bf16x8 af1 = *reinterpret_cast<const bf16x8*>(&As[wm * 32 + 16 + row16][ko]);
    bf16x8 bf0 = *reinterpret_cast<const bf16x8*>(&Ws[wn * 32 + row16][ko]);
    bf16x8 bf1 = *reinterpret_cast<const bf16x8*>(&Ws[wn * 32 + 16 + row16][ko]);
    acc[0][0] = __builtin_amdgcn_mfma_f32_16x16x32_bf16(af0, bf0, acc[0][0], 0, 0, 0);
    acc[0][1] = __builtin_amdgcn_mfma_f32_16x16x32_bf16(af0, bf1, acc[0][1], 0, 0, 0);
    acc[1][0] = __builtin_amdgcn_mfma_f32_16x16x32_bf16(af1, bf0, acc[1][0], 0, 0, 0);
    acc[1][1] = __builtin_amdgcn_mfma_f32_16x16x32_bf16(af1, bf1, acc[1][1], 0, 0, 0);
  }

  // ---- epilogue: C/D layout col = lane&15, row = (lane>>4)*4 + reg ----
  const int cl = lane & 15;
  const int rg = lane >> 4;
  #pragma unroll
  for (int j = 0; j < 2; ++j) {
    const int col = bn + wn * 32 + j * 16 + cl;
    if (MODE == 0) {
      #pragma unroll
      for (int i = 0; i < 2; ++i) {
        const int rbase = bm + wm * 32 + i * 16 + rg * 4;
        #pragma unroll
        for (int rr = 0; rr < 4; ++rr)
          C0[(size_t)(rbase + rr) * 256 + col] = acc[i][j][rr];
      }
    } else if (MODE == 2) {
      float* dst = (col < 256) ? C0 : C1;
      const int cc = col & 255;
      #pragma unroll
      for (int i = 0; i < 2; ++i) {
        const int rbase = bm + wm * 32 + i * 16 + rg * 4;
        #pragma unroll
        for (int rr = 0; rr < 4; ++rr)
          dst[(size_t)(rbase + rr) * 256 + cc] = acc[i][j][rr];
      }
    } else {   // MODE 1: bc | lambda
      if (col < 128) {
        const float bv = bias0[col];
        #pragma unroll
        for (int i = 0; i < 2; ++i) {
          const int rbase = bm + wm * 32 + i * 16 + rg * 4;
          #pragma unroll
          for (int rr = 0; rr < 4; ++rr)
            C0[(size_t)(rbase + rr) * 128 + col] = acc[i][j][rr] + bv;
        }
      } else {
        const int dd = col - 128;
        const float bv = bias1[dd];
        const float adg = -8.f * log1pf(__expf(Avec[dd]));
        #pragma unroll
        for (int i = 0; i < 2; ++i) {
          const int rbase = bm + wm * 32 + i * 16 + rg * 4;
          #pragma unroll
          for (int rr = 0; rr < 4; ++rr) {
            const int row = rbase + rr;
            float v = acc[i][j][rr] + bv;
            float s = 1.f / (1.f + __expf(-v));
            float lam = __expf(s * adg);
            float wq = sqrtf(1.f + 1e-6f - lam * lam);
            float u = bf2f(ubf2[(size_t)row * 256 + dd]);
            C1[(size_t)row * 256 + dd] = lam;
            C2[(size_t)row * 256 + dd] = u * wq;
          }
        }
      }
    }
  }
}

// ---- depthwise causal conv, 8 rows/block, LDS-staged halo tile ------------
__global__ __launch_bounds__(256) void conv_kernel(
    const float* __restrict__ praw, const float* __restrict__ cw,
    const float* __restrict__ cb, ushort_t* __restrict__ ubf) {
  __shared__ __align__(16) float pst[11][256];   // rows m0-3 .. m0+7
  const int tid = threadIdx.x;
  const int m0 = blockIdx.x * 8;
  for (int i = tid; i < 704; i += 256) {
    int row = i >> 6;
    int q = i & 63;
    int gm = m0 - 3 + row;
    float4 v = {0.f, 0.f, 0.f, 0.f};
    if (gm >= 0 && (gm >> 11) == (m0 >> 11))
      v = *reinterpret_cast<const float4*>(&praw[(size_t)gm * 256 + q * 4]);
    *reinterpret_cast<float4*>(&pst[row][q * 4]) = v;
  }
  __syncthreads();
  const int d = tid;
  const float4 w4 = *reinterpret_cast<const float4*>(&cw[d * 4]);
  const float bias = cb[d];
  #pragma unroll
  for (int r = 0; r < 8; ++r) {
    float acc = bias + w4.x * pst[r][d] + w4.y * pst[r + 1][d] +
                w4.z * pst[r + 2][d] + w4.w * pst[r + 3][d];
    ubf[(size_t)(m0 + r) * 256 + d] = f2bf(acc);
  }
}

// ---- scan pass A: grid = B*NC*4 (d-quarters), 4 waves = 4 n-groups -------
__global__ __launch_bounds__(256) void passA(
    const float* __restrict__ lamb, const float* __restrict__ uwb,
    const float* __restrict__ bcb, float* __restrict__ Pc,
    ushort_t* __restrict__ Hc, float* __restrict__ ybuf) {
  const int bx = blockIdx.x;
  const int dq = bx & 3;
  const int c = (bx >> 2) & (NC - 1);
  const int b = bx >> 9;
  const int lane = threadIdx.x & 63;
  const int ng = threadIdx.x >> 6;       // wave id = n-group
  const int dd = dq * 64 + lane;
  __shared__ __align__(16) float bcs[CL][128];    // 8 KB
  __shared__ __align__(16) float lam_s[CL][64];   // 4 KB
  __shared__ __align__(16) float uw_s[CL][64];    // 4 KB
  __shared__ float ypar[CL][4][64];               // 16 KB
  {
    const float4* src = reinterpret_cast<const float4*>(
        bcb + (size_t)(b * L_SEQ + c * CL) * 128);
    float4* dst = reinterpret_cast<float4*>(&bcs[0][0]);
    dst[threadIdx.x] = src[threadIdx.x];
    dst[threadIdx.x + 256] = src[threadIdx.x + 256];
    const int ts = threadIdx.x >> 4, qs = threadIdx.x & 15;
    size_t rowb = (size_t)(b * L_SEQ + c * CL + ts) * 256 + dq * 64 + qs * 4;
    *reinterpret_cast<float4*>(&lam_s[ts][qs * 4]) =
        *reinterpret_cast<const float4*>(&lamb[rowb]);
    *reinterpret_cast<float4*>(&uw_s[ts][qs * 4]) =
        *reinterpret_cast<const float4*>(&uwb[rowb]);
  }
  __syncthreads();
  float H[16];
  #pragma unroll
  for (int j = 0; j < 16; ++j) H[j] = 0.f;
  float P = 1.f;
  const size_t base0 = (size_t)(b * L_SEQ + c * CL) * 256 + dd;
  #pragma unroll 4
  for (int t = 0; t < CL; ++t) {
    float lam = lam_s[t][lane];
    float uw = uw_s[t][lane];
    P *= lam;
    float yp = 0.f;
    const float* bt = &bcs[t][ng * 16];
    const float* ct = &bcs[t][64 + ng * 16];
    #pragma unroll
    for (int j = 0; j < 16; ++j) {
      H[j] = lam * H[j] + bt[j] * uw;
      yp += ct[j] * H[j];
    }
    ypar[t][ng][lane] = yp;
  }
  if (ng == 0) Pc[(size_t)(b * NC + c) * 256 + dd] = P;
  #pragma unroll
  for (int j = 0; j < 16; ++j)
    Hc[((size_t)(b * NC + c) * 64 + ng * 16 + j) * 256 + dd] = f2bf(H[j]);
  __syncthreads();
  #pragma unroll
  for (int tt = 0; tt < 4; ++tt) {
    int t = ng * 4 + tt;
    float y = ypar[t][0][lane] + ypar[t][1][lane] +
              ypar[t][2][lane] + ypar[t][3][lane];
    ybuf[base0 + (size_t)t * 256] = y;
  }
}

// ---- sequential chunk scan, pipelined unroll-16 (hin in-place, bf16) ------
__global__ __launch_bounds__(128) void chunkscan(
    const float* __restrict__ Pc, ushort_t* __restrict__ Hc) {
  int tid = blockIdx.x * 128 + threadIdx.x;   // 32768 = B*N*D
  int d = tid & 255;
  int j = (tid >> 8) & 63;
  int b = tid >> 14;
  const size_t hstride = (size_t)N_DIM * 256;
  const size_t ihb = ((size_t)(b * NC) * 64 + j) * 256 + d;
  const size_t ipb = (size_t)(b * NC) * 256 + d;
  float h = 0.f;
  float Hv[16], Pv[16];
  #pragma unroll
  for (int q = 0; q < 16; ++q) {
    Hv[q] = bf2f(Hc[ihb + (size_t)q * hstride]);
    Pv[q] = Pc[ipb + (size_t)q * 256];
  }
  #pragma unroll 1
  for (int c0 = 0; c0 < NC; c0 += 16) {
    float Hn[16], Pn[16];
    if (c0 + 16 < NC) {
      #pragma unroll
      for (int q = 0; q < 16; ++q) {
        Hn[q] = bf2f(Hc[ihb + (size_t)(c0 + 16 + q) * hstride]);
        Pn[q] = Pc[ipb + (size_t)(c0 + 16 + q) * 256];
      }
    }
    #pragma unroll
    for (int q = 0; q < 16; ++q) {
      Hc[ihb + (size_t)(c0 + q) * hstride] = f2bf(h);
      h = fmaf(Pv[q], h, Hv[q]);
    }
    #pragma unroll
    for (int q = 0; q < 16; ++q) { Hv[q] = Hn[q]; Pv[q] = Pn[q]; }
  }
}

// ---- scan pass B + GELU gate; lam prefix from LDS; writes bf16 g ----------
__global__ __launch_bounds__(256) void passB_gelu(
    const float* __restrict__ lamb, const float* __restrict__ bcb,
    const ushort_t* __restrict__ hin, const float* __restrict__ skipb,
    const float* __restrict__ ybuf, ushort_t* __restrict__ gbf) {
  const int bx = blockIdx.x;
  const int dq = bx & 3;
  const int c = (bx >> 2) & (NC - 1);
  const int b = bx >> 9;
  const int lane = threadIdx.x & 63;
  const int ng = threadIdx.x >> 6;
  const int dd = dq * 64 + lane;
  __shared__ __align__(16) float cs[CL][64];      // 4 KB
  __shared__ __align__(16) float lam_s[CL][64];   // 4 KB
  __shared__ float spar[CL][4][64];               // 16 KB
  {
    int t0 = threadIdx.x >> 4;
    int jq = threadIdx.x & 15;
    *reinterpret_cast<float4*>(&cs[t0][jq * 4]) =
        *reinterpret_cast<const float4*>(
            bcb + (size_t)(b * L_SEQ + c * CL + t0) * 128 + 64 + jq * 4);
    size_t rowb = (size_t)(b * L_SEQ + c * CL + t0) * 256 + dq * 64 + jq * 4;
    *reinterpret_cast<float4*>(&lam_s[t0][jq * 4]) =
        *reinterpret_cast<const float4*>(&lamb[rowb]);
  }
  float h16[16];
  #pragma unroll
  for (int j = 0; j < 16; ++j)
    h16[j] = bf2f(hin[((size_t)(b * NC + c) * 64 + ng * 16 + j) * 256 + dd]);
  __syncthreads();
  const size_t base0 = (size_t)(b * L_SEQ + c * CL) * 256 + dd;
  #pragma unroll 4
  for (int t = 0; t < CL; ++t) {
    float S = 0.f;
    const float* ct = &cs[t][ng * 16];
    #pragma unroll
    for (int j = 0; j < 16; ++j) S += ct[j] * h16[j];
    spar[t][ng][lane] = S;
  }
  __syncthreads();
  float Pp = 1.f;
  #pragma unroll
  for (int tau = 0; tau < 12; ++tau)
    if (tau < ng * 4) Pp *= lam_s[tau][lane];
  #pragma unroll
  for (int tt = 0; tt < 4; ++tt) {
    int t = ng * 4 + tt;
    Pp *= lam_s[t][lane];
    float S4 = spar[t][0][lane] + spar[t][1][lane] +
               spar[t][2][lane] + spar[t][3][lane];
    float y = ybuf[base0 + (size_t)t * 256] + Pp * S4;
    float sk = skipb[base0 + (size_t)t * 256];
    float g = 0.5f * sk * (1.f + erff(sk * 0.70710678118f));
    gbf[base0 + (size_t)t * 256] = f2bf(g * y);
  }
}

extern "C" void kernel_launch(void* const* d_in, const int* in_sizes, int n_in,
                              void* d_out, int out_size, void* d_ws, size_t ws_size,
                              hipStream_t stream) {
  const float* x      = (const float*)d_in[0];
  const float* W_in   = (const float*)d_in[1];
  const float* conv_w = (const float*)d_in[2];
  const float* conv_b = (const float*)d_in[3];
  const float* W_bc   = (const float*)d_in[4];
  const float* b_bc   = (const float*)d_in[5];
  const float* W_lam  = (const float*)d_in[6];
  const float* b_lam  = (const float*)d_in[7];
  const float* A      = (const float*)d_in[8];
  const float* W_out  = (const float*)d_in[9];
  float* out = (float*)d_out;

  float* ws = (float*)d_ws;
  float* skipb = ws;                        // 1,048,576
  float* praw  = ws + 1048576;              // 1,048,576
  float* lamb  = ws + 2097152;              // 1,048,576
  float* uwb   = ws + 3145728;              // 1,048,576
  float* bcb   = ws + 4194304;              //   524,288
  float* ybuf  = ws + 4718592;              // 1,048,576
  float* Pc    = ws + 5767168;              //    65,536
  ushort_t* Hc = (ushort_t*)(ws + 5832704); // 4,194,304 shorts (bf16)
  ushort_t* xbf  = (ushort_t*)(ws + 7929856);   // 1,048,576 shorts
  ushort_t* wib  = (ushort_t*)(ws + 8454144);   //   131,072 shorts
  ushort_t* wbcb = (ushort_t*)(ws + 8519680);   //    32,768 shorts
  ushort_t* wlb  = (ushort_t*)(ws + 8536064);   //    65,536 shorts
  ushort_t* wob  = (ushort_t*)(ws + 8568832);   //    65,536 shorts
  ushort_t* ubf  = (ushort_t*)(ws + 8601600);   // 1,048,576 shorts
  ushort_t* gbf  = (ushort_t*)(ws + 9125888);   // 1,048,576 shorts
  // end: 9,650,176 floats ~ 38.6 MB

  // 0) one-time f32 -> bf16 conversion of x and all weights
  cvt5<<<dim3(1312), dim3(256), 0, stream>>>(
      x, W_in, W_bc, W_lam, W_out, xbf, wib, wbcb, wlb, wob);
  // 1) proj = x @ W_in^T -> skipb | praw  [bf16 MFMA, 512 blocks]
  pgemm<2><<<dim3(8, 64), dim3(256), 0, stream>>>(
      xbf, wib, nullptr, skipb, praw, nullptr, nullptr, nullptr, nullptr, nullptr);
  // 2) depthwise causal conv + bias -> ubf
  conv_kernel<<<dim3(M_ROWS / 8), dim3(256), 0, stream>>>(praw, conv_w, conv_b, ubf);
  // 3) fused bc + lambda GEMM (N=384, 384 blocks)
  pgemm<1><<<dim3(6, 64), dim3(256), 0, stream>>>(
      ubf, wbcb, wlb, bcb, lamb, uwb, b_bc, b_lam, A, ubf);
  // 4) chunk-local scan
  passA<<<dim3(B_DIM * NC * 4), dim3(256), 0, stream>>>(lamb, uwb, bcb, Pc, Hc, ybuf);
  // 5) chunk-prefix scan (pipelined, bf16 summaries)
  chunkscan<<<dim3(256), dim3(128), 0, stream>>>(Pc, Hc);
  // 6) cross-chunk correction + gelu gate -> bf16 g
  passB_gelu<<<dim3(B_DIM * NC * 4), dim3(256), 0, stream>>>(
      lamb, bcb, Hc, skipb, ybuf, gbf);
  // 7) out = g @ W_out^T  [bf16 MFMA, 256 blocks]
  pgemm<0><<<dim3(4, 64), dim3(256), 0, stream>>>(
      gbf, wob, nullptr, out, nullptr, nullptr, nullptr, nullptr, nullptr, nullptr);
}

// Round 9
// 70.075 us; speedup vs baseline: 6.7692x; 1.1658x over previous
//
#include <hip/hip_runtime.h>
#include <hip/hip_bf16.h>
#include <math.h>

// Problem constants
#define B_DIM 2
#define L_SEQ 2048
#define D_DIM 256
#define N_DIM 64
#define K_CONV 4
#define M_ROWS (B_DIM * L_SEQ)   // 4096
#define NC 128                    // number of scan chunks
#define CL (L_SEQ / NC)           // 16 steps per chunk

typedef __attribute__((ext_vector_type(8))) short bf16x8;
typedef __attribute__((ext_vector_type(4))) float f32x4;
typedef unsigned short ushort_t;

static __device__ __forceinline__ unsigned short f2bf(float f) {
  unsigned int u = __float_as_uint(f);
  unsigned int r = u + 0x7FFF + ((u >> 16) & 1);   // round-to-nearest-even
  return (unsigned short)(r >> 16);
}
static __device__ __forceinline__ float bf2f(ushort_t s) {
  return __uint_as_float(((unsigned int)s) << 16);
}

// ---------------- convert x + 4 weight matrices f32 -> bf16 ----------------
__global__ __launch_bounds__(256) void cvt5(
    const float* __restrict__ x, const float* __restrict__ wi,
    const float* __restrict__ wbc, const float* __restrict__ wl,
    const float* __restrict__ wo,
    ushort_t* __restrict__ xb, ushort_t* __restrict__ wib,
    ushort_t* __restrict__ wbcb, ushort_t* __restrict__ wlb,
    ushort_t* __restrict__ wob) {
  int bid = blockIdx.x;
  const float* src; ushort_t* dst; int off;
  if (bid < 1024)      { src = x;   dst = xb;   off = bid; }
  else if (bid < 1152) { src = wi;  dst = wib;  off = bid - 1024; }
  else if (bid < 1184) { src = wbc; dst = wbcb; off = bid - 1152; }
  else if (bid < 1248) { src = wl;  dst = wlb;  off = bid - 1184; }
  else                 { src = wo;  dst = wob;  off = bid - 1248; }
  size_t i = (size_t)off * 1024 + threadIdx.x * 4;
  float4 v = *reinterpret_cast<const float4*>(&src[i]);
  ushort4 o;
  o.x = f2bf(v.x); o.y = f2bf(v.y); o.z = f2bf(v.z); o.w = f2bf(v.w);
  *reinterpret_cast<ushort4*>(&dst[i]) = o;
}

// ====== 128x64-tile MFMA bf16 GEMM (round-6 structure), K=256 ==============
// MODE 0: out = A @ W^T           -> C0[row*256+col]
// MODE 1: bc|lambda fused         -> C0=bcb(+bias0), C1=lamb, C2=uwb
// MODE 2: proj split              -> C0=skipb (col<256), C1=praw (col>=256)
template<int MODE>
__global__ __launch_bounds__(256) void mgemm(
    const ushort_t* __restrict__ Ag, const ushort_t* __restrict__ Wg,
    const ushort_t* __restrict__ Wg2,
    float* __restrict__ C0, float* __restrict__ C1, float* __restrict__ C2,
    const float* __restrict__ bias0, const float* __restrict__ bias1,
    const float* __restrict__ Avec, const ushort_t* __restrict__ ubf2) {
  __shared__ __align__(16) ushort_t As[128][72];
  __shared__ __align__(16) ushort_t Ws[64][72];
  const int tid = threadIdx.x;
  const int lane = tid & 63;
  const int w = tid >> 6;
  const int wm = w >> 1;
  const int wn = w & 1;
  const int bm = blockIdx.y * 128;
  const int bn = blockIdx.x * 64;
  const int r0 = tid >> 3;         // 0..31
  const int c8 = (tid & 7) * 8;    // contiguous 16B per 8 lanes (coalesced)
  const int K = 256;

  const ushort_t* Wsrc;
  if (MODE == 1) Wsrc = (bn < 128) ? (Wg + (size_t)bn * 256)
                                   : (Wg2 + (size_t)(bn - 128) * 256);
  else Wsrc = Wg + (size_t)bn * 256;

  f32x4 acc[4][2];
  #pragma unroll
  for (int i = 0; i < 4; ++i)
    #pragma unroll
    for (int j = 0; j < 2; ++j)
      acc[i][j] = (f32x4){0.f, 0.f, 0.f, 0.f};

  const int row16 = lane & 15;

  for (int k0 = 0; k0 < K; k0 += 64) {
    #pragma unroll
    for (int p = 0; p < 4; ++p) {
      int r = r0 + p * 32;
      uint4 v = *reinterpret_cast<const uint4*>(&Ag[(size_t)(bm + r) * K + k0 + c8]);
      *reinterpret_cast<uint4*>(&As[r][c8]) = v;
    }
    #pragma unroll
    for (int p = 0; p < 2; ++p) {
      int r = r0 + p * 32;
      uint4 v = *reinterpret_cast<const uint4*>(&Wsrc[(size_t)r * K + k0 + c8]);
      *reinterpret_cast<uint4*>(&Ws[r][c8]) = v;
    }
    __syncthreads();
    #pragma unroll
    for (int ks = 0; ks < 2; ++ks) {
      const int ko = ks * 32 + (lane >> 4) * 8;
      bf16x8 af[4], bfr[2];
      #pragma unroll
      for (int i = 0; i < 4; ++i)
        af[i] = *reinterpret_cast<const bf16x8*>(&As[wm * 64 + i * 16 + row16][ko]);
      #pragma unroll
      for (int j = 0; j < 2; ++j)
        bfr[j] = *reinterpret_cast<const bf16x8*>(&Ws[wn * 32 + j * 16 + row16][ko]);
      #pragma unroll
      for (int i = 0; i < 4; ++i)
        #pragma unroll
        for (int j = 0; j < 2; ++j)
          acc[i][j] = __builtin_amdgcn_mfma_f32_16x16x32_bf16(af[i], bfr[j], acc[i][j], 0, 0, 0);
    }
    __syncthreads();
  }

  // ---- epilogue: C/D layout col = lane&15, row = (lane>>4)*4 + reg ----
  const int cl = lane & 15;
  const int rg = lane >> 4;
  #pragma unroll
  for (int j = 0; j < 2; ++j) {
    const int col = bn + wn * 32 + j * 16 + cl;
    if (MODE == 0) {
      #pragma unroll
      for (int i = 0; i < 4; ++i) {
        const int rbase = bm + wm * 64 + i * 16 + rg * 4;
        #pragma unroll
        for (int rr = 0; rr < 4; ++rr)
          C0[(size_t)(rbase + rr) * 256 + col] = acc[i][j][rr];
      }
    } else if (MODE == 2) {
      float* dst = (col < 256) ? C0 : C1;
      const int cc = col & 255;
      #pragma unroll
      for (int i = 0; i < 4; ++i) {
        const int rbase = bm + wm * 64 + i * 16 + rg * 4;
        #pragma unroll
        for (int rr = 0; rr < 4; ++rr)
          dst[(size_t)(rbase + rr) * 256 + cc] = acc[i][j][rr];
      }
    } else {   // MODE 1: bc | lambda
      if (col < 128) {
        const float bv = bias0[col];
        #pragma unroll
        for (int i = 0; i < 4; ++i) {
          const int rbase = bm + wm * 64 + i * 16 + rg * 4;
          #pragma unroll
          for (int rr = 0; rr < 4; ++rr)
            C0[(size_t)(rbase + rr) * 128 + col] = acc[i][j][rr] + bv;
        }
      } else {
        const int dd = col - 128;
        const float bv = bias1[dd];
        const float adg = -8.f * log1pf(__expf(Avec[dd]));
        #pragma unroll
        for (int i = 0; i < 4; ++i) {
          const int rbase = bm + wm * 64 + i * 16 + rg * 4;
          #pragma unroll
          for (int rr = 0; rr < 4; ++rr) {
            const int row = rbase + rr;
            float v = acc[i][j][rr] + bv;
            float s = 1.f / (1.f + __expf(-v));
            float lam = __expf(s * adg);
            float wq = sqrtf(1.f + 1e-6f - lam * lam);
            float u = bf2f(ubf2[(size_t)row * 256 + dd]);
            C1[(size_t)row * 256 + dd] = lam;
            C2[(size_t)row * 256 + dd] = u * wq;
          }
        }
      }
    }
  }
}

// ---- depthwise causal conv, 8 rows/block, LDS-staged halo tile ------------
__global__ __launch_bounds__(256) void conv_kernel(
    const float* __restrict__ praw, const float* __restrict__ cw,
    const float* __restrict__ cb, ushort_t* __restrict__ ubf) {
  __shared__ __align__(16) float pst[11][256];   // rows m0-3 .. m0+7
  const int tid = threadIdx.x;
  const int m0 = blockIdx.x * 8;
  for (int i = tid; i < 704; i += 256) {
    int row = i >> 6;
    int q = i & 63;
    int gm = m0 - 3 + row;
    float4 v = {0.f, 0.f, 0.f, 0.f};
    if (gm >= 0 && (gm >> 11) == (m0 >> 11))
      v = *reinterpret_cast<const float4*>(&praw[(size_t)gm * 256 + q * 4]);
    *reinterpret_cast<float4*>(&pst[row][q * 4]) = v;
  }
  __syncthreads();
  const int d = tid;
  const float4 w4 = *reinterpret_cast<const float4*>(&cw[d * 4]);
  const float bias = cb[d];
  #pragma unroll
  for (int r = 0; r < 8; ++r) {
    float acc = bias + w4.x * pst[r][d] + w4.y * pst[r + 1][d] +
                w4.z * pst[r + 2][d] + w4.w * pst[r + 3][d];
    ubf[(size_t)(m0 + r) * 256 + d] = f2bf(acc);
  }
}

// ---- scan pass A: grid = B*NC*4 (d-quarters), 4 waves = 4 n-groups -------
__global__ __launch_bounds__(256) void passA(
    const float* __restrict__ lamb, const float* __restrict__ uwb,
    const float* __restrict__ bcb, float* __restrict__ Pc,
    ushort_t* __restrict__ Hc, float* __restrict__ ybuf) {
  const int bx = blockIdx.x;
  const int dq = bx & 3;
  const int c = (bx >> 2) & (NC - 1);
  const int b = bx >> 9;
  const int lane = threadIdx.x & 63;
  const int ng = threadIdx.x >> 6;       // wave id = n-group
  const int dd = dq * 64 + lane;
  __shared__ __align__(16) float bcs[CL][128];    // 8 KB
  __shared__ __align__(16) float lam_s[CL][64];   // 4 KB
  __shared__ __align__(16) float uw_s[CL][64];    // 4 KB
  __shared__ float ypar[CL][4][64];               // 16 KB
  {
    const float4* src = reinterpret_cast<const float4*>(
        bcb + (size_t)(b * L_SEQ + c * CL) * 128);
    float4* dst = reinterpret_cast<float4*>(&bcs[0][0]);
    dst[threadIdx.x] = src[threadIdx.x];
    dst[threadIdx.x + 256] = src[threadIdx.x + 256];
    const int ts = threadIdx.x >> 4, qs = threadIdx.x & 15;
    size_t rowb = (size_t)(b * L_SEQ + c * CL + ts) * 256 + dq * 64 + qs * 4;
    *reinterpret_cast<float4*>(&lam_s[ts][qs * 4]) =
        *reinterpret_cast<const float4*>(&lamb[rowb]);
    *reinterpret_cast<float4*>(&uw_s[ts][qs * 4]) =
        *reinterpret_cast<const float4*>(&uwb[rowb]);
  }
  __syncthreads();
  float H[16];
  #pragma unroll
  for (int j = 0; j < 16; ++j) H[j] = 0.f;
  float P = 1.f;
  const size_t base0 = (size_t)(b * L_SEQ + c * CL) * 256 + dd;
  #pragma unroll 4
  for (int t = 0; t < CL; ++t) {
    float lam = lam_s[t][lane];
    float uw = uw_s[t][lane];
    P *= lam;
    float yp = 0.f;
    const float4* btv = reinterpret_cast<const float4*>(&bcs[t][ng * 16]);
    const float4* ctv = reinterpret_cast<const float4*>(&bcs[t][64 + ng * 16]);
    #pragma unroll
    for (int q = 0; q < 4; ++q) {
      float4 b4 = btv[q];
      float4 c4 = ctv[q];
      H[q * 4 + 0] = lam * H[q * 4 + 0] + b4.x * uw; yp += c4.x * H[q * 4 + 0];
      H[q * 4 + 1] = lam * H[q * 4 + 1] + b4.y * uw; yp += c4.y * H[q * 4 + 1];
      H[q * 4 + 2] = lam * H[q * 4 + 2] + b4.z * uw; yp += c4.z * H[q * 4 + 2];
      H[q * 4 + 3] = lam * H[q * 4 + 3] + b4.w * uw; yp += c4.w * H[q * 4 + 3];
    }
    ypar[t][ng][lane] = yp;
  }
  if (ng == 0) Pc[(size_t)(b * NC + c) * 256 + dd] = P;
  #pragma unroll
  for (int j = 0; j < 16; ++j)
    Hc[((size_t)(b * NC + c) * 64 + ng * 16 + j) * 256 + dd] = f2bf(H[j]);
  __syncthreads();
  #pragma unroll
  for (int tt = 0; tt < 4; ++tt) {
    int t = ng * 4 + tt;
    float y = ypar[t][0][lane] + ypar[t][1][lane] +
              ypar[t][2][lane] + ypar[t][3][lane];
    ybuf[base0 + (size_t)t * 256] = y;
  }
}

// ---- sequential chunk scan, pipelined unroll-16 (hin in-place, bf16) ------
__global__ __launch_bounds__(128) void chunkscan(
    const float* __restrict__ Pc, ushort_t* __restrict__ Hc) {
  int tid = blockIdx.x * 128 + threadIdx.x;   // 32768 = B*N*D
  int d = tid & 255;
  int j = (tid >> 8) & 63;
  int b = tid >> 14;
  const size_t hstride = (size_t)N_DIM * 256;
  const size_t ihb = ((size_t)(b * NC) * 64 + j) * 256 + d;
  const size_t ipb = (size_t)(b * NC) * 256 + d;
  float h = 0.f;
  float Hv[16], Pv[16];
  #pragma unroll
  for (int q = 0; q < 16; ++q) {
    Hv[q] = bf2f(Hc[ihb + (size_t)q * hstride]);
    Pv[q] = Pc[ipb + (size_t)q * 256];
  }
  #pragma unroll 1
  for (int c0 = 0; c0 < NC; c0 += 16) {
    float Hn[16], Pn[16];
    if (c0 + 16 < NC) {
      #pragma unroll
      for (int q = 0; q < 16; ++q) {
        Hn[q] = bf2f(Hc[ihb + (size_t)(c0 + 16 + q) * hstride]);
        Pn[q] = Pc[ipb + (size_t)(c0 + 16 + q) * 256];
      }
    }
    #pragma unroll
    for (int q = 0; q < 16; ++q) {
      Hc[ihb + (size_t)(c0 + q) * hstride] = f2bf(h);
      h = fmaf(Pv[q], h, Hv[q]);
    }
    #pragma unroll
    for (int q = 0; q < 16; ++q) { Hv[q] = Hn[q]; Pv[q] = Pn[q]; }
  }
}

// ---- scan pass B + GELU gate; lam prefix from LDS; writes bf16 g ----------
__global__ __launch_bounds__(256) void passB_gelu(
    const float* __restrict__ lamb, const float* __restrict__ bcb,
    const ushort_t* __restrict__ hin, const float* __restrict__ skipb,
    const float* __restrict__ ybuf, ushort_t* __restrict__ gbf) {
  const int bx = blockIdx.x;
  const int dq = bx & 3;
  const int c = (bx >> 2) & (NC - 1);
  const int b = bx >> 9;
  const int lane = threadIdx.x & 63;
  const int ng = threadIdx.x >> 6;
  const int dd = dq * 64 + lane;
  __shared__ __align__(16) float cs[CL][64];      // 4 KB
  __shared__ __align__(16) float lam_s[CL][64];   // 4 KB
  __shared__ float spar[CL][4][64];               // 16 KB
  {
    int t0 = threadIdx.x >> 4;
    int jq = threadIdx.x & 15;
    *reinterpret_cast<float4*>(&cs[t0][jq * 4]) =
        *reinterpret_cast<const float4*>(
            bcb + (size_t)(b * L_SEQ + c * CL + t0) * 128 + 64 + jq * 4);
    size_t rowb = (size_t)(b * L_SEQ + c * CL + t0) * 256 + dq * 64 + jq * 4;
    *reinterpret_cast<float4*>(&lam_s[t0][jq * 4]) =
        *reinterpret_cast<const float4*>(&lamb[rowb]);
  }
  float h16[16];
  #pragma unroll
  for (int j = 0; j < 16; ++j)
    h16[j] = bf2f(hin[((size_t)(b * NC + c) * 64 + ng * 16 + j) * 256 + dd]);
  __syncthreads();
  const size_t base0 = (size_t)(b * L_SEQ + c * CL) * 256 + dd;
  #pragma unroll 4
  for (int t = 0; t < CL; ++t) {
    float S = 0.f;
    const float4* ctv = reinterpret_cast<const float4*>(&cs[t][ng * 16]);
    #pragma unroll
    for (int q = 0; q < 4; ++q) {
      float4 c4 = ctv[q];
      S += c4.x * h16[q * 4 + 0] + c4.y * h16[q * 4 + 1] +
           c4.z * h16[q * 4 + 2] + c4.w * h16[q * 4 + 3];
    }
    spar[t][ng][lane] = S;
  }
  __syncthreads();
  float Pp = 1.f;
  #pragma unroll
  for (int tau = 0; tau < 12; ++tau)
    if (tau < ng * 4) Pp *= lam_s[tau][lane];
  #pragma unroll
  for (int tt = 0; tt < 4; ++tt) {
    int t = ng * 4 + tt;
    Pp *= lam_s[t][lane];
    float S4 = spar[t][0][lane] + spar[t][1][lane] +
               spar[t][2][lane] + spar[t][3][lane];
    float y = ybuf[base0 + (size_t)t * 256] + Pp * S4;
    float sk = skipb[base0 + (size_t)t * 256];
    float g = 0.5f * sk * (1.f + erff(sk * 0.70710678118f));
    gbf[base0 + (size_t)t * 256] = f2bf(g * y);
  }
}

extern "C" void kernel_launch(void* const* d_in, const int* in_sizes, int n_in,
                              void* d_out, int out_size, void* d_ws, size_t ws_size,
                              hipStream_t stream) {
  const float* x      = (const float*)d_in[0];
  const float* W_in   = (const float*)d_in[1];
  const float* conv_w = (const float*)d_in[2];
  const float* conv_b = (const float*)d_in[3];
  const float* W_bc   = (const float*)d_in[4];
  const float* b_bc   = (const float*)d_in[5];
  const float* W_lam  = (const float*)d_in[6];
  const float* b_lam  = (const float*)d_in[7];
  const float* A      = (const float*)d_in[8];
  const float* W_out  = (const float*)d_in[9];
  float* out = (float*)d_out;

  float* ws = (float*)d_ws;
  float* skipb = ws;                        // 1,048,576
  float* praw  = ws + 1048576;              // 1,048,576
  float* lamb  = ws + 2097152;              // 1,048,576
  float* uwb   = ws + 3145728;              // 1,048,576
  float* bcb   = ws + 4194304;              //   524,288
  float* ybuf  = ws + 4718592;              // 1,048,576
  float* Pc    = ws + 5767168;              //    65,536
  ushort_t* Hc = (ushort_t*)(ws + 5832704); // 4,194,304 shorts (bf16)
  ushort_t* xbf  = (ushort_t*)(ws + 7929856);   // 1,048,576 shorts
  ushort_t* wib  = (ushort_t*)(ws + 8454144);   //   131,072 shorts
  ushort_t* wbcb = (ushort_t*)(ws + 8519680);   //    32,768 shorts
  ushort_t* wlb  = (ushort_t*)(ws + 8536064);   //    65,536 shorts
  ushort_t* wob  = (ushort_t*)(ws + 8568832);   //    65,536 shorts
  ushort_t* ubf  = (ushort_t*)(ws + 8601600);   // 1,048,576 shorts
  ushort_t* gbf  = (ushort_t*)(ws + 9125888);   // 1,048,576 shorts
  // end: 9,650,176 floats ~ 38.6 MB

  // 0) one-time f32 -> bf16 conversion of x and all weights
  cvt5<<<dim3(1312), dim3(256), 0, stream>>>(
      x, W_in, W_bc, W_lam, W_out, xbf, wib, wbcb, wlb, wob);
  // 1) proj = x @ W_in^T -> skipb | praw  [bf16 MFMA, 128x64 tiles]
  mgemm<2><<<dim3(8, 32), dim3(256), 0, stream>>>(
      xbf, wib, nullptr, skipb, praw, nullptr, nullptr, nullptr, nullptr, nullptr);
  // 2) depthwise causal conv + bias -> ubf
  conv_kernel<<<dim3(M_ROWS / 8), dim3(256), 0, stream>>>(praw, conv_w, conv_b, ubf);
  // 3) fused bc + lambda GEMM (N=384)
  mgemm<1><<<dim3(6, 32), dim3(256), 0, stream>>>(
      ubf, wbcb, wlb, bcb, lamb, uwb, b_bc, b_lam, A, ubf);
  // 4) chunk-local scan
  passA<<<dim3(B_DIM * NC * 4), dim3(256), 0, stream>>>(lamb, uwb, bcb, Pc, Hc, ybuf);
  // 5) chunk-prefix scan (pipelined, bf16 summaries)
  chunkscan<<<dim3(256), dim3(128), 0, stream>>>(Pc, Hc);
  // 6) cross-chunk correction + gelu gate -> bf16 g
  passB_gelu<<<dim3(B_DIM * NC * 4), dim3(256), 0, stream>>>(
      lamb, bcb, Hc, skipb, ybuf, gbf);
  // 7) out = g @ W_out^T  [bf16 MFMA]
  mgemm<0><<<dim3(4, 32), dim3(256), 0, stream>>>(
      gbf, wob, nullptr, out, nullptr, nullptr, nullptr, nullptr, nullptr, nullptr);
}

// Round 10
// 69.535 us; speedup vs baseline: 6.8217x; 1.0078x over previous
//
#include <hip/hip_runtime.h>
#include <hip/hip_bf16.h>
#include <math.h>

// Problem constants
#define B_DIM 2
#define L_SEQ 2048
#define D_DIM 256
#define N_DIM 64
#define K_CONV 4
#define M_ROWS (B_DIM * L_SEQ)   // 4096
#define NC 128                    // number of scan chunks
#define CL (L_SEQ / NC)           // 16 steps per chunk

typedef __attribute__((ext_vector_type(8))) short bf16x8;
typedef __attribute__((ext_vector_type(4))) float f32x4;
typedef unsigned short ushort_t;

static __device__ __forceinline__ unsigned short f2bf(float f) {
  unsigned int u = __float_as_uint(f);
  unsigned int r = u + 0x7FFF + ((u >> 16) & 1);   // round-to-nearest-even
  return (unsigned short)(r >> 16);
}
static __device__ __forceinline__ float bf2f(ushort_t s) {
  return __uint_as_float(((unsigned int)s) << 16);
}
static __device__ __forceinline__ unsigned int pack2(float a, float b) {
  return (unsigned int)f2bf(a) | ((unsigned int)f2bf(b) << 16);
}

// ====== K1: proj GEMM (inline f32->bf16 staging) + weight conversions ======
// blocks 0..255: 128x64 GEMM tile of proj = x @ W_in^T, split skipb|praw.
// blocks 256..415: convert W_bc/W_lam/W_out to bf16 (for later kernels).
__global__ __launch_bounds__(256) void projcvt(
    const float* __restrict__ x, const float* __restrict__ wi,
    const float* __restrict__ wbc, const float* __restrict__ wl,
    const float* __restrict__ wo,
    ushort_t* __restrict__ wbcb, ushort_t* __restrict__ wlb,
    ushort_t* __restrict__ wob,
    float* __restrict__ skipb, float* __restrict__ praw) {
  const int bid = blockIdx.x;
  const int tid = threadIdx.x;
  if (bid >= 256) {                 // ---- converter blocks ----
    int vb = bid - 256;
    const float* src; ushort_t* dst; int off;
    if (vb < 32)      { src = wbc; dst = wbcb; off = vb; }
    else if (vb < 96) { src = wl;  dst = wlb;  off = vb - 32; }
    else              { src = wo;  dst = wob;  off = vb - 96; }
    size_t i = (size_t)off * 1024 + tid * 4;
    float4 v = *reinterpret_cast<const float4*>(&src[i]);
    ushort4 o;
    o.x = f2bf(v.x); o.y = f2bf(v.y); o.z = f2bf(v.z); o.w = f2bf(v.w);
    *reinterpret_cast<ushort4*>(&dst[i]) = o;
    return;
  }
  // ---- GEMM block ----
  __shared__ __align__(16) ushort_t As[128][72];
  __shared__ __align__(16) ushort_t Ws[64][72];
  const int lane = tid & 63;
  const int w = tid >> 6;
  const int wm = w >> 1;
  const int wn = w & 1;
  const int bn = (bid & 7) * 64;
  const int bm = (bid >> 3) * 128;
  const int r0 = tid >> 3;          // 0..31
  const int c8 = (tid & 7) * 8;     // f32/bf16 column offset

  f32x4 acc[4][2];
  #pragma unroll
  for (int i = 0; i < 4; ++i)
    #pragma unroll
    for (int j = 0; j < 2; ++j)
      acc[i][j] = (f32x4){0.f, 0.f, 0.f, 0.f};

  const int row16 = lane & 15;

  for (int k0 = 0; k0 < 256; k0 += 64) {
    #pragma unroll
    for (int p = 0; p < 4; ++p) {
      int r = r0 + p * 32;
      const float* src = &x[(size_t)(bm + r) * 256 + k0 + c8];
      float4 v0 = *reinterpret_cast<const float4*>(src);
      float4 v1 = *reinterpret_cast<const float4*>(src + 4);
      uint4 o;
      o.x = pack2(v0.x, v0.y); o.y = pack2(v0.z, v0.w);
      o.z = pack2(v1.x, v1.y); o.w = pack2(v1.z, v1.w);
      *reinterpret_cast<uint4*>(&As[r][c8]) = o;
    }
    #pragma unroll
    for (int p = 0; p < 2; ++p) {
      int r = r0 + p * 32;
      const float* src = &wi[(size_t)(bn + r) * 256 + k0 + c8];
      float4 v0 = *reinterpret_cast<const float4*>(src);
      float4 v1 = *reinterpret_cast<const float4*>(src + 4);
      uint4 o;
      o.x = pack2(v0.x, v0.y); o.y = pack2(v0.z, v0.w);
      o.z = pack2(v1.x, v1.y); o.w = pack2(v1.z, v1.w);
      *reinterpret_cast<uint4*>(&Ws[r][c8]) = o;
    }
    __syncthreads();
    #pragma unroll
    for (int ks = 0; ks < 2; ++ks) {
      const int ko = ks * 32 + (lane >> 4) * 8;
      bf16x8 af[4], bfr[2];
      #pragma unroll
      for (int i = 0; i < 4; ++i)
        af[i] = *reinterpret_cast<const bf16x8*>(&As[wm * 64 + i * 16 + row16][ko]);
      #pragma unroll
      for (int j = 0; j < 2; ++j)
        bfr[j] = *reinterpret_cast<const bf16x8*>(&Ws[wn * 32 + j * 16 + row16][ko]);
      #pragma unroll
      for (int i = 0; i < 4; ++i)
        #pragma unroll
        for (int j = 0; j < 2; ++j)
          acc[i][j] = __builtin_amdgcn_mfma_f32_16x16x32_bf16(af[i], bfr[j], acc[i][j], 0, 0, 0);
    }
    __syncthreads();
  }

  const int cl = lane & 15;
  const int rg = lane >> 4;
  #pragma unroll
  for (int j = 0; j < 2; ++j) {
    const int col = bn + wn * 32 + j * 16 + cl;
    float* dst = (col < 256) ? skipb : praw;
    const int cc = col & 255;
    #pragma unroll
    for (int i = 0; i < 4; ++i) {
      const int rbase = bm + wm * 64 + i * 16 + rg * 4;
      #pragma unroll
      for (int rr = 0; rr < 4; ++rr)
        dst[(size_t)(rbase + rr) * 256 + cc] = acc[i][j][rr];
    }
  }
}

// ====== K2: depthwise conv (into LDS) + bc|lambda GEMM ======================
// grid 192 = 6 bn-tiles x 32 bm-panels. Conv computes u for the block's
// 128-row panel into LDS (bf16, full K=256), GEMM reads A-fragments from it.
__global__ __launch_bounds__(256) void convbclam(
    const float* __restrict__ praw, const float* __restrict__ cw,
    const float* __restrict__ cb,
    const ushort_t* __restrict__ wbcb, const ushort_t* __restrict__ wlb,
    const float* __restrict__ b_bc, const float* __restrict__ b_lam,
    const float* __restrict__ Avec,
    float* __restrict__ bcb, float* __restrict__ lamb, float* __restrict__ uwb) {
  __shared__ __align__(16) ushort_t Us[128][264];   // 67.6 KB: u bf16, K=256+8 pad
  __shared__ __align__(16) ushort_t Ws[64][72];     // 9.2 KB
  const int tid = threadIdx.x;
  const int lane = tid & 63;
  const int w = tid >> 6;
  const int wm = w >> 1;
  const int wn = w & 1;
  const int bid = blockIdx.x;
  const int bn = (bid % 6) * 64;     // 0..383 (bc: 0-127, lambda: 128-383)
  const int bm = (bid / 6) * 128;

  // ---- conv: thread d handles column d over rows bm..bm+127 ----
  {
    const int d = tid;
    const float4 w4 = *reinterpret_cast<const float4*>(&cw[d * 4]);
    const float bias = cb[d];
    const bool edge = (bm & 2047) == 0;   // batch boundary (bm==0 or 2048)
    float p0 = edge ? 0.f : praw[(size_t)(bm - 3) * 256 + d];
    float p1 = edge ? 0.f : praw[(size_t)(bm - 2) * 256 + d];
    float p2 = edge ? 0.f : praw[(size_t)(bm - 1) * 256 + d];
    #pragma unroll 8
    for (int r = 0; r < 128; ++r) {
      float p3 = praw[(size_t)(bm + r) * 256 + d];
      float u = bias + w4.x * p0 + w4.y * p1 + w4.z * p2 + w4.w * p3;
      Us[r][d] = f2bf(u);
      p0 = p1; p1 = p2; p2 = p3;
    }
  }
  __syncthreads();

  const ushort_t* Wsrc = (bn < 128) ? (wbcb + (size_t)bn * 256)
                                    : (wlb + (size_t)(bn - 128) * 256);
  const int r0 = tid >> 3;
  const int c8 = (tid & 7) * 8;
  const int row16 = lane & 15;

  f32x4 acc[4][2];
  #pragma unroll
  for (int i = 0; i < 4; ++i)
    #pragma unroll
    for (int j = 0; j < 2; ++j)
      acc[i][j] = (f32x4){0.f, 0.f, 0.f, 0.f};

  for (int k0 = 0; k0 < 256; k0 += 64) {
    #pragma unroll
    for (int p = 0; p < 2; ++p) {
      int r = r0 + p * 32;
      uint4 v = *reinterpret_cast<const uint4*>(&Wsrc[(size_t)r * 256 + k0 + c8]);
      *reinterpret_cast<uint4*>(&Ws[r][c8]) = v;
    }
    __syncthreads();
    #pragma unroll
    for (int ks = 0; ks < 2; ++ks) {
      const int ko = ks * 32 + (lane >> 4) * 8;
      bf16x8 af[4], bfr[2];
      #pragma unroll
      for (int i = 0; i < 4; ++i)
        af[i] = *reinterpret_cast<const bf16x8*>(&Us[wm * 64 + i * 16 + row16][k0 + ko]);
      #pragma unroll
      for (int j = 0; j < 2; ++j)
        bfr[j] = *reinterpret_cast<const bf16x8*>(&Ws[wn * 32 + j * 16 + row16][ko]);
      #pragma unroll
      for (int i = 0; i < 4; ++i)
        #pragma unroll
        for (int j = 0; j < 2; ++j)
          acc[i][j] = __builtin_amdgcn_mfma_f32_16x16x32_bf16(af[i], bfr[j], acc[i][j], 0, 0, 0);
    }
    __syncthreads();
  }

  // ---- epilogue: bc (col<128) | lambda (col>=128) ----
  const int cl = lane & 15;
  const int rg = lane >> 4;
  #pragma unroll
  for (int j = 0; j < 2; ++j) {
    const int col = bn + wn * 32 + j * 16 + cl;
    if (col < 128) {
      const float bv = b_bc[col];
      #pragma unroll
      for (int i = 0; i < 4; ++i) {
        const int rbase = bm + wm * 64 + i * 16 + rg * 4;
        #pragma unroll
        for (int rr = 0; rr < 4; ++rr)
          bcb[(size_t)(rbase + rr) * 128 + col] = acc[i][j][rr] + bv;
      }
    } else {
      const int dd = col - 128;
      const float bv = b_lam[dd];
      const float adg = -8.f * log1pf(__expf(Avec[dd]));
      #pragma unroll
      for (int i = 0; i < 4; ++i) {
        const int rbase = bm + wm * 64 + i * 16 + rg * 4;
        #pragma unroll
        for (int rr = 0; rr < 4; ++rr) {
          const int row = rbase + rr;
          float v = acc[i][j][rr] + bv;
          float s = 1.f / (1.f + __expf(-v));
          float lam = __expf(s * adg);
          float wq = sqrtf(1.f + 1e-6f - lam * lam);
          float u = bf2f(Us[row - bm][dd]);
          lamb[(size_t)row * 256 + dd] = lam;
          uwb[(size_t)row * 256 + dd] = u * wq;
        }
      }
    }
  }
}

// ---- scan pass A: grid = B*NC*4 (d-quarters), 4 waves = 4 n-groups -------
__global__ __launch_bounds__(256) void passA(
    const float* __restrict__ lamb, const float* __restrict__ uwb,
    const float* __restrict__ bcb, float* __restrict__ Pc,
    ushort_t* __restrict__ Hc, float* __restrict__ ybuf) {
  const int bx = blockIdx.x;
  const int dq = bx & 3;
  const int c = (bx >> 2) & (NC - 1);
  const int b = bx >> 9;
  const int lane = threadIdx.x & 63;
  const int ng = threadIdx.x >> 6;       // wave id = n-group
  const int dd = dq * 64 + lane;
  __shared__ __align__(16) float bcs[CL][128];    // 8 KB
  __shared__ __align__(16) float lam_s[CL][64];   // 4 KB
  __shared__ __align__(16) float uw_s[CL][64];    // 4 KB
  __shared__ float ypar[CL][4][64];               // 16 KB
  {
    const float4* src = reinterpret_cast<const float4*>(
        bcb + (size_t)(b * L_SEQ + c * CL) * 128);
    float4* dst = reinterpret_cast<float4*>(&bcs[0][0]);
    dst[threadIdx.x] = src[threadIdx.x];
    dst[threadIdx.x + 256] = src[threadIdx.x + 256];
    const int ts = threadIdx.x >> 4, qs = threadIdx.x & 15;
    size_t rowb = (size_t)(b * L_SEQ + c * CL + ts) * 256 + dq * 64 + qs * 4;
    *reinterpret_cast<float4*>(&lam_s[ts][qs * 4]) =
        *reinterpret_cast<const float4*>(&lamb[rowb]);
    *reinterpret_cast<float4*>(&uw_s[ts][qs * 4]) =
        *reinterpret_cast<const float4*>(&uwb[rowb]);
  }
  __syncthreads();
  float H[16];
  #pragma unroll
  for (int j = 0; j < 16; ++j) H[j] = 0.f;
  float P = 1.f;
  const size_t base0 = (size_t)(b * L_SEQ + c * CL) * 256 + dd;
  #pragma unroll 4
  for (int t = 0; t < CL; ++t) {
    float lam = lam_s[t][lane];
    float uw = uw_s[t][lane];
    P *= lam;
    float yp = 0.f;
    const float4* btv = reinterpret_cast<const float4*>(&bcs[t][ng * 16]);
    const float4* ctv = reinterpret_cast<const float4*>(&bcs[t][64 + ng * 16]);
    #pragma unroll
    for (int q = 0; q < 4; ++q) {
      float4 b4 = btv[q];
      float4 c4 = ctv[q];
      H[q * 4 + 0] = lam * H[q * 4 + 0] + b4.x * uw; yp += c4.x * H[q * 4 + 0];
      H[q * 4 + 1] = lam * H[q * 4 + 1] + b4.y * uw; yp += c4.y * H[q * 4 + 1];
      H[q * 4 + 2] = lam * H[q * 4 + 2] + b4.z * uw; yp += c4.z * H[q * 4 + 2];
      H[q * 4 + 3] = lam * H[q * 4 + 3] + b4.w * uw; yp += c4.w * H[q * 4 + 3];
    }
    ypar[t][ng][lane] = yp;
  }
  if (ng == 0) Pc[(size_t)(b * NC + c) * 256 + dd] = P;
  #pragma unroll
  for (int j = 0; j < 16; ++j)
    Hc[((size_t)(b * NC + c) * 64 + ng * 16 + j) * 256 + dd] = f2bf(H[j]);
  __syncthreads();
  #pragma unroll
  for (int tt = 0; tt < 4; ++tt) {
    int t = ng * 4 + tt;
    float y = ypar[t][0][lane] + ypar[t][1][lane] +
              ypar[t][2][lane] + ypar[t][3][lane];
    ybuf[base0 + (size_t)t * 256] = y;
  }
}

// ---- sequential chunk scan, pipelined unroll-16 (hin in-place, bf16) ------
__global__ __launch_bounds__(128) void chunkscan(
    const float* __restrict__ Pc, ushort_t* __restrict__ Hc) {
  int tid = blockIdx.x * 128 + threadIdx.x;   // 32768 = B*N*D
  int d = tid & 255;
  int j = (tid >> 8) & 63;
  int b = tid >> 14;
  const size_t hstride = (size_t)N_DIM * 256;
  const size_t ihb = ((size_t)(b * NC) * 64 + j) * 256 + d;
  const size_t ipb = (size_t)(b * NC) * 256 + d;
  float h = 0.f;
  float Hv[16], Pv[16];
  #pragma unroll
  for (int q = 0; q < 16; ++q) {
    Hv[q] = bf2f(Hc[ihb + (size_t)q * hstride]);
    Pv[q] = Pc[ipb + (size_t)q * 256];
  }
  #pragma unroll 1
  for (int c0 = 0; c0 < NC; c0 += 16) {
    float Hn[16], Pn[16];
    if (c0 + 16 < NC) {
      #pragma unroll
      for (int q = 0; q < 16; ++q) {
        Hn[q] = bf2f(Hc[ihb + (size_t)(c0 + 16 + q) * hstride]);
        Pn[q] = Pc[ipb + (size_t)(c0 + 16 + q) * 256];
      }
    }
    #pragma unroll
    for (int q = 0; q < 16; ++q) {
      Hc[ihb + (size_t)(c0 + q) * hstride] = f2bf(h);
      h = fmaf(Pv[q], h, Hv[q]);
    }
    #pragma unroll
    for (int q = 0; q < 16; ++q) { Hv[q] = Hn[q]; Pv[q] = Pn[q]; }
  }
}

// ---- scan pass B + GELU gate; lam prefix from LDS; writes bf16 g ----------
__global__ __launch_bounds__(256) void passB_gelu(
    const float* __restrict__ lamb, const float* __restrict__ bcb,
    const ushort_t* __restrict__ hin, const float* __restrict__ skipb,
    const float* __restrict__ ybuf, ushort_t* __restrict__ gbf) {
  const int bx = blockIdx.x;
  const int dq = bx & 3;
  const int c = (bx >> 2) & (NC - 1);
  const int b = bx >> 9;
  const int lane = threadIdx.x & 63;
  const int ng = threadIdx.x >> 6;
  const int dd = dq * 64 + lane;
  __shared__ __align__(16) float cs[CL][64];      // 4 KB
  __shared__ __align__(16) float lam_s[CL][64];   // 4 KB
  __shared__ float spar[CL][4][64];               // 16 KB
  {
    int t0 = threadIdx.x >> 4;
    int jq = threadIdx.x & 15;
    *reinterpret_cast<float4*>(&cs[t0][jq * 4]) =
        *reinterpret_cast<const float4*>(
            bcb + (size_t)(b * L_SEQ + c * CL + t0) * 128 + 64 + jq * 4);
    size_t rowb = (size_t)(b * L_SEQ + c * CL + t0) * 256 + dq * 64 + jq * 4;
    *reinterpret_cast<float4*>(&lam_s[t0][jq * 4]) =
        *reinterpret_cast<const float4*>(&lamb[rowb]);
  }
  float h16[16];
  #pragma unroll
  for (int j = 0; j < 16; ++j)
    h16[j] = bf2f(hin[((size_t)(b * NC + c) * 64 + ng * 16 + j) * 256 + dd]);
  __syncthreads();
  const size_t base0 = (size_t)(b * L_SEQ + c * CL) * 256 + dd;
  #pragma unroll 4
  for (int t = 0; t < CL; ++t) {
    float S = 0.f;
    const float4* ctv = reinterpret_cast<const float4*>(&cs[t][ng * 16]);
    #pragma unroll
    for (int q = 0; q < 4; ++q) {
      float4 c4 = ctv[q];
      S += c4.x * h16[q * 4 + 0] + c4.y * h16[q * 4 + 1] +
           c4.z * h16[q * 4 + 2] + c4.w * h16[q * 4 + 3];
    }
    spar[t][ng][lane] = S;
  }
  __syncthreads();
  float Pp = 1.f;
  #pragma unroll
  for (int tau = 0; tau < 12; ++tau)
    if (tau < ng * 4) Pp *= lam_s[tau][lane];
  #pragma unroll
  for (int tt = 0; tt < 4; ++tt) {
    int t = ng * 4 + tt;
    Pp *= lam_s[t][lane];
    float S4 = spar[t][0][lane] + spar[t][1][lane] +
               spar[t][2][lane] + spar[t][3][lane];
    float y = ybuf[base0 + (size_t)t * 256] + Pp * S4;
    float sk = skipb[base0 + (size_t)t * 256];
    float g = 0.5f * sk * (1.f + erff(sk * 0.70710678118f));
    gbf[base0 + (size_t)t * 256] = f2bf(g * y);
  }
}

// ====== K6: out = g @ W_out^T, 64x64 tiles (256 blocks, coalesced staging) ==
__global__ __launch_bounds__(256) void mgemm64(
    const ushort_t* __restrict__ Ag, const ushort_t* __restrict__ Wg,
    float* __restrict__ C) {
  __shared__ __align__(16) ushort_t As[64][72];
  __shared__ __align__(16) ushort_t Ws[64][72];
  const int tid = threadIdx.x;
  const int lane = tid & 63;
  const int w = tid >> 6;
  const int wm = w >> 1;
  const int wn = w & 1;
  const int bn = blockIdx.x * 64;
  const int bm = blockIdx.y * 64;
  const int r0 = tid >> 3;
  const int c8 = (tid & 7) * 8;
  const int row16 = lane & 15;

  f32x4 acc[2][2];
  #pragma unroll
  for (int i = 0; i < 2; ++i)
    #pragma unroll
    for (int j = 0; j < 2; ++j)
      acc[i][j] = (f32x4){0.f, 0.f, 0.f, 0.f};

  for (int k0 = 0; k0 < 256; k0 += 64) {
    #pragma unroll
    for (int p = 0; p < 2; ++p) {
      int r = r0 + p * 32;
      *reinterpret_cast<uint4*>(&As[r][c8]) =
          *reinterpret_cast<const uint4*>(&Ag[(size_t)(bm + r) * 256 + k0 + c8]);
      *reinterpret_cast<uint4*>(&Ws[r][c8]) =
          *reinterpret_cast<const uint4*>(&Wg[(size_t)(bn + r) * 256 + k0 + c8]);
    }
    __syncthreads();
    #pragma unroll
    for (int ks = 0; ks < 2; ++ks) {
      const int ko = ks * 32 + (lane >> 4) * 8;
      bf16x8 af[2], bfr[2];
      #pragma unroll
      for (int i = 0; i < 2; ++i)
        af[i] = *reinterpret_cast<const bf16x8*>(&As[wm * 32 + i * 16 + row16][ko]);
      #pragma unroll
      for (int j = 0; j < 2; ++j)
        bfr[j] = *reinterpret_cast<const bf16x8*>(&Ws[wn * 32 + j * 16 + row16][ko]);
      #pragma unroll
      for (int i = 0; i < 2; ++i)
        #pragma unroll
        for (int j = 0; j < 2; ++j)
          acc[i][j] = __builtin_amdgcn_mfma_f32_16x16x32_bf16(af[i], bfr[j], acc[i][j], 0, 0, 0);
    }
    __syncthreads();
  }

  const int cl = lane & 15;
  const int rg = lane >> 4;
  #pragma unroll
  for (int j = 0; j < 2; ++j) {
    const int col = bn + wn * 32 + j * 16 + cl;
    #pragma unroll
    for (int i = 0; i < 2; ++i) {
      const int rbase = bm + wm * 32 + i * 16 + rg * 4;
      #pragma unroll
      for (int rr = 0; rr < 4; ++rr)
        C[(size_t)(rbase + rr) * 256 + col] = acc[i][j][rr];
    }
  }
}

extern "C" void kernel_launch(void* const* d_in, const int* in_sizes, int n_in,
                              void* d_out, int out_size, void* d_ws, size_t ws_size,
                              hipStream_t stream) {
  const float* x      = (const float*)d_in[0];
  const float* W_in   = (const float*)d_in[1];
  const float* conv_w = (const float*)d_in[2];
  const float* conv_b = (const float*)d_in[3];
  const float* W_bc   = (const float*)d_in[4];
  const float* b_bc   = (const float*)d_in[5];
  const float* W_lam  = (const float*)d_in[6];
  const float* b_lam  = (const float*)d_in[7];
  const float* A      = (const float*)d_in[8];
  const float* W_out  = (const float*)d_in[9];
  float* out = (float*)d_out;

  float* ws = (float*)d_ws;
  float* skipb = ws;                        // 1,048,576
  float* praw  = ws + 1048576;              // 1,048,576
  float* lamb  = ws + 2097152;              // 1,048,576
  float* uwb   = ws + 3145728;              // 1,048,576
  float* bcb   = ws + 4194304;              //   524,288
  float* ybuf  = ws + 4718592;              // 1,048,576
  float* Pc    = ws + 5767168;              //    65,536
  ushort_t* Hc = (ushort_t*)(ws + 5832704); // 4,194,304 shorts (bf16)
  ushort_t* wbcb = (ushort_t*)(ws + 7929856);   //    32,768 shorts
  ushort_t* wlb  = (ushort_t*)(ws + 7946240);   //    65,536 shorts
  ushort_t* wob  = (ushort_t*)(ws + 7979008);   //    65,536 shorts
  ushort_t* gbf  = (ushort_t*)(ws + 8011776);   // 1,048,576 shorts
  // end: 8,536,064 floats ~ 34.1 MB

  // 1) proj GEMM (inline cvt) + weight conversions      [416 blocks]
  projcvt<<<dim3(416), dim3(256), 0, stream>>>(
      x, W_in, W_bc, W_lam, W_out, wbcb, wlb, wob, skipb, praw);
  // 2) conv (LDS) + fused bc|lambda GEMM                [192 blocks]
  convbclam<<<dim3(192), dim3(256), 0, stream>>>(
      praw, conv_w, conv_b, wbcb, wlb, b_bc, b_lam, A, bcb, lamb, uwb);
  // 3) chunk-local scan                                 [1024 blocks]
  passA<<<dim3(B_DIM * NC * 4), dim3(256), 0, stream>>>(lamb, uwb, bcb, Pc, Hc, ybuf);
  // 4) chunk-prefix scan                                [256 blocks]
  chunkscan<<<dim3(256), dim3(128), 0, stream>>>(Pc, Hc);
  // 5) cross-chunk correction + gelu gate -> bf16 g     [1024 blocks]
  passB_gelu<<<dim3(B_DIM * NC * 4), dim3(256), 0, stream>>>(
      lamb, bcb, Hc, skipb, ybuf, gbf);
  // 6) out = g @ W_out^T                                [256 blocks]
  mgemm64<<<dim3(4, 64), dim3(256), 0, stream>>>(gbf, wob, out);
}

// Round 11
// 65.435 us; speedup vs baseline: 7.2492x; 1.0627x over previous
//
#include <hip/hip_runtime.h>
#include <hip/hip_bf16.h>
#include <math.h>

// Problem constants
#define B_DIM 2
#define L_SEQ 2048
#define D_DIM 256
#define N_DIM 64
#define K_CONV 4
#define M_ROWS (B_DIM * L_SEQ)   // 4096
#define NC 64                     // number of scan chunks
#define CL (L_SEQ / NC)           // 32 steps per chunk

typedef __attribute__((ext_vector_type(8))) short bf16x8;
typedef __attribute__((ext_vector_type(4))) float f32x4;
typedef unsigned short ushort_t;

static __device__ __forceinline__ unsigned short f2bf(float f) {
  unsigned int u = __float_as_uint(f);
  unsigned int r = u + 0x7FFF + ((u >> 16) & 1);   // round-to-nearest-even
  return (unsigned short)(r >> 16);
}
static __device__ __forceinline__ float bf2f(ushort_t s) {
  return __uint_as_float(((unsigned int)s) << 16);
}
static __device__ __forceinline__ unsigned int pack2(float a, float b) {
  return (unsigned int)f2bf(a) | ((unsigned int)f2bf(b) << 16);
}

// ====== K1: proj GEMM (inline f32->bf16 staging) + weight conversions ======
// blocks 0..255: 128x64 GEMM tile of proj = x @ W_in^T -> bf16 skipb | praw.
// blocks 256..415: convert W_bc/W_lam/W_out to bf16.
__global__ __launch_bounds__(256) void projcvt(
    const float* __restrict__ x, const float* __restrict__ wi,
    const float* __restrict__ wbc, const float* __restrict__ wl,
    const float* __restrict__ wo,
    ushort_t* __restrict__ wbcb, ushort_t* __restrict__ wlb,
    ushort_t* __restrict__ wob,
    ushort_t* __restrict__ skipb, ushort_t* __restrict__ praw) {
  const int bid = blockIdx.x;
  const int tid = threadIdx.x;
  if (bid >= 256) {                 // ---- converter blocks ----
    int vb = bid - 256;
    const float* src; ushort_t* dst; int off;
    if (vb < 32)      { src = wbc; dst = wbcb; off = vb; }
    else if (vb < 96) { src = wl;  dst = wlb;  off = vb - 32; }
    else              { src = wo;  dst = wob;  off = vb - 96; }
    size_t i = (size_t)off * 1024 + tid * 4;
    float4 v = *reinterpret_cast<const float4*>(&src[i]);
    ushort4 o;
    o.x = f2bf(v.x); o.y = f2bf(v.y); o.z = f2bf(v.z); o.w = f2bf(v.w);
    *reinterpret_cast<ushort4*>(&dst[i]) = o;
    return;
  }
  // ---- GEMM block ----
  __shared__ __align__(16) ushort_t As[128][72];
  __shared__ __align__(16) ushort_t Ws[64][72];
  const int lane = tid & 63;
  const int w = tid >> 6;
  const int wm = w >> 1;
  const int wn = w & 1;
  const int bn = (bid & 7) * 64;
  const int bm = (bid >> 3) * 128;
  const int r0 = tid >> 3;          // 0..31
  const int c8 = (tid & 7) * 8;

  f32x4 acc[4][2];
  #pragma unroll
  for (int i = 0; i < 4; ++i)
    #pragma unroll
    for (int j = 0; j < 2; ++j)
      acc[i][j] = (f32x4){0.f, 0.f, 0.f, 0.f};

  const int row16 = lane & 15;

  for (int k0 = 0; k0 < 256; k0 += 64) {
    #pragma unroll
    for (int p = 0; p < 4; ++p) {
      int r = r0 + p * 32;
      const float* src = &x[(size_t)(bm + r) * 256 + k0 + c8];
      float4 v0 = *reinterpret_cast<const float4*>(src);
      float4 v1 = *reinterpret_cast<const float4*>(src + 4);
      uint4 o;
      o.x = pack2(v0.x, v0.y); o.y = pack2(v0.z, v0.w);
      o.z = pack2(v1.x, v1.y); o.w = pack2(v1.z, v1.w);
      *reinterpret_cast<uint4*>(&As[r][c8]) = o;
    }
    #pragma unroll
    for (int p = 0; p < 2; ++p) {
      int r = r0 + p * 32;
      const float* src = &wi[(size_t)(bn + r) * 256 + k0 + c8];
      float4 v0 = *reinterpret_cast<const float4*>(src);
      float4 v1 = *reinterpret_cast<const float4*>(src + 4);
      uint4 o;
      o.x = pack2(v0.x, v0.y); o.y = pack2(v0.z, v0.w);
      o.z = pack2(v1.x, v1.y); o.w = pack2(v1.z, v1.w);
      *reinterpret_cast<uint4*>(&Ws[r][c8]) = o;
    }
    __syncthreads();
    #pragma unroll
    for (int ks = 0; ks < 2; ++ks) {
      const int ko = ks * 32 + (lane >> 4) * 8;
      bf16x8 af[4], bfr[2];
      #pragma unroll
      for (int i = 0; i < 4; ++i)
        af[i] = *reinterpret_cast<const bf16x8*>(&As[wm * 64 + i * 16 + row16][ko]);
      #pragma unroll
      for (int j = 0; j < 2; ++j)
        bfr[j] = *reinterpret_cast<const bf16x8*>(&Ws[wn * 32 + j * 16 + row16][ko]);
      #pragma unroll
      for (int i = 0; i < 4; ++i)
        #pragma unroll
        for (int j = 0; j < 2; ++j)
          acc[i][j] = __builtin_amdgcn_mfma_f32_16x16x32_bf16(af[i], bfr[j], acc[i][j], 0, 0, 0);
    }
    __syncthreads();
  }

  const int cl = lane & 15;
  const int rg = lane >> 4;
  #pragma unroll
  for (int j = 0; j < 2; ++j) {
    const int col = bn + wn * 32 + j * 16 + cl;
    ushort_t* dst = (col < 256) ? skipb : praw;
    const int cc = col & 255;
    #pragma unroll
    for (int i = 0; i < 4; ++i) {
      const int rbase = bm + wm * 64 + i * 16 + rg * 4;
      #pragma unroll
      for (int rr = 0; rr < 4; ++rr)
        dst[(size_t)(rbase + rr) * 256 + cc] = f2bf(acc[i][j][rr]);
    }
  }
}

// ====== K2: depthwise conv (into LDS) + bc|lambda GEMM ======================
__global__ __launch_bounds__(256) void convbclam(
    const ushort_t* __restrict__ praw, const float* __restrict__ cw,
    const float* __restrict__ cb,
    const ushort_t* __restrict__ wbcb, const ushort_t* __restrict__ wlb,
    const float* __restrict__ b_bc, const float* __restrict__ b_lam,
    const float* __restrict__ Avec,
    ushort_t* __restrict__ bcbf, float* __restrict__ lamb,
    ushort_t* __restrict__ uwb) {
  __shared__ __align__(16) ushort_t Us[128][264];   // 67.6 KB
  __shared__ __align__(16) ushort_t Ws[64][72];
  const int tid = threadIdx.x;
  const int lane = tid & 63;
  const int w = tid >> 6;
  const int wm = w >> 1;
  const int wn = w & 1;
  const int bid = blockIdx.x;
  const int bn = (bid % 6) * 64;
  const int bm = (bid / 6) * 128;

  // ---- conv: thread d handles column d over rows bm..bm+127 ----
  {
    const int d = tid;
    const float4 w4 = *reinterpret_cast<const float4*>(&cw[d * 4]);
    const float bias = cb[d];
    const bool edge = (bm & 2047) == 0;
    float p0 = edge ? 0.f : bf2f(praw[(size_t)(bm - 3) * 256 + d]);
    float p1 = edge ? 0.f : bf2f(praw[(size_t)(bm - 2) * 256 + d]);
    float p2 = edge ? 0.f : bf2f(praw[(size_t)(bm - 1) * 256 + d]);
    #pragma unroll 8
    for (int r = 0; r < 128; ++r) {
      float p3 = bf2f(praw[(size_t)(bm + r) * 256 + d]);
      float u = bias + w4.x * p0 + w4.y * p1 + w4.z * p2 + w4.w * p3;
      Us[r][d] = f2bf(u);
      p0 = p1; p1 = p2; p2 = p3;
    }
  }
  __syncthreads();

  const ushort_t* Wsrc = (bn < 128) ? (wbcb + (size_t)bn * 256)
                                    : (wlb + (size_t)(bn - 128) * 256);
  const int r0 = tid >> 3;
  const int c8 = (tid & 7) * 8;
  const int row16 = lane & 15;

  f32x4 acc[4][2];
  #pragma unroll
  for (int i = 0; i < 4; ++i)
    #pragma unroll
    for (int j = 0; j < 2; ++j)
      acc[i][j] = (f32x4){0.f, 0.f, 0.f, 0.f};

  for (int k0 = 0; k0 < 256; k0 += 64) {
    #pragma unroll
    for (int p = 0; p < 2; ++p) {
      int r = r0 + p * 32;
      uint4 v = *reinterpret_cast<const uint4*>(&Wsrc[(size_t)r * 256 + k0 + c8]);
      *reinterpret_cast<uint4*>(&Ws[r][c8]) = v;
    }
    __syncthreads();
    #pragma unroll
    for (int ks = 0; ks < 2; ++ks) {
      const int ko = ks * 32 + (lane >> 4) * 8;
      bf16x8 af[4], bfr[2];
      #pragma unroll
      for (int i = 0; i < 4; ++i)
        af[i] = *reinterpret_cast<const bf16x8*>(&Us[wm * 64 + i * 16 + row16][k0 + ko]);
      #pragma unroll
      for (int j = 0; j < 2; ++j)
        bfr[j] = *reinterpret_cast<const bf16x8*>(&Ws[wn * 32 + j * 16 + row16][ko]);
      #pragma unroll
      for (int i = 0; i < 4; ++i)
        #pragma unroll
        for (int j = 0; j < 2; ++j)
          acc[i][j] = __builtin_amdgcn_mfma_f32_16x16x32_bf16(af[i], bfr[j], acc[i][j], 0, 0, 0);
    }
    __syncthreads();
  }

  const int cl = lane & 15;
  const int rg = lane >> 4;
  #pragma unroll
  for (int j = 0; j < 2; ++j) {
    const int col = bn + wn * 32 + j * 16 + cl;
    if (col < 128) {
      const float bv = b_bc[col];
      #pragma unroll
      for (int i = 0; i < 4; ++i) {
        const int rbase = bm + wm * 64 + i * 16 + rg * 4;
        #pragma unroll
        for (int rr = 0; rr < 4; ++rr)
          bcbf[(size_t)(rbase + rr) * 128 + col] = f2bf(acc[i][j][rr] + bv);
      }
    } else {
      const int dd = col - 128;
      const float bv = b_lam[dd];
      const float adg = -8.f * log1pf(__expf(Avec[dd]));
      #pragma unroll
      for (int i = 0; i < 4; ++i) {
        const int rbase = bm + wm * 64 + i * 16 + rg * 4;
        #pragma unroll
        for (int rr = 0; rr < 4; ++rr) {
          const int row = rbase + rr;
          float v = acc[i][j][rr] + bv;
          float s = 1.f / (1.f + __expf(-v));
          float lam = __expf(s * adg);
          float wq = sqrtf(1.f + 1e-6f - lam * lam);
          float u = bf2f(Us[row - bm][dd]);
          lamb[(size_t)row * 256 + dd] = lam;
          uwb[(size_t)row * 256 + dd] = f2bf(u * wq);
        }
      }
    }
  }
}

// ---- scan pass A: grid = B*NC*4 (d-quarters), 4 waves = 4 n-groups -------
// CL=32; ypar is an 8-deep ring reduced per segment.
__global__ __launch_bounds__(256) void passA(
    const float* __restrict__ lamb, const ushort_t* __restrict__ uwb,
    const ushort_t* __restrict__ bcbf, float* __restrict__ Pc,
    ushort_t* __restrict__ Hc, float* __restrict__ ybuf) {
  const int bx = blockIdx.x;
  const int dq = bx & 3;
  const int c = (bx >> 2) & (NC - 1);
  const int b = bx >> 8;
  const int lane = threadIdx.x & 63;
  const int ng = threadIdx.x >> 6;
  const int dd = dq * 64 + lane;
  __shared__ __align__(16) float bcs[CL][128];    // 16 KB
  __shared__ __align__(16) float lam_s[CL][64];   // 8 KB
  __shared__ __align__(16) float uw_s[CL][64];    // 8 KB
  __shared__ float ypar[8][4][64];                // 8 KB
  {
    // stage bc (CL x 128 bf16 -> f32)
    const ushort_t* src = bcbf + (size_t)(b * L_SEQ + c * CL) * 128;
    const int f0 = threadIdx.x * 16;
    bf16x8 v0 = *reinterpret_cast<const bf16x8*>(src + f0);
    bf16x8 v1 = *reinterpret_cast<const bf16x8*>(src + f0 + 8);
    float* dstf = &bcs[0][0] + f0;
    #pragma unroll
    for (int q = 0; q < 2; ++q) {
      bf16x8 v = q ? v1 : v0;
      *reinterpret_cast<float4*>(dstf + q * 8) =
          (float4){bf2f((ushort_t)v[0]), bf2f((ushort_t)v[1]),
                   bf2f((ushort_t)v[2]), bf2f((ushort_t)v[3])};
      *reinterpret_cast<float4*>(dstf + q * 8 + 4) =
          (float4){bf2f((ushort_t)v[4]), bf2f((ushort_t)v[5]),
                   bf2f((ushort_t)v[6]), bf2f((ushort_t)v[7])};
    }
    // stage lam (f32) and uw (bf16 -> f32), 8 elems/thread
    const int ts = threadIdx.x >> 3, qs = threadIdx.x & 7;
    size_t rowb = (size_t)(b * L_SEQ + c * CL + ts) * 256 + dq * 64 + qs * 8;
    *reinterpret_cast<float4*>(&lam_s[ts][qs * 8]) =
        *reinterpret_cast<const float4*>(&lamb[rowb]);
    *reinterpret_cast<float4*>(&lam_s[ts][qs * 8 + 4]) =
        *reinterpret_cast<const float4*>(&lamb[rowb + 4]);
    bf16x8 uv = *reinterpret_cast<const bf16x8*>(uwb + rowb);
    *reinterpret_cast<float4*>(&uw_s[ts][qs * 8]) =
        (float4){bf2f((ushort_t)uv[0]), bf2f((ushort_t)uv[1]),
                 bf2f((ushort_t)uv[2]), bf2f((ushort_t)uv[3])};
    *reinterpret_cast<float4*>(&uw_s[ts][qs * 8 + 4]) =
        (float4){bf2f((ushort_t)uv[4]), bf2f((ushort_t)uv[5]),
                 bf2f((ushort_t)uv[6]), bf2f((ushort_t)uv[7])};
  }
  __syncthreads();
  float H[16];
  #pragma unroll
  for (int j = 0; j < 16; ++j) H[j] = 0.f;
  float P = 1.f;
  const size_t base0 = (size_t)(b * L_SEQ + c * CL) * 256 + dd;
  for (int seg = 0; seg < 4; ++seg) {
    #pragma unroll
    for (int tt = 0; tt < 8; ++tt) {
      const int t = seg * 8 + tt;
      float lam = lam_s[t][lane];
      float uw = uw_s[t][lane];
      P *= lam;
      float yp = 0.f;
      const float4* btv = reinterpret_cast<const float4*>(&bcs[t][ng * 16]);
      const float4* ctv = reinterpret_cast<const float4*>(&bcs[t][64 + ng * 16]);
      #pragma unroll
      for (int q = 0; q < 4; ++q) {
        float4 b4 = btv[q];
        float4 c4 = ctv[q];
        H[q * 4 + 0] = lam * H[q * 4 + 0] + b4.x * uw; yp += c4.x * H[q * 4 + 0];
        H[q * 4 + 1] = lam * H[q * 4 + 1] + b4.y * uw; yp += c4.y * H[q * 4 + 1];
        H[q * 4 + 2] = lam * H[q * 4 + 2] + b4.z * uw; yp += c4.z * H[q * 4 + 2];
        H[q * 4 + 3] = lam * H[q * 4 + 3] + b4.w * uw; yp += c4.w * H[q * 4 + 3];
      }
      ypar[tt][ng][lane] = yp;
    }
    __syncthreads();
    #pragma unroll
    for (int k = 0; k < 2; ++k) {
      const int tt = ng * 2 + k;
      const int t = seg * 8 + tt;
      float y = ypar[tt][0][lane] + ypar[tt][1][lane] +
                ypar[tt][2][lane] + ypar[tt][3][lane];
      ybuf[base0 + (size_t)t * 256] = y;
    }
    __syncthreads();
  }
  if (ng == 0) Pc[(size_t)(b * NC + c) * 256 + dd] = P;
  #pragma unroll
  for (int j = 0; j < 16; ++j)
    Hc[((size_t)(b * NC + c) * 64 + ng * 16 + j) * 256 + dd] = f2bf(H[j]);
}

// ---- sequential chunk scan over NC=64, pipelined unroll-16 ---------------
__global__ __launch_bounds__(128) void chunkscan(
    const float* __restrict__ Pc, ushort_t* __restrict__ Hc) {
  int tid = blockIdx.x * 128 + threadIdx.x;   // 32768 = B*N*D
  int d = tid & 255;
  int j = (tid >> 8) & 63;
  int b = tid >> 14;
  const size_t hstride = (size_t)N_DIM * 256;
  const size_t ihb = ((size_t)(b * NC) * 64 + j) * 256 + d;
  const size_t ipb = (size_t)(b * NC) * 256 + d;
  float h = 0.f;
  float Hv[16], Pv[16];
  #pragma unroll
  for (int q = 0; q < 16; ++q) {
    Hv[q] = bf2f(Hc[ihb + (size_t)q * hstride]);
    Pv[q] = Pc[ipb + (size_t)q * 256];
  }
  #pragma unroll 1
  for (int c0 = 0; c0 < NC; c0 += 16) {
    float Hn[16], Pn[16];
    if (c0 + 16 < NC) {
      #pragma unroll
      for (int q = 0; q < 16; ++q) {
        Hn[q] = bf2f(Hc[ihb + (size_t)(c0 + 16 + q) * hstride]);
        Pn[q] = Pc[ipb + (size_t)(c0 + 16 + q) * 256];
      }
    }
    #pragma unroll
    for (int q = 0; q < 16; ++q) {
      Hc[ihb + (size_t)(c0 + q) * hstride] = f2bf(h);
      h = fmaf(Pv[q], h, Hv[q]);
    }
    #pragma unroll
    for (int q = 0; q < 16; ++q) { Hv[q] = Hn[q]; Pv[q] = Pn[q]; }
  }
}

// ---- scan pass B + GELU gate; CL=32, waves finalize 8 t each --------------
__global__ __launch_bounds__(256) void passB_gelu(
    const float* __restrict__ lamb, const ushort_t* __restrict__ bcbf,
    const ushort_t* __restrict__ hin, const ushort_t* __restrict__ skipb,
    const float* __restrict__ ybuf, ushort_t* __restrict__ gbf) {
  const int bx = blockIdx.x;
  const int dq = bx & 3;
  const int c = (bx >> 2) & (NC - 1);
  const int b = bx >> 8;
  const int lane = threadIdx.x & 63;
  const int ng = threadIdx.x >> 6;
  const int dd = dq * 64 + lane;
  __shared__ __align__(16) float cs[CL][64];      // 8 KB
  __shared__ __align__(16) float lam_s[CL][64];   // 8 KB
  __shared__ float spar[CL][4][64];               // 32 KB
  {
    const int ts = threadIdx.x >> 3, qs = threadIdx.x & 7;
    bf16x8 cv = *reinterpret_cast<const bf16x8*>(
        bcbf + (size_t)(b * L_SEQ + c * CL + ts) * 128 + 64 + qs * 8);
    *reinterpret_cast<float4*>(&cs[ts][qs * 8]) =
        (float4){bf2f((ushort_t)cv[0]), bf2f((ushort_t)cv[1]),
                 bf2f((ushort_t)cv[2]), bf2f((ushort_t)cv[3])};
    *reinterpret_cast<float4*>(&cs[ts][qs * 8 + 4]) =
        (float4){bf2f((ushort_t)cv[4]), bf2f((ushort_t)cv[5]),
                 bf2f((ushort_t)cv[6]), bf2f((ushort_t)cv[7])};
    size_t rowb = (size_t)(b * L_SEQ + c * CL + ts) * 256 + dq * 64 + qs * 8;
    *reinterpret_cast<float4*>(&lam_s[ts][qs * 8]) =
        *reinterpret_cast<const float4*>(&lamb[rowb]);
    *reinterpret_cast<float4*>(&lam_s[ts][qs * 8 + 4]) =
        *reinterpret_cast<const float4*>(&lamb[rowb + 4]);
  }
  float h16[16];
  #pragma unroll
  for (int j = 0; j < 16; ++j)
    h16[j] = bf2f(hin[((size_t)(b * NC + c) * 64 + ng * 16 + j) * 256 + dd]);
  __syncthreads();
  const size_t base0 = (size_t)(b * L_SEQ + c * CL) * 256 + dd;
  #pragma unroll 4
  for (int t = 0; t < CL; ++t) {
    float S = 0.f;
    const float4* ctv = reinterpret_cast<const float4*>(&cs[t][ng * 16]);
    #pragma unroll
    for (int q = 0; q < 4; ++q) {
      float4 c4 = ctv[q];
      S += c4.x * h16[q * 4 + 0] + c4.y * h16[q * 4 + 1] +
           c4.z * h16[q * 4 + 2] + c4.w * h16[q * 4 + 3];
    }
    spar[t][ng][lane] = S;
  }
  __syncthreads();
  float Pp = 1.f;
  #pragma unroll
  for (int tau = 0; tau < 24; ++tau)
    if (tau < ng * 8) Pp *= lam_s[tau][lane];
  #pragma unroll
  for (int tt = 0; tt < 8; ++tt) {
    const int t = ng * 8 + tt;
    Pp *= lam_s[t][lane];
    float S4 = spar[t][0][lane] + spar[t][1][lane] +
               spar[t][2][lane] + spar[t][3][lane];
    float y = ybuf[base0 + (size_t)t * 256] + Pp * S4;
    float sk = bf2f(skipb[base0 + (size_t)t * 256]);
    float g = 0.5f * sk * (1.f + erff(sk * 0.70710678118f));
    gbf[base0 + (size_t)t * 256] = f2bf(g * y);
  }
}

// ====== K6: out = g @ W_out^T, 64x64 tiles ================================
__global__ __launch_bounds__(256) void mgemm64(
    const ushort_t* __restrict__ Ag, const ushort_t* __restrict__ Wg,
    float* __restrict__ C) {
  __shared__ __align__(16) ushort_t As[64][72];
  __shared__ __align__(16) ushort_t Ws[64][72];
  const int tid = threadIdx.x;
  const int lane = tid & 63;
  const int w = tid >> 6;
  const int wm = w >> 1;
  const int wn = w & 1;
  const int bn = blockIdx.x * 64;
  const int bm = blockIdx.y * 64;
  const int r0 = tid >> 3;
  const int c8 = (tid & 7) * 8;
  const int row16 = lane & 15;

  f32x4 acc[2][2];
  #pragma unroll
  for (int i = 0; i < 2; ++i)
    #pragma unroll
    for (int j = 0; j < 2; ++j)
      acc[i][j] = (f32x4){0.f, 0.f, 0.f, 0.f};

  for (int k0 = 0; k0 < 256; k0 += 64) {
    #pragma unroll
    for (int p = 0; p < 2; ++p) {
      int r = r0 + p * 32;
      *reinterpret_cast<uint4*>(&As[r][c8]) =
          *reinterpret_cast<const uint4*>(&Ag[(size_t)(bm + r) * 256 + k0 + c8]);
      *reinterpret_cast<uint4*>(&Ws[r][c8]) =
          *reinterpret_cast<const uint4*>(&Wg[(size_t)(bn + r) * 256 + k0 + c8]);
    }
    __syncthreads();
    #pragma unroll
    for (int ks = 0; ks < 2; ++ks) {
      const int ko = ks * 32 + (lane >> 4) * 8;
      bf16x8 af[2], bfr[2];
      #pragma unroll
      for (int i = 0; i < 2; ++i)
        af[i] = *reinterpret_cast<const bf16x8*>(&As[wm * 32 + i * 16 + row16][ko]);
      #pragma unroll
      for (int j = 0; j < 2; ++j)
        bfr[j] = *reinterpret_cast<const bf16x8*>(&Ws[wn * 32 + j * 16 + row16][ko]);
      #pragma unroll
      for (int i = 0; i < 2; ++i)
        #pragma unroll
        for (int j = 0; j < 2; ++j)
          acc[i][j] = __builtin_amdgcn_mfma_f32_16x16x32_bf16(af[i], bfr[j], acc[i][j], 0, 0, 0);
    }
    __syncthreads();
  }

  const int cl = lane & 15;
  const int rg = lane >> 4;
  #pragma unroll
  for (int j = 0; j < 2; ++j) {
    const int col = bn + wn * 32 + j * 16 + cl;
    #pragma unroll
    for (int i = 0; i < 2; ++i) {
      const int rbase = bm + wm * 32 + i * 16 + rg * 4;
      #pragma unroll
      for (int rr = 0; rr < 4; ++rr)
        C[(size_t)(rbase + rr) * 256 + col] = acc[i][j][rr];
    }
  }
}

extern "C" void kernel_launch(void* const* d_in, const int* in_sizes, int n_in,
                              void* d_out, int out_size, void* d_ws, size_t ws_size,
                              hipStream_t stream) {
  const float* x      = (const float*)d_in[0];
  const float* W_in   = (const float*)d_in[1];
  const float* conv_w = (const float*)d_in[2];
  const float* conv_b = (const float*)d_in[3];
  const float* W_bc   = (const float*)d_in[4];
  const float* b_bc   = (const float*)d_in[5];
  const float* W_lam  = (const float*)d_in[6];
  const float* b_lam  = (const float*)d_in[7];
  const float* A      = (const float*)d_in[8];
  const float* W_out  = (const float*)d_in[9];
  float* out = (float*)d_out;

  float* ws = (float*)d_ws;
  // layout in float-units
  ushort_t* skipb = (ushort_t*)(ws + 0);        // 1,048,576 shorts (524,288 f)
  ushort_t* praw  = (ushort_t*)(ws + 524288);   // 1,048,576 shorts
  float*    lamb  = ws + 1048576;               // 1,048,576 f
  ushort_t* uwb   = (ushort_t*)(ws + 2097152);  // 1,048,576 shorts
  ushort_t* bcbf  = (ushort_t*)(ws + 2621440);  //   524,288 shorts
  float*    ybuf  = ws + 2883584;               // 1,048,576 f
  float*    Pc    = ws + 3932160;               //    32,768 f
  ushort_t* Hc    = (ushort_t*)(ws + 3964928);  // 2,097,152 shorts (bf16)
  ushort_t* wbcb  = (ushort_t*)(ws + 5013504);  //    32,768 shorts
  ushort_t* wlb   = (ushort_t*)(ws + 5029888);  //    65,536 shorts
  ushort_t* wob   = (ushort_t*)(ws + 5062656);  //    65,536 shorts
  ushort_t* gbf   = (ushort_t*)(ws + 5095424);  // 1,048,576 shorts
  // end: 5,619,712 floats ~ 22.5 MB

  // 1) proj GEMM (inline cvt) + weight conversions      [416 blocks]
  projcvt<<<dim3(416), dim3(256), 0, stream>>>(
      x, W_in, W_bc, W_lam, W_out, wbcb, wlb, wob, skipb, praw);
  // 2) conv (LDS) + fused bc|lambda GEMM                [192 blocks]
  convbclam<<<dim3(192), dim3(256), 0, stream>>>(
      praw, conv_w, conv_b, wbcb, wlb, b_bc, b_lam, A, bcbf, lamb, uwb);
  // 3) chunk-local scan (NC=64, CL=32)                  [512 blocks]
  passA<<<dim3(B_DIM * NC * 4), dim3(256), 0, stream>>>(lamb, uwb, bcbf, Pc, Hc, ybuf);
  // 4) chunk-prefix scan                                [256 blocks]
  chunkscan<<<dim3(256), dim3(128), 0, stream>>>(Pc, Hc);
  // 5) cross-chunk correction + gelu gate -> bf16 g     [512 blocks]
  passB_gelu<<<dim3(B_DIM * NC * 4), dim3(256), 0, stream>>>(
      lamb, bcbf, Hc, skipb, ybuf, gbf);
  // 6) out = g @ W_out^T                                [256 blocks]
  mgemm64<<<dim3(4, 64), dim3(256), 0, stream>>>(gbf, wob, out);
}

// Round 12
// 61.686 us; speedup vs baseline: 7.6898x; 1.0608x over previous
//
#include <hip/hip_runtime.h>
#include <hip/hip_bf16.h>
#include <math.h>

// Problem constants
#define B_DIM 2
#define L_SEQ 2048
#define D_DIM 256
#define N_DIM 64
#define K_CONV 4
#define M_ROWS (B_DIM * L_SEQ)   // 4096
#define NC 64                     // number of scan chunks
#define CL (L_SEQ / NC)           // 32 steps per chunk

typedef __attribute__((ext_vector_type(8))) short bf16x8;
typedef __attribute__((ext_vector_type(4))) float f32x4;
typedef unsigned short ushort_t;

static __device__ __forceinline__ unsigned short f2bf(float f) {
  unsigned int u = __float_as_uint(f);
  unsigned int r = u + 0x7FFF + ((u >> 16) & 1);   // round-to-nearest-even
  return (unsigned short)(r >> 16);
}
static __device__ __forceinline__ float bf2f(ushort_t s) {
  return __uint_as_float(((unsigned int)s) << 16);
}
static __device__ __forceinline__ unsigned int pack2(float a, float b) {
  return (unsigned int)f2bf(a) | ((unsigned int)f2bf(b) << 16);
}

// ====== K1: proj GEMM (inline f32->bf16 staging) + weight conversions ======
// blocks 0..255: 128x64 GEMM tile; XCD-swizzled: bm = bid&31, bn = bid>>5 so
// the 8 blocks sharing an x-panel sit on ONE XCD (bid mod 8 == bm mod 8).
// blocks 256..415: convert W_bc/W_lam/W_out to bf16.
__global__ __launch_bounds__(256) void projcvt(
    const float* __restrict__ x, const float* __restrict__ wi,
    const float* __restrict__ wbc, const float* __restrict__ wl,
    const float* __restrict__ wo,
    ushort_t* __restrict__ wbcb, ushort_t* __restrict__ wlb,
    ushort_t* __restrict__ wob,
    ushort_t* __restrict__ skipb, ushort_t* __restrict__ praw) {
  const int bid = blockIdx.x;
  const int tid = threadIdx.x;
  if (bid >= 256) {                 // ---- converter blocks ----
    int vb = bid - 256;
    const float* src; ushort_t* dst; int off;
    if (vb < 32)      { src = wbc; dst = wbcb; off = vb; }
    else if (vb < 96) { src = wl;  dst = wlb;  off = vb - 32; }
    else              { src = wo;  dst = wob;  off = vb - 96; }
    size_t i = (size_t)off * 1024 + tid * 4;
    float4 v = *reinterpret_cast<const float4*>(&src[i]);
    ushort4 o;
    o.x = f2bf(v.x); o.y = f2bf(v.y); o.z = f2bf(v.z); o.w = f2bf(v.w);
    *reinterpret_cast<ushort4*>(&dst[i]) = o;
    return;
  }
  // ---- GEMM block (XCD-swizzled index map) ----
  __shared__ __align__(16) ushort_t As[128][72];
  __shared__ __align__(16) ushort_t Ws[64][72];
  const int lane = tid & 63;
  const int w = tid >> 6;
  const int wm = w >> 1;
  const int wn = w & 1;
  const int bm = (bid & 31) * 128;
  const int bn = (bid >> 5) * 64;
  const int r0 = tid >> 3;          // 0..31
  const int c8 = (tid & 7) * 8;

  f32x4 acc[4][2];
  #pragma unroll
  for (int i = 0; i < 4; ++i)
    #pragma unroll
    for (int j = 0; j < 2; ++j)
      acc[i][j] = (f32x4){0.f, 0.f, 0.f, 0.f};

  const int row16 = lane & 15;

  for (int k0 = 0; k0 < 256; k0 += 64) {
    #pragma unroll
    for (int p = 0; p < 4; ++p) {
      int r = r0 + p * 32;
      const float* src = &x[(size_t)(bm + r) * 256 + k0 + c8];
      float4 v0 = *reinterpret_cast<const float4*>(src);
      float4 v1 = *reinterpret_cast<const float4*>(src + 4);
      uint4 o;
      o.x = pack2(v0.x, v0.y); o.y = pack2(v0.z, v0.w);
      o.z = pack2(v1.x, v1.y); o.w = pack2(v1.z, v1.w);
      *reinterpret_cast<uint4*>(&As[r][c8]) = o;
    }
    #pragma unroll
    for (int p = 0; p < 2; ++p) {
      int r = r0 + p * 32;
      const float* src = &wi[(size_t)(bn + r) * 256 + k0 + c8];
      float4 v0 = *reinterpret_cast<const float4*>(src);
      float4 v1 = *reinterpret_cast<const float4*>(src + 4);
      uint4 o;
      o.x = pack2(v0.x, v0.y); o.y = pack2(v0.z, v0.w);
      o.z = pack2(v1.x, v1.y); o.w = pack2(v1.z, v1.w);
      *reinterpret_cast<uint4*>(&Ws[r][c8]) = o;
    }
    __syncthreads();
    #pragma unroll
    for (int ks = 0; ks < 2; ++ks) {
      const int ko = ks * 32 + (lane >> 4) * 8;
      bf16x8 af[4], bfr[2];
      #pragma unroll
      for (int i = 0; i < 4; ++i)
        af[i] = *reinterpret_cast<const bf16x8*>(&As[wm * 64 + i * 16 + row16][ko]);
      #pragma unroll
      for (int j = 0; j < 2; ++j)
        bfr[j] = *reinterpret_cast<const bf16x8*>(&Ws[wn * 32 + j * 16 + row16][ko]);
      #pragma unroll
      for (int i = 0; i < 4; ++i)
        #pragma unroll
        for (int j = 0; j < 2; ++j)
          acc[i][j] = __builtin_amdgcn_mfma_f32_16x16x32_bf16(af[i], bfr[j], acc[i][j], 0, 0, 0);
    }
    __syncthreads();
  }

  const int cl = lane & 15;
  const int rg = lane >> 4;
  #pragma unroll
  for (int j = 0; j < 2; ++j) {
    const int col = bn + wn * 32 + j * 16 + cl;
    ushort_t* dst = (col < 256) ? skipb : praw;
    const int cc = col & 255;
    #pragma unroll
    for (int i = 0; i < 4; ++i) {
      const int rbase = bm + wm * 64 + i * 16 + rg * 4;
      #pragma unroll
      for (int rr = 0; rr < 4; ++rr)
        dst[(size_t)(rbase + rr) * 256 + cc] = f2bf(acc[i][j][rr]);
    }
  }
}

// ====== K2: depthwise conv (into LDS) + bc|lambda GEMM ======================
// XCD-swizzled: bm = bid&31, bn = bid>>5 — the 6 blocks sharing a praw panel
// (and its conv recompute) land on one XCD.
__global__ __launch_bounds__(256) void convbclam(
    const ushort_t* __restrict__ praw, const float* __restrict__ cw,
    const float* __restrict__ cb,
    const ushort_t* __restrict__ wbcb, const ushort_t* __restrict__ wlb,
    const float* __restrict__ b_bc, const float* __restrict__ b_lam,
    const float* __restrict__ Avec,
    ushort_t* __restrict__ bcbf, float* __restrict__ lamb,
    ushort_t* __restrict__ uwb) {
  __shared__ __align__(16) ushort_t Us[128][264];   // 67.6 KB
  __shared__ __align__(16) ushort_t Ws[64][72];
  const int tid = threadIdx.x;
  const int lane = tid & 63;
  const int w = tid >> 6;
  const int wm = w >> 1;
  const int wn = w & 1;
  const int bid = blockIdx.x;
  const int bm = (bid & 31) * 128;
  const int bn = (bid >> 5) * 64;    // 0..5

  // ---- conv: thread d handles column d over rows bm..bm+127 ----
  {
    const int d = tid;
    const float4 w4 = *reinterpret_cast<const float4*>(&cw[d * 4]);
    const float bias = cb[d];
    const bool edge = (bm & 2047) == 0;
    float p0 = edge ? 0.f : bf2f(praw[(size_t)(bm - 3) * 256 + d]);
    float p1 = edge ? 0.f : bf2f(praw[(size_t)(bm - 2) * 256 + d]);
    float p2 = edge ? 0.f : bf2f(praw[(size_t)(bm - 1) * 256 + d]);
    #pragma unroll 8
    for (int r = 0; r < 128; ++r) {
      float p3 = bf2f(praw[(size_t)(bm + r) * 256 + d]);
      float u = bias + w4.x * p0 + w4.y * p1 + w4.z * p2 + w4.w * p3;
      Us[r][d] = f2bf(u);
      p0 = p1; p1 = p2; p2 = p3;
    }
  }
  __syncthreads();

  const ushort_t* Wsrc = (bn < 128) ? (wbcb + (size_t)bn * 256)
                                    : (wlb + (size_t)(bn - 128) * 256);
  const int r0 = tid >> 3;
  const int c8 = (tid & 7) * 8;
  const int row16 = lane & 15;

  f32x4 acc[4][2];
  #pragma unroll
  for (int i = 0; i < 4; ++i)
    #pragma unroll
    for (int j = 0; j < 2; ++j)
      acc[i][j] = (f32x4){0.f, 0.f, 0.f, 0.f};

  for (int k0 = 0; k0 < 256; k0 += 64) {
    #pragma unroll
    for (int p = 0; p < 2; ++p) {
      int r = r0 + p * 32;
      uint4 v = *reinterpret_cast<const uint4*>(&Wsrc[(size_t)r * 256 + k0 + c8]);
      *reinterpret_cast<uint4*>(&Ws[r][c8]) = v;
    }
    __syncthreads();
    #pragma unroll
    for (int ks = 0; ks < 2; ++ks) {
      const int ko = ks * 32 + (lane >> 4) * 8;
      bf16x8 af[4], bfr[2];
      #pragma unroll
      for (int i = 0; i < 4; ++i)
        af[i] = *reinterpret_cast<const bf16x8*>(&Us[wm * 64 + i * 16 + row16][k0 + ko]);
      #pragma unroll
      for (int j = 0; j < 2; ++j)
        bfr[j] = *reinterpret_cast<const bf16x8*>(&Ws[wn * 32 + j * 16 + row16][ko]);
      #pragma unroll
      for (int i = 0; i < 4; ++i)
        #pragma unroll
        for (int j = 0; j < 2; ++j)
          acc[i][j] = __builtin_amdgcn_mfma_f32_16x16x32_bf16(af[i], bfr[j], acc[i][j], 0, 0, 0);
    }
    __syncthreads();
  }

  const int cl = lane & 15;
  const int rg = lane >> 4;
  #pragma unroll
  for (int j = 0; j < 2; ++j) {
    const int col = bn + wn * 32 + j * 16 + cl;
    if (col < 128) {
      const float bv = b_bc[col];
      #pragma unroll
      for (int i = 0; i < 4; ++i) {
        const int rbase = bm + wm * 64 + i * 16 + rg * 4;
        #pragma unroll
        for (int rr = 0; rr < 4; ++rr)
          bcbf[(size_t)(rbase + rr) * 128 + col] = f2bf(acc[i][j][rr] + bv);
      }
    } else {
      const int dd = col - 128;
      const float bv = b_lam[dd];
      const float adg = -8.f * log1pf(__expf(Avec[dd]));
      #pragma unroll
      for (int i = 0; i < 4; ++i) {
        const int rbase = bm + wm * 64 + i * 16 + rg * 4;
        #pragma unroll
        for (int rr = 0; rr < 4; ++rr) {
          const int row = rbase + rr;
          float v = acc[i][j][rr] + bv;
          float s = 1.f / (1.f + __expf(-v));
          float lam = __expf(s * adg);
          float wq = sqrtf(1.f + 1e-6f - lam * lam);
          float u = bf2f(Us[row - bm][dd]);
          lamb[(size_t)row * 256 + dd] = lam;
          uwb[(size_t)row * 256 + dd] = f2bf(u * wq);
        }
      }
    }
  }
}

// ---- scan pass A: grid = B*NC*4 (d-quarters), 4 waves = 4 n-groups -------
// CL=32; ypar is an 8-deep ring reduced per segment.
__global__ __launch_bounds__(256) void passA(
    const float* __restrict__ lamb, const ushort_t* __restrict__ uwb,
    const ushort_t* __restrict__ bcbf, float* __restrict__ Pc,
    ushort_t* __restrict__ Hc, float* __restrict__ ybuf) {
  const int bx = blockIdx.x;
  const int dq = bx & 3;
  const int c = (bx >> 2) & (NC - 1);
  const int b = bx >> 8;
  const int lane = threadIdx.x & 63;
  const int ng = threadIdx.x >> 6;
  const int dd = dq * 64 + lane;
  __shared__ __align__(16) float bcs[CL][128];    // 16 KB
  __shared__ __align__(16) float lam_s[CL][64];   // 8 KB
  __shared__ __align__(16) float uw_s[CL][64];    // 8 KB
  __shared__ float ypar[8][4][64];                // 8 KB
  {
    // stage bc (CL x 128 bf16 -> f32)
    const ushort_t* src = bcbf + (size_t)(b * L_SEQ + c * CL) * 128;
    const int f0 = threadIdx.x * 16;
    bf16x8 v0 = *reinterpret_cast<const bf16x8*>(src + f0);
    bf16x8 v1 = *reinterpret_cast<const bf16x8*>(src + f0 + 8);
    float* dstf = &bcs[0][0] + f0;
    #pragma unroll
    for (int q = 0; q < 2; ++q) {
      bf16x8 v = q ? v1 : v0;
      *reinterpret_cast<float4*>(dstf + q * 8) =
          (float4){bf2f((ushort_t)v[0]), bf2f((ushort_t)v[1]),
                   bf2f((ushort_t)v[2]), bf2f((ushort_t)v[3])};
      *reinterpret_cast<float4*>(dstf + q * 8 + 4) =
          (float4){bf2f((ushort_t)v[4]), bf2f((ushort_t)v[5]),
                   bf2f((ushort_t)v[6]), bf2f((ushort_t)v[7])};
    }
    // stage lam (f32) and uw (bf16 -> f32), 8 elems/thread
    const int ts = threadIdx.x >> 3, qs = threadIdx.x & 7;
    size_t rowb = (size_t)(b * L_SEQ + c * CL + ts) * 256 + dq * 64 + qs * 8;
    *reinterpret_cast<float4*>(&lam_s[ts][qs * 8]) =
        *reinterpret_cast<const float4*>(&lamb[rowb]);
    *reinterpret_cast<float4*>(&lam_s[ts][qs * 8 + 4]) =
        *reinterpret_cast<const float4*>(&lamb[rowb + 4]);
    bf16x8 uv = *reinterpret_cast<const bf16x8*>(uwb + rowb);
    *reinterpret_cast<float4*>(&uw_s[ts][qs * 8]) =
        (float4){bf2f((ushort_t)uv[0]), bf2f((ushort_t)uv[1]),
                 bf2f((ushort_t)uv[2]), bf2f((ushort_t)uv[3])};
    *reinterpret_cast<float4*>(&uw_s[ts][qs * 8 + 4]) =
        (float4){bf2f((ushort_t)uv[4]), bf2f((ushort_t)uv[5]),
                 bf2f((ushort_t)uv[6]), bf2f((ushort_t)uv[7])};
  }
  __syncthreads();
  float H[16];
  #pragma unroll
  for (int j = 0; j < 16; ++j) H[j] = 0.f;
  float P = 1.f;
  const size_t base0 = (size_t)(b * L_SEQ + c * CL) * 256 + dd;
  for (int seg = 0; seg < 4; ++seg) {
    #pragma unroll
    for (int tt = 0; tt < 8; ++tt) {
      const int t = seg * 8 + tt;
      float lam = lam_s[t][lane];
      float uw = uw_s[t][lane];
      P *= lam;
      float yp = 0.f;
      const float4* btv = reinterpret_cast<const float4*>(&bcs[t][ng * 16]);
      const float4* ctv = reinterpret_cast<const float4*>(&bcs[t][64 + ng * 16]);
      #pragma unroll
      for (int q = 0; q < 4; ++q) {
        float4 b4 = btv[q];
        float4 c4 = ctv[q];
        H[q * 4 + 0] = lam * H[q * 4 + 0] + b4.x * uw; yp += c4.x * H[q * 4 + 0];
        H[q * 4 + 1] = lam * H[q * 4 + 1] + b4.y * uw; yp += c4.y * H[q * 4 + 1];
        H[q * 4 + 2] = lam * H[q * 4 + 2] + b4.z * uw; yp += c4.z * H[q * 4 + 2];
        H[q * 4 + 3] = lam * H[q * 4 + 3] + b4.w * uw; yp += c4.w * H[q * 4 + 3];
      }
      ypar[tt][ng][lane] = yp;
    }
    __syncthreads();
    #pragma unroll
    for (int k = 0; k < 2; ++k) {
      const int tt = ng * 2 + k;
      const int t = seg * 8 + tt;
      float y = ypar[tt][0][lane] + ypar[tt][1][lane] +
                ypar[tt][2][lane] + ypar[tt][3][lane];
      ybuf[base0 + (size_t)t * 256] = y;
    }
    __syncthreads();
  }
  if (ng == 0) Pc[(size_t)(b * NC + c) * 256 + dd] = P;
  #pragma unroll
  for (int j = 0; j < 16; ++j)
    Hc[((size_t)(b * NC + c) * 64 + ng * 16 + j) * 256 + dd] = f2bf(H[j]);
}

// ---- sequential chunk scan over NC=64, pipelined unroll-16 ---------------
__global__ __launch_bounds__(128) void chunkscan(
    const float* __restrict__ Pc, ushort_t* __restrict__ Hc) {
  int tid = blockIdx.x * 128 + threadIdx.x;   // 32768 = B*N*D
  int d = tid & 255;
  int j = (tid >> 8) & 63;
  int b = tid >> 14;
  const size_t hstride = (size_t)N_DIM * 256;
  const size_t ihb = ((size_t)(b * NC) * 64 + j) * 256 + d;
  const size_t ipb = (size_t)(b * NC) * 256 + d;
  float h = 0.f;
  float Hv[16], Pv[16];
  #pragma unroll
  for (int q = 0; q < 16; ++q) {
    Hv[q] = bf2f(Hc[ihb + (size_t)q * hstride]);
    Pv[q] = Pc[ipb + (size_t)q * 256];
  }
  #pragma unroll 1
  for (int c0 = 0; c0 < NC; c0 += 16) {
    float Hn[16], Pn[16];
    if (c0 + 16 < NC) {
      #pragma unroll
      for (int q = 0; q < 16; ++q) {
        Hn[q] = bf2f(Hc[ihb + (size_t)(c0 + 16 + q) * hstride]);
        Pn[q] = Pc[ipb + (size_t)(c0 + 16 + q) * 256];
      }
    }
    #pragma unroll
    for (int q = 0; q < 16; ++q) {
      Hc[ihb + (size_t)(c0 + q) * hstride] = f2bf(h);
      h = fmaf(Pv[q], h, Hv[q]);
    }
    #pragma unroll
    for (int q = 0; q < 16; ++q) { Hv[q] = Hn[q]; Pv[q] = Pn[q]; }
  }
}

// ---- scan pass B + GELU gate; CL=32, waves finalize 8 t each --------------
__global__ __launch_bounds__(256) void passB_gelu(
    const float* __restrict__ lamb, const ushort_t* __restrict__ bcbf,
    const ushort_t* __restrict__ hin, const ushort_t* __restrict__ skipb,
    const float* __restrict__ ybuf, ushort_t* __restrict__ gbf) {
  const int bx = blockIdx.x;
  const int dq = bx & 3;
  const int c = (bx >> 2) & (NC - 1);
  const int b = bx >> 8;
  const int lane = threadIdx.x & 63;
  const int ng = threadIdx.x >> 6;
  const int dd = dq * 64 + lane;
  __shared__ __align__(16) float cs[CL][64];      // 8 KB
  __shared__ __align__(16) float lam_s[CL][64];   // 8 KB
  __shared__ float spar[CL][4][64];               // 32 KB
  {
    const int ts = threadIdx.x >> 3, qs = threadIdx.x & 7;
    bf16x8 cv = *reinterpret_cast<const bf16x8*>(
        bcbf + (size_t)(b * L_SEQ + c * CL + ts) * 128 + 64 + qs * 8);
    *reinterpret_cast<float4*>(&cs[ts][qs * 8]) =
        (float4){bf2f((ushort_t)cv[0]), bf2f((ushort_t)cv[1]),
                 bf2f((ushort_t)cv[2]), bf2f((ushort_t)cv[3])};
    *reinterpret_cast<float4*>(&cs[ts][qs * 8 + 4]) =
        (float4){bf2f((ushort_t)cv[4]), bf2f((ushort_t)cv[5]),
                 bf2f((ushort_t)cv[6]), bf2f((ushort_t)cv[7])};
    size_t rowb = (size_t)(b * L_SEQ + c * CL + ts) * 256 + dq * 64 + qs * 8;
    *reinterpret_cast<float4*>(&lam_s[ts][qs * 8]) =
        *reinterpret_cast<const float4*>(&lamb[rowb]);
    *reinterpret_cast<float4*>(&lam_s[ts][qs * 8 + 4]) =
        *reinterpret_cast<const float4*>(&lamb[rowb + 4]);
  }
  float h16[16];
  #pragma unroll
  for (int j = 0; j < 16; ++j)
    h16[j] = bf2f(hin[((size_t)(b * NC + c) * 64 + ng * 16 + j) * 256 + dd]);
  __syncthreads();
  const size_t base0 = (size_t)(b * L_SEQ + c * CL) * 256 + dd;
  #pragma unroll 4
  for (int t = 0; t < CL; ++t) {
    float S = 0.f;
    const float4* ctv = reinterpret_cast<const float4*>(&cs[t][ng * 16]);
    #pragma unroll
    for (int q = 0; q < 4; ++q) {
      float4 c4 = ctv[q];
      S += c4.x * h16[q * 4 + 0] + c4.y * h16[q * 4 + 1] +
           c4.z * h16[q * 4 + 2] + c4.w * h16[q * 4 + 3];
    }
    spar[t][ng][lane] = S;
  }
  __syncthreads();
  float Pp = 1.f;
  #pragma unroll
  for (int tau = 0; tau < 24; ++tau)
    if (tau < ng * 8) Pp *= lam_s[tau][lane];
  #pragma unroll
  for (int tt = 0; tt < 8; ++tt) {
    const int t = ng * 8 + tt;
    Pp *= lam_s[t][lane];
    float S4 = spar[t][0][lane] + spar[t][1][lane] +
               spar[t][2][lane] + spar[t][3][lane];
    float y = ybuf[base0 + (size_t)t * 256] + Pp * S4;
    float sk = bf2f(skipb[base0 + (size_t)t * 256]);
    float g = 0.5f * sk * (1.f + erff(sk * 0.70710678118f));
    gbf[base0 + (size_t)t * 256] = f2bf(g * y);
  }
}

// ====== K6: out = g @ W_out^T, 64x64 tiles, XCD-swizzled ===================
// 1-D grid 256: bm = bid&63, bn = bid>>6 — the 4 blocks sharing a g-panel
// land on one XCD (bid mod 8 == bm mod 8).
__global__ __launch_bounds__(256) void mgemm64(
    const ushort_t* __restrict__ Ag, const ushort_t* __restrict__ Wg,
    float* __restrict__ C) {
  __shared__ __align__(16) ushort_t As[64][72];
  __shared__ __align__(16) ushort_t Ws[64][72];
  const int tid = threadIdx.x;
  const int lane = tid & 63;
  const int w = tid >> 6;
  const int wm = w >> 1;
  const int wn = w & 1;
  const int bid = blockIdx.x;
  const int bm = (bid & 63) * 64;
  const int bn = (bid >> 6) * 64;
  const int r0 = tid >> 3;
  const int c8 = (tid & 7) * 8;
  const int row16 = lane & 15;

  f32x4 acc[2][2];
  #pragma unroll
  for (int i = 0; i < 2; ++i)
    #pragma unroll
    for (int j = 0; j < 2; ++j)
      acc[i][j] = (f32x4){0.f, 0.f, 0.f, 0.f};

  for (int k0 = 0; k0 < 256; k0 += 64) {
    #pragma unroll
    for (int p = 0; p < 2; ++p) {
      int r = r0 + p * 32;
      *reinterpret_cast<uint4*>(&As[r][c8]) =
          *reinterpret_cast<const uint4*>(&Ag[(size_t)(bm + r) * 256 + k0 + c8]);
      *reinterpret_cast<uint4*>(&Ws[r][c8]) =
          *reinterpret_cast<const uint4*>(&Wg[(size_t)(bn + r) * 256 + k0 + c8]);
    }
    __syncthreads();
    #pragma unroll
    for (int ks = 0; ks < 2; ++ks) {
      const int ko = ks * 32 + (lane >> 4) * 8;
      bf16x8 af[2], bfr[2];
      #pragma unroll
      for (int i = 0; i < 2; ++i)
        af[i] = *reinterpret_cast<const bf16x8*>(&As[wm * 32 + i * 16 + row16][ko]);
      #pragma unroll
      for (int j = 0; j < 2; ++j)
        bfr[j] = *reinterpret_cast<const bf16x8*>(&Ws[wn * 32 + j * 16 + row16][ko]);
      #pragma unroll
      for (int i = 0; i < 2; ++i)
        #pragma unroll
        for (int j = 0; j < 2; ++j)
          acc[i][j] = __builtin_amdgcn_mfma_f32_16x16x32_bf16(af[i], bfr[j], acc[i][j], 0, 0, 0);
    }
    __syncthreads();
  }

  const int cl = lane & 15;
  const int rg = lane >> 4;
  #pragma unroll
  for (int j = 0; j < 2; ++j) {
    const int col = bn + wn * 32 + j * 16 + cl;
    #pragma unroll
    for (int i = 0; i < 2; ++i) {
      const int rbase = bm + wm * 32 + i * 16 + rg * 4;
      #pragma unroll
      for (int rr = 0; rr < 4; ++rr)
        C[(size_t)(rbase + rr) * 256 + col] = acc[i][j][rr];
    }
  }
}

extern "C" void kernel_launch(void* const* d_in, const int* in_sizes, int n_in,
                              void* d_out, int out_size, void* d_ws, size_t ws_size,
                              hipStream_t stream) {
  const float* x      = (const float*)d_in[0];
  const float* W_in   = (const float*)d_in[1];
  const float* conv_w = (const float*)d_in[2];
  const float* conv_b = (const float*)d_in[3];
  const float* W_bc   = (const float*)d_in[4];
  const float* b_bc   = (const float*)d_in[5];
  const float* W_lam  = (const float*)d_in[6];
  const float* b_lam  = (const float*)d_in[7];
  const float* A      = (const float*)d_in[8];
  const float* W_out  = (const float*)d_in[9];
  float* out = (float*)d_out;

  float* ws = (float*)d_ws;
  // layout in float-units
  ushort_t* skipb = (ushort_t*)(ws + 0);        // 1,048,576 shorts (524,288 f)
  ushort_t* praw  = (ushort_t*)(ws + 524288);   // 1,048,576 shorts
  float*    lamb  = ws + 1048576;               // 1,048,576 f
  ushort_t* uwb   = (ushort_t*)(ws + 2097152);  // 1,048,576 shorts
  ushort_t* bcbf  = (ushort_t*)(ws + 2621440);  //   524,288 shorts
  float*    ybuf  = ws + 2883584;               // 1,048,576 f
  float*    Pc    = ws + 3932160;               //    32,768 f
  ushort_t* Hc    = (ushort_t*)(ws + 3964928);  // 2,097,152 shorts (bf16)
  ushort_t* wbcb  = (ushort_t*)(ws + 5013504);  //    32,768 shorts
  ushort_t* wlb   = (ushort_t*)(ws + 5029888);  //    65,536 shorts
  ushort_t* wob   = (ushort_t*)(ws + 5062656);  //    65,536 shorts
  ushort_t* gbf   = (ushort_t*)(ws + 5095424);  // 1,048,576 shorts
  // end: 5,619,712 floats ~ 22.5 MB

  // 1) proj GEMM (inline cvt, XCD-swizzled) + weight conversions
  projcvt<<<dim3(416), dim3(256), 0, stream>>>(
      x, W_in, W_bc, W_lam, W_out, wbcb, wlb, wob, skipb, praw);
  // 2) conv (LDS) + fused bc|lambda GEMM (XCD-swizzled)
  convbclam<<<dim3(192), dim3(256), 0, stream>>>(
      praw, conv_w, conv_b, wbcb, wlb, b_bc, b_lam, A, bcbf, lamb, uwb);
  // 3) chunk-local scan (NC=64, CL=32)
  passA<<<dim3(B_DIM * NC * 4), dim3(256), 0, stream>>>(lamb, uwb, bcbf, Pc, Hc, ybuf);
  // 4) chunk-prefix scan
  chunkscan<<<dim3(256), dim3(128), 0, stream>>>(Pc, Hc);
  // 5) cross-chunk correction + gelu gate -> bf16 g
  passB_gelu<<<dim3(B_DIM * NC * 4), dim3(256), 0, stream>>>(
      lamb, bcbf, Hc, skipb, ybuf, gbf);
  // 6) out = g @ W_out^T (XCD-swizzled)
  mgemm64<<<dim3(256), dim3(256), 0, stream>>>(gbf, wob, out);
}

// Round 13
// 52.232 us; speedup vs baseline: 9.0816x; 1.1810x over previous
//
#include <hip/hip_runtime.h>
#include <hip/hip_bf16.h>
#include <math.h>

// Problem constants
#define B_DIM 2
#define L_SEQ 2048
#define D_DIM 256
#define N_DIM 64
#define K_CONV 4
#define M_ROWS (B_DIM * L_SEQ)   // 4096
#define NC 64                     // number of scan chunks
#define CL (L_SEQ / NC)           // 32 steps per chunk

typedef __attribute__((ext_vector_type(8))) short bf16x8;
typedef __attribute__((ext_vector_type(4))) float f32x4;
typedef unsigned short ushort_t;

static __device__ __forceinline__ unsigned short f2bf(float f) {
  unsigned int u = __float_as_uint(f);
  unsigned int r = u + 0x7FFF + ((u >> 16) & 1);   // round-to-nearest-even
  return (unsigned short)(r >> 16);
}
static __device__ __forceinline__ float bf2f(ushort_t s) {
  return __uint_as_float(((unsigned int)s) << 16);
}
static __device__ __forceinline__ unsigned int pack2(float a, float b) {
  return (unsigned int)f2bf(a) | ((unsigned int)f2bf(b) << 16);
}

// ====== K1: proj GEMM (inline f32->bf16 staging) + weight conversions ======
__global__ __launch_bounds__(256) void projcvt(
    const float* __restrict__ x, const float* __restrict__ wi,
    const float* __restrict__ wbc, const float* __restrict__ wl,
    const float* __restrict__ wo,
    ushort_t* __restrict__ wbcb, ushort_t* __restrict__ wlb,
    ushort_t* __restrict__ wob,
    ushort_t* __restrict__ skipb, ushort_t* __restrict__ praw) {
  const int bid = blockIdx.x;
  const int tid = threadIdx.x;
  if (bid >= 256) {                 // ---- converter blocks ----
    int vb = bid - 256;
    const float* src; ushort_t* dst; int off;
    if (vb < 32)      { src = wbc; dst = wbcb; off = vb; }
    else if (vb < 96) { src = wl;  dst = wlb;  off = vb - 32; }
    else              { src = wo;  dst = wob;  off = vb - 96; }
    size_t i = (size_t)off * 1024 + tid * 4;
    float4 v = *reinterpret_cast<const float4*>(&src[i]);
    ushort4 o;
    o.x = f2bf(v.x); o.y = f2bf(v.y); o.z = f2bf(v.z); o.w = f2bf(v.w);
    *reinterpret_cast<ushort4*>(&dst[i]) = o;
    return;
  }
  // ---- GEMM block (XCD-swizzled index map) ----
  __shared__ __align__(16) ushort_t As[128][72];
  __shared__ __align__(16) ushort_t Ws[64][72];
  const int lane = tid & 63;
  const int w = tid >> 6;
  const int wm = w >> 1;
  const int wn = w & 1;
  const int bm = (bid & 31) * 128;
  const int bn = (bid >> 5) * 64;
  const int r0 = tid >> 3;          // 0..31
  const int c8 = (tid & 7) * 8;

  f32x4 acc[4][2];
  #pragma unroll
  for (int i = 0; i < 4; ++i)
    #pragma unroll
    for (int j = 0; j < 2; ++j)
      acc[i][j] = (f32x4){0.f, 0.f, 0.f, 0.f};

  const int row16 = lane & 15;

  for (int k0 = 0; k0 < 256; k0 += 64) {
    #pragma unroll
    for (int p = 0; p < 4; ++p) {
      int r = r0 + p * 32;
      const float* src = &x[(size_t)(bm + r) * 256 + k0 + c8];
      float4 v0 = *reinterpret_cast<const float4*>(src);
      float4 v1 = *reinterpret_cast<const float4*>(src + 4);
      uint4 o;
      o.x = pack2(v0.x, v0.y); o.y = pack2(v0.z, v0.w);
      o.z = pack2(v1.x, v1.y); o.w = pack2(v1.z, v1.w);
      *reinterpret_cast<uint4*>(&As[r][c8]) = o;
    }
    #pragma unroll
    for (int p = 0; p < 2; ++p) {
      int r = r0 + p * 32;
      const float* src = &wi[(size_t)(bn + r) * 256 + k0 + c8];
      float4 v0 = *reinterpret_cast<const float4*>(src);
      float4 v1 = *reinterpret_cast<const float4*>(src + 4);
      uint4 o;
      o.x = pack2(v0.x, v0.y); o.y = pack2(v0.z, v0.w);
      o.z = pack2(v1.x, v1.y); o.w = pack2(v1.z, v1.w);
      *reinterpret_cast<uint4*>(&Ws[r][c8]) = o;
    }
    __syncthreads();
    #pragma unroll
    for (int ks = 0; ks < 2; ++ks) {
      const int ko = ks * 32 + (lane >> 4) * 8;
      bf16x8 af[4], bfr[2];
      #pragma unroll
      for (int i = 0; i < 4; ++i)
        af[i] = *reinterpret_cast<const bf16x8*>(&As[wm * 64 + i * 16 + row16][ko]);
      #pragma unroll
      for (int j = 0; j < 2; ++j)
        bfr[j] = *reinterpret_cast<const bf16x8*>(&Ws[wn * 32 + j * 16 + row16][ko]);
      #pragma unroll
      for (int i = 0; i < 4; ++i)
        #pragma unroll
        for (int j = 0; j < 2; ++j)
          acc[i][j] = __builtin_amdgcn_mfma_f32_16x16x32_bf16(af[i], bfr[j], acc[i][j], 0, 0, 0);
    }
    __syncthreads();
  }

  const int cl = lane & 15;
  const int rg = lane >> 4;
  #pragma unroll
  for (int j = 0; j < 2; ++j) {
    const int col = bn + wn * 32 + j * 16 + cl;
    ushort_t* dst = (col < 256) ? skipb : praw;
    const int cc = col & 255;
    #pragma unroll
    for (int i = 0; i < 4; ++i) {
      const int rbase = bm + wm * 64 + i * 16 + rg * 4;
      #pragma unroll
      for (int rr = 0; rr < 4; ++rr)
        dst[(size_t)(rbase + rr) * 256 + cc] = f2bf(acc[i][j][rr]);
    }
  }
}

// ====== K2: depthwise conv (into LDS) + bc|lambda GEMM ======================
__global__ __launch_bounds__(256) void convbclam(
    const ushort_t* __restrict__ praw, const float* __restrict__ cw,
    const float* __restrict__ cb,
    const ushort_t* __restrict__ wbcb, const ushort_t* __restrict__ wlb,
    const float* __restrict__ b_bc, const float* __restrict__ b_lam,
    const float* __restrict__ Avec,
    ushort_t* __restrict__ bcbf, float* __restrict__ lamb,
    ushort_t* __restrict__ uwb) {
  __shared__ __align__(16) ushort_t Us[128][264];   // 67.6 KB
  __shared__ __align__(16) ushort_t Ws[64][72];
  const int tid = threadIdx.x;
  const int lane = tid & 63;
  const int w = tid >> 6;
  const int wm = w >> 1;
  const int wn = w & 1;
  const int bid = blockIdx.x;
  const int bm = (bid & 31) * 128;
  const int bn = (bid >> 5) * 64;    // 0..5

  {
    const int d = tid;
    const float4 w4 = *reinterpret_cast<const float4*>(&cw[d * 4]);
    const float bias = cb[d];
    const bool edge = (bm & 2047) == 0;
    float p0 = edge ? 0.f : bf2f(praw[(size_t)(bm - 3) * 256 + d]);
    float p1 = edge ? 0.f : bf2f(praw[(size_t)(bm - 2) * 256 + d]);
    float p2 = edge ? 0.f : bf2f(praw[(size_t)(bm - 1) * 256 + d]);
    #pragma unroll 8
    for (int r = 0; r < 128; ++r) {
      float p3 = bf2f(praw[(size_t)(bm + r) * 256 + d]);
      float u = bias + w4.x * p0 + w4.y * p1 + w4.z * p2 + w4.w * p3;
      Us[r][d] = f2bf(u);
      p0 = p1; p1 = p2; p2 = p3;
    }
  }
  __syncthreads();

  const ushort_t* Wsrc = (bn < 128) ? (wbcb + (size_t)bn * 256)
                                    : (wlb + (size_t)(bn - 128) * 256);
  const int r0 = tid >> 3;
  const int c8 = (tid & 7) * 8;
  const int row16 = lane & 15;

  f32x4 acc[4][2];
  #pragma unroll
  for (int i = 0; i < 4; ++i)
    #pragma unroll
    for (int j = 0; j < 2; ++j)
      acc[i][j] = (f32x4){0.f, 0.f, 0.f, 0.f};

  for (int k0 = 0; k0 < 256; k0 += 64) {
    #pragma unroll
    for (int p = 0; p < 2; ++p) {
      int r = r0 + p * 32;
      uint4 v = *reinterpret_cast<const uint4*>(&Wsrc[(size_t)r * 256 + k0 + c8]);
      *reinterpret_cast<uint4*>(&Ws[r][c8]) = v;
    }
    __syncthreads();
    #pragma unroll
    for (int ks = 0; ks < 2; ++ks) {
      const int ko = ks * 32 + (lane >> 4) * 8;
      bf16x8 af[4], bfr[2];
      #pragma unroll
      for (int i = 0; i < 4; ++i)
        af[i] = *reinterpret_cast<const bf16x8*>(&Us[wm * 64 + i * 16 + row16][k0 + ko]);
      #pragma unroll
      for (int j = 0; j < 2; ++j)
        bfr[j] = *reinterpret_cast<const bf16x8*>(&Ws[wn * 32 + j * 16 + row16][ko]);
      #pragma unroll
      for (int i = 0; i < 4; ++i)
        #pragma unroll
        for (int j = 0; j < 2; ++j)
          acc[i][j] = __builtin_amdgcn_mfma_f32_16x16x32_bf16(af[i], bfr[j], acc[i][j], 0, 0, 0);
    }
    __syncthreads();
  }

  const int cl = lane & 15;
  const int rg = lane >> 4;
  #pragma unroll
  for (int j = 0; j < 2; ++j) {
    const int col = bn + wn * 32 + j * 16 + cl;
    if (col < 128) {
      const float bv = b_bc[col];
      #pragma unroll
      for (int i = 0; i < 4; ++i) {
        const int rbase = bm + wm * 64 + i * 16 + rg * 4;
        #pragma unroll
        for (int rr = 0; rr < 4; ++rr)
          bcbf[(size_t)(rbase + rr) * 128 + col] = f2bf(acc[i][j][rr] + bv);
      }
    } else {
      const int dd = col - 128;
      const float bv = b_lam[dd];
      const float adg = -8.f * log1pf(__expf(Avec[dd]));
      #pragma unroll
      for (int i = 0; i < 4; ++i) {
        const int rbase = bm + wm * 64 + i * 16 + rg * 4;
        #pragma unroll
        for (int rr = 0; rr < 4; ++rr) {
          const int row = rbase + rr;
          float v = acc[i][j][rr] + bv;
          float s = 1.f / (1.f + __expf(-v));
          float lam = __expf(s * adg);
          float wq = sqrtf(1.f + 1e-6f - lam * lam);
          float u = bf2f(Us[row - bm][dd]);
          lamb[(size_t)row * 256 + dd] = lam;
          uwb[(size_t)row * 256 + dd] = f2bf(u * wq);
        }
      }
    }
  }
}

// ====== K3: chunk-local scan via MFMA (chunked linear attention) ===========
// Block = (b, chunk, dq). y_local = L .* (tril(C.B^T) . V),
// Hc = L_end .* (B^T . V), Pc = L_end, with V = uw / L (per-chunk cumprod).
__global__ __launch_bounds__(256) void passA_mfma(
    const float* __restrict__ lamb, const ushort_t* __restrict__ uwb,
    const ushort_t* __restrict__ bcbf, float* __restrict__ Pc,
    ushort_t* __restrict__ Hc, ushort_t* __restrict__ ylocal) {
  const int bx = blockIdx.x;
  const int dq = bx & 3;
  const int c = (bx >> 2) & (NC - 1);
  const int b = bx >> 8;
  const int tid = threadIdx.x;
  const int lane = tid & 63;
  const int w = tid >> 6;
  const int row16 = lane & 15;
  const int cl = lane & 15;
  const int rg = lane >> 4;

  __shared__ __align__(16) ushort_t bcs[CL][136];  // [t][0..63]=b, [64..127]=c
  __shared__ __align__(16) float    Ls[CL][68];    // lam -> cumprod (in place)
  __shared__ __align__(16) ushort_t uws[CL][72];
  __shared__ __align__(16) ushort_t VT[64][40];    // V^T[d][tau]
  __shared__ __align__(16) ushort_t bT[64][40];    // b^T[n][tau]
  __shared__ __align__(16) ushort_t GL[CL][40];    // tril(G)[t][tau]

  // ---- stage ----
  {
    const int r = tid >> 3;
    const int q = tid & 7;
    const ushort_t* src = bcbf + (size_t)(b * L_SEQ + c * CL + r) * 128;
    *reinterpret_cast<uint4*>(&bcs[r][q * 16]) =
        *reinterpret_cast<const uint4*>(src + q * 16);
    *reinterpret_cast<uint4*>(&bcs[r][q * 16 + 8]) =
        *reinterpret_cast<const uint4*>(src + q * 16 + 8);
    size_t rowb = (size_t)(b * L_SEQ + c * CL + r) * 256 + dq * 64 + q * 8;
    *reinterpret_cast<float4*>(&Ls[r][q * 8]) =
        *reinterpret_cast<const float4*>(&lamb[rowb]);
    *reinterpret_cast<float4*>(&Ls[r][q * 8 + 4]) =
        *reinterpret_cast<const float4*>(&lamb[rowb + 4]);
    *reinterpret_cast<uint4*>(&uws[r][q * 8]) =
        *reinterpret_cast<const uint4*>(uwb + rowb);
  }
  __syncthreads();

  // ---- G = C.B^T (4 tiles, 1/wave), mask tril, store bf16 ----
  {
    const int ti = w >> 1;
    const int tj = w & 1;
    f32x4 g = (f32x4){0.f, 0.f, 0.f, 0.f};
    #pragma unroll
    for (int ks = 0; ks < 2; ++ks) {
      const int ko = ks * 32 + rg * 8;
      bf16x8 aC = *reinterpret_cast<const bf16x8*>(&bcs[ti * 16 + row16][64 + ko]);
      bf16x8 bB = *reinterpret_cast<const bf16x8*>(&bcs[tj * 16 + row16][ko]);
      g = __builtin_amdgcn_mfma_f32_16x16x32_bf16(aC, bB, g, 0, 0, 0);
    }
    #pragma unroll
    for (int r = 0; r < 4; ++r) {
      const int t = ti * 16 + rg * 4 + r;
      const int tau = tj * 16 + cl;
      GL[t][tau] = (tau <= t) ? f2bf(g[r]) : (ushort_t)0;
    }
  }
  // ---- b^T build (all threads; reads bcs only) ----
  {
    #pragma unroll
    for (int k = 0; k < 8; ++k) {
      int el = tid * 8 + k;            // 0..2047
      int n = el >> 5;
      int tau = el & 31;
      bT[n][tau] = bcs[tau][n];
    }
  }
  // ---- cumprod L + V^T (threads 0..63) ----
  if (tid < 64) {
    const int d = tid;
    float L = 1.f;
    #pragma unroll 8
    for (int t = 0; t < CL; ++t) {
      L *= Ls[t][d];
      Ls[t][d] = L;
      VT[d][t] = f2bf(bf2f(uws[t][d]) / L);
    }
  }
  __syncthreads();

  // ---- Y1 = tril(G).V, y_local = L .* Y1 (8 tiles, 2/wave) ----
  {
    const int ti = w & 1;
    #pragma unroll
    for (int p = 0; p < 2; ++p) {
      const int dj = (w >> 1) + p * 2;
      bf16x8 aG = *reinterpret_cast<const bf16x8*>(&GL[ti * 16 + row16][rg * 8]);
      bf16x8 bV = *reinterpret_cast<const bf16x8*>(&VT[dj * 16 + row16][rg * 8]);
      f32x4 y = __builtin_amdgcn_mfma_f32_16x16x32_bf16(aG, bV,
                  (f32x4){0.f, 0.f, 0.f, 0.f}, 0, 0, 0);
      #pragma unroll
      for (int r = 0; r < 4; ++r) {
        const int t = ti * 16 + rg * 4 + r;
        const int dcol = dj * 16 + cl;
        ylocal[(size_t)(b * L_SEQ + c * CL + t) * 256 + dq * 64 + dcol] =
            f2bf(Ls[t][dcol] * y[r]);
      }
    }
  }
  // ---- H_end = L_end .* (B^T.V) (16 tiles, 4/wave) ----
  {
    const int ni = w;
    bf16x8 aB = *reinterpret_cast<const bf16x8*>(&bT[ni * 16 + row16][rg * 8]);
    #pragma unroll
    for (int dj = 0; dj < 4; ++dj) {
      bf16x8 bV = *reinterpret_cast<const bf16x8*>(&VT[dj * 16 + row16][rg * 8]);
      f32x4 h = __builtin_amdgcn_mfma_f32_16x16x32_bf16(aB, bV,
                  (f32x4){0.f, 0.f, 0.f, 0.f}, 0, 0, 0);
      #pragma unroll
      for (int r = 0; r < 4; ++r) {
        const int n = ni * 16 + rg * 4 + r;
        const int dcol = dj * 16 + cl;
        Hc[((size_t)(b * NC + c) * 64 + n) * 256 + dq * 64 + dcol] =
            f2bf(Ls[CL - 1][dcol] * h[r]);
      }
    }
  }
  if (tid < 64)
    Pc[(size_t)(b * NC + c) * 256 + dq * 64 + tid] = Ls[CL - 1][tid];
}

// ---- sequential chunk scan over NC=64, pipelined unroll-16 ---------------
__global__ __launch_bounds__(128) void chunkscan(
    const float* __restrict__ Pc, ushort_t* __restrict__ Hc) {
  int tid = blockIdx.x * 128 + threadIdx.x;   // 32768 = B*N*D
  int d = tid & 255;
  int j = (tid >> 8) & 63;
  int b = tid >> 14;
  const size_t hstride = (size_t)N_DIM * 256;
  const size_t ihb = ((size_t)(b * NC) * 64 + j) * 256 + d;
  const size_t ipb = (size_t)(b * NC) * 256 + d;
  float h = 0.f;
  float Hv[16], Pv[16];
  #pragma unroll
  for (int q = 0; q < 16; ++q) {
    Hv[q] = bf2f(Hc[ihb + (size_t)q * hstride]);
    Pv[q] = Pc[ipb + (size_t)q * 256];
  }
  #pragma unroll 1
  for (int c0 = 0; c0 < NC; c0 += 16) {
    float Hn[16], Pn[16];
    if (c0 + 16 < NC) {
      #pragma unroll
      for (int q = 0; q < 16; ++q) {
        Hn[q] = bf2f(Hc[ihb + (size_t)(c0 + 16 + q) * hstride]);
        Pn[q] = Pc[ipb + (size_t)(c0 + 16 + q) * 256];
      }
    }
    #pragma unroll
    for (int q = 0; q < 16; ++q) {
      Hc[ihb + (size_t)(c0 + q) * hstride] = f2bf(h);
      h = fmaf(Pv[q], h, Hv[q]);
    }
    #pragma unroll
    for (int q = 0; q < 16; ++q) { Hv[q] = Hn[q]; Pv[q] = Pn[q]; }
  }
}

// ====== K5: cross-chunk correction via MFMA + GELU gate ====================
// y = ylocal + L .* (C.Hin); g = gelu(skip)*y -> gbf
__global__ __launch_bounds__(256) void passB_mfma(
    const float* __restrict__ lamb, const ushort_t* __restrict__ bcbf,
    const ushort_t* __restrict__ hin, const ushort_t* __restrict__ skipb,
    const ushort_t* __restrict__ ylocal, ushort_t* __restrict__ gbf) {
  const int bx = blockIdx.x;
  const int dq = bx & 3;
  const int c = (bx >> 2) & (NC - 1);
  const int b = bx >> 8;
  const int tid = threadIdx.x;
  const int lane = tid & 63;
  const int w = tid >> 6;
  const int row16 = lane & 15;
  const int cl = lane & 15;
  const int rg = lane >> 4;

  __shared__ __align__(16) ushort_t cs[CL][72];   // c[t][n]
  __shared__ __align__(16) float    Ls[CL][68];   // lam -> cumprod
  __shared__ __align__(16) ushort_t HT[64][72];   // Hin^T[d][n]

  {
    const int r = tid >> 3;
    const int q = tid & 7;
    *reinterpret_cast<uint4*>(&cs[r][q * 8]) =
        *reinterpret_cast<const uint4*>(
            bcbf + (size_t)(b * L_SEQ + c * CL + r) * 128 + 64 + q * 8);
    size_t rowb = (size_t)(b * L_SEQ + c * CL + r) * 256 + dq * 64 + q * 8;
    *reinterpret_cast<float4*>(&Ls[r][q * 8]) =
        *reinterpret_cast<const float4*>(&lamb[rowb]);
    *reinterpret_cast<float4*>(&Ls[r][q * 8 + 4]) =
        *reinterpret_cast<const float4*>(&lamb[rowb + 4]);
    #pragma unroll
    for (int nn = 0; nn < 2; ++nn) {
      const int n = (tid >> 3) + nn * 32;
      bf16x8 hv = *reinterpret_cast<const bf16x8*>(
          hin + ((size_t)(b * NC + c) * 64 + n) * 256 + dq * 64 + q * 8);
      #pragma unroll
      for (int k = 0; k < 8; ++k)
        HT[q * 8 + k][n] = (ushort_t)hv[k];
    }
  }
  __syncthreads();
  if (tid < 64) {
    const int d = tid;
    float L = 1.f;
    #pragma unroll 8
    for (int t = 0; t < CL; ++t) {
      L *= Ls[t][d];
      Ls[t][d] = L;
    }
  }
  __syncthreads();

  // corr = C.Hin (8 tiles, 2/wave, K=64)
  const int ti = w & 1;
  #pragma unroll
  for (int p = 0; p < 2; ++p) {
    const int dj = (w >> 1) + p * 2;
    f32x4 acc = (f32x4){0.f, 0.f, 0.f, 0.f};
    #pragma unroll
    for (int ks = 0; ks < 2; ++ks) {
      const int ko = ks * 32 + rg * 8;
      bf16x8 aC = *reinterpret_cast<const bf16x8*>(&cs[ti * 16 + row16][ko]);
      bf16x8 bH = *reinterpret_cast<const bf16x8*>(&HT[dj * 16 + row16][ko]);
      acc = __builtin_amdgcn_mfma_f32_16x16x32_bf16(aC, bH, acc, 0, 0, 0);
    }
    #pragma unroll
    for (int r = 0; r < 4; ++r) {
      const int t = ti * 16 + rg * 4 + r;
      const int dcol = dj * 16 + cl;
      size_t gi = (size_t)(b * L_SEQ + c * CL + t) * 256 + dq * 64 + dcol;
      float y = bf2f(ylocal[gi]) + Ls[t][dcol] * acc[r];
      float sk = bf2f(skipb[gi]);
      float g = 0.5f * sk * (1.f + erff(sk * 0.70710678118f));
      gbf[gi] = f2bf(g * y);
    }
  }
}

// ====== K6: out = g @ W_out^T, 64x64 tiles, XCD-swizzled ===================
__global__ __launch_bounds__(256) void mgemm64(
    const ushort_t* __restrict__ Ag, const ushort_t* __restrict__ Wg,
    float* __restrict__ C) {
  __shared__ __align__(16) ushort_t As[64][72];
  __shared__ __align__(16) ushort_t Ws[64][72];
  const int tid = threadIdx.x;
  const int lane = tid & 63;
  const int w = tid >> 6;
  const int wm = w >> 1;
  const int wn = w & 1;
  const int bid = blockIdx.x;
  const int bm = (bid & 63) * 64;
  const int bn = (bid >> 6) * 64;
  const int r0 = tid >> 3;
  const int c8 = (tid & 7) * 8;
  const int row16 = lane & 15;

  f32x4 acc[2][2];
  #pragma unroll
  for (int i = 0; i < 2; ++i)
    #pragma unroll
    for (int j = 0; j < 2; ++j)
      acc[i][j] = (f32x4){0.f, 0.f, 0.f, 0.f};

  for (int k0 = 0; k0 < 256; k0 += 64) {
    #pragma unroll
    for (int p = 0; p < 2; ++p) {
      int r = r0 + p * 32;
      *reinterpret_cast<uint4*>(&As[r][c8]) =
          *reinterpret_cast<const uint4*>(&Ag[(size_t)(bm + r) * 256 + k0 + c8]);
      *reinterpret_cast<uint4*>(&Ws[r][c8]) =
          *reinterpret_cast<const uint4*>(&Wg[(size_t)(bn + r) * 256 + k0 + c8]);
    }
    __syncthreads();
    #pragma unroll
    for (int ks = 0; ks < 2; ++ks) {
      const int ko = ks * 32 + (lane >> 4) * 8;
      bf16x8 af[2], bfr[2];
      #pragma unroll
      for (int i = 0; i < 2; ++i)
        af[i] = *reinterpret_cast<const bf16x8*>(&As[wm * 32 + i * 16 + row16][ko]);
      #pragma unroll
      for (int j = 0; j < 2; ++j)
        bfr[j] = *reinterpret_cast<const bf16x8*>(&Ws[wn * 32 + j * 16 + row16][ko]);
      #pragma unroll
      for (int i = 0; i < 2; ++i)
        #pragma unroll
        for (int j = 0; j < 2; ++j)
          acc[i][j] = __builtin_amdgcn_mfma_f32_16x16x32_bf16(af[i], bfr[j], acc[i][j], 0, 0, 0);
    }
    __syncthreads();
  }

  const int cl = lane & 15;
  const int rg = lane >> 4;
  #pragma unroll
  for (int j = 0; j < 2; ++j) {
    const int col = bn + wn * 32 + j * 16 + cl;
    #pragma unroll
    for (int i = 0; i < 2; ++i) {
      const int rbase = bm + wm * 32 + i * 16 + rg * 4;
      #pragma unroll
      for (int rr = 0; rr < 4; ++rr)
        C[(size_t)(rbase + rr) * 256 + col] = acc[i][j][rr];
    }
  }
}

extern "C" void kernel_launch(void* const* d_in, const int* in_sizes, int n_in,
                              void* d_out, int out_size, void* d_ws, size_t ws_size,
                              hipStream_t stream) {
  const float* x      = (const float*)d_in[0];
  const float* W_in   = (const float*)d_in[1];
  const float* conv_w = (const float*)d_in[2];
  const float* conv_b = (const float*)d_in[3];
  const float* W_bc   = (const float*)d_in[4];
  const float* b_bc   = (const float*)d_in[5];
  const float* W_lam  = (const float*)d_in[6];
  const float* b_lam  = (const float*)d_in[7];
  const float* A      = (const float*)d_in[8];
  const float* W_out  = (const float*)d_in[9];
  float* out = (float*)d_out;

  float* ws = (float*)d_ws;
  ushort_t* skipb  = (ushort_t*)(ws + 0);        // 1,048,576 sh
  ushort_t* praw   = (ushort_t*)(ws + 524288);   // 1,048,576 sh
  float*    lamb   = ws + 1048576;               // 1,048,576 f
  ushort_t* uwb    = (ushort_t*)(ws + 2097152);  // 1,048,576 sh
  ushort_t* bcbf   = (ushort_t*)(ws + 2621440);  //   524,288 sh
  ushort_t* ylocal = (ushort_t*)(ws + 2883584);  // 1,048,576 sh
  float*    Pc     = ws + 3407872;               //    32,768 f
  ushort_t* Hc     = (ushort_t*)(ws + 3440640);  // 2,097,152 sh
  ushort_t* wbcb   = (ushort_t*)(ws + 4489216);  //    32,768 sh
  ushort_t* wlb    = (ushort_t*)(ws + 4505600);  //    65,536 sh
  ushort_t* wob    = (ushort_t*)(ws + 4538368);  //    65,536 sh
  ushort_t* gbf    = (ushort_t*)(ws + 4571136);  // 1,048,576 sh
  // end: 5,095,424 floats ~ 20.4 MB

  // 1) proj GEMM (inline cvt, XCD-swizzled) + weight conversions
  projcvt<<<dim3(416), dim3(256), 0, stream>>>(
      x, W_in, W_bc, W_lam, W_out, wbcb, wlb, wob, skipb, praw);
  // 2) conv (LDS) + fused bc|lambda GEMM (XCD-swizzled)
  convbclam<<<dim3(192), dim3(256), 0, stream>>>(
      praw, conv_w, conv_b, wbcb, wlb, b_bc, b_lam, A, bcbf, lamb, uwb);
  // 3) chunk-local scan via MFMA
  passA_mfma<<<dim3(B_DIM * NC * 4), dim3(256), 0, stream>>>(
      lamb, uwb, bcbf, Pc, Hc, ylocal);
  // 4) chunk-prefix scan
  chunkscan<<<dim3(256), dim3(128), 0, stream>>>(Pc, Hc);
  // 5) cross-chunk correction via MFMA + gelu gate -> bf16 g
  passB_mfma<<<dim3(B_DIM * NC * 4), dim3(256), 0, stream>>>(
      lamb, bcbf, Hc, skipb, ylocal, gbf);
  // 6) out = g @ W_out^T (XCD-swizzled)
  mgemm64<<<dim3(256), dim3(256), 0, stream>>>(gbf, wob, out);
}

// Round 14
// 52.144 us; speedup vs baseline: 9.0969x; 1.0017x over previous
//
#include <hip/hip_runtime.h>
#include <hip/hip_bf16.h>
#include <math.h>

// Problem constants
#define B_DIM 2
#define L_SEQ 2048
#define D_DIM 256
#define N_DIM 64
#define K_CONV 4
#define M_ROWS (B_DIM * L_SEQ)   // 4096
#define NC 64                     // number of scan chunks
#define CL (L_SEQ / NC)           // 32 steps per chunk

typedef __attribute__((ext_vector_type(8))) short bf16x8;
typedef __attribute__((ext_vector_type(4))) float f32x4;
typedef unsigned short ushort_t;

static __device__ __forceinline__ unsigned short f2bf(float f) {
  unsigned int u = __float_as_uint(f);
  unsigned int r = u + 0x7FFF + ((u >> 16) & 1);   // round-to-nearest-even
  return (unsigned short)(r >> 16);
}
static __device__ __forceinline__ float bf2f(ushort_t s) {
  return __uint_as_float(((unsigned int)s) << 16);
}

// ====== K1: convert x + W_in + W_bc + W_lam + W_out to bf16 ================
// segments: x:1024 | wi:128 | wbc:32 | wl:64 | wo:64  => 1312 blocks
__global__ __launch_bounds__(256) void cvt6(
    const float* __restrict__ x, const float* __restrict__ wi,
    const float* __restrict__ wbc, const float* __restrict__ wl,
    const float* __restrict__ wo,
    ushort_t* __restrict__ xbf, ushort_t* __restrict__ wib,
    ushort_t* __restrict__ wbcb, ushort_t* __restrict__ wlb,
    ushort_t* __restrict__ wob) {
  int bid = blockIdx.x;
  const float* src; ushort_t* dst; int off;
  if (bid < 1024)      { src = x;   dst = xbf;  off = bid; }
  else if (bid < 1152) { src = wi;  dst = wib;  off = bid - 1024; }
  else if (bid < 1184) { src = wbc; dst = wbcb; off = bid - 1152; }
  else if (bid < 1248) { src = wl;  dst = wlb;  off = bid - 1184; }
  else                 { src = wo;  dst = wob;  off = bid - 1248; }
  size_t i = (size_t)off * 1024 + threadIdx.x * 4;
  float4 v = *reinterpret_cast<const float4*>(&src[i]);
  ushort4 o;
  o.x = f2bf(v.x); o.y = f2bf(v.y); o.z = f2bf(v.z); o.w = f2bf(v.w);
  *reinterpret_cast<ushort4*>(&dst[i]) = o;
}

// ====== K2: proj = x @ W_in^T, 64x64 tiles, pure bf16, XCD-swizzled ========
// grid 512 (1-D): bm = (bid&63)*64, bn = (bid>>6)*64 (N=512 -> 8 bn tiles).
// Split output: col<256 -> skipb, col>=256 -> praw (both bf16).
__global__ __launch_bounds__(256) void projgemm(
    const ushort_t* __restrict__ Ag, const ushort_t* __restrict__ Wg,
    ushort_t* __restrict__ skipb, ushort_t* __restrict__ praw) {
  __shared__ __align__(16) ushort_t As[64][72];
  __shared__ __align__(16) ushort_t Ws[64][72];
  const int tid = threadIdx.x;
  const int lane = tid & 63;
  const int w = tid >> 6;
  const int wm = w >> 1;
  const int wn = w & 1;
  const int bid = blockIdx.x;
  const int bm = (bid & 63) * 64;
  const int bn = (bid >> 6) * 64;
  const int r0 = tid >> 3;
  const int c8 = (tid & 7) * 8;
  const int row16 = lane & 15;

  f32x4 acc[2][2];
  #pragma unroll
  for (int i = 0; i < 2; ++i)
    #pragma unroll
    for (int j = 0; j < 2; ++j)
      acc[i][j] = (f32x4){0.f, 0.f, 0.f, 0.f};

  for (int k0 = 0; k0 < 256; k0 += 64) {
    #pragma unroll
    for (int p = 0; p < 2; ++p) {
      int r = r0 + p * 32;
      *reinterpret_cast<uint4*>(&As[r][c8]) =
          *reinterpret_cast<const uint4*>(&Ag[(size_t)(bm + r) * 256 + k0 + c8]);
      *reinterpret_cast<uint4*>(&Ws[r][c8]) =
          *reinterpret_cast<const uint4*>(&Wg[(size_t)(bn + r) * 256 + k0 + c8]);
    }
    __syncthreads();
    #pragma unroll
    for (int ks = 0; ks < 2; ++ks) {
      const int ko = ks * 32 + (lane >> 4) * 8;
      bf16x8 af[2], bfr[2];
      #pragma unroll
      for (int i = 0; i < 2; ++i)
        af[i] = *reinterpret_cast<const bf16x8*>(&As[wm * 32 + i * 16 + row16][ko]);
      #pragma unroll
      for (int j = 0; j < 2; ++j)
        bfr[j] = *reinterpret_cast<const bf16x8*>(&Ws[wn * 32 + j * 16 + row16][ko]);
      #pragma unroll
      for (int i = 0; i < 2; ++i)
        #pragma unroll
        for (int j = 0; j < 2; ++j)
          acc[i][j] = __builtin_amdgcn_mfma_f32_16x16x32_bf16(af[i], bfr[j], acc[i][j], 0, 0, 0);
    }
    __syncthreads();
  }

  const int cl = lane & 15;
  const int rg = lane >> 4;
  #pragma unroll
  for (int j = 0; j < 2; ++j) {
    const int col = bn + wn * 32 + j * 16 + cl;
    ushort_t* dst = (col < 256) ? skipb : praw;
    const int cc = col & 255;
    #pragma unroll
    for (int i = 0; i < 2; ++i) {
      const int rbase = bm + wm * 32 + i * 16 + rg * 4;
      #pragma unroll
      for (int rr = 0; rr < 4; ++rr)
        dst[(size_t)(rbase + rr) * 256 + cc] = f2bf(acc[i][j][rr]);
    }
  }
}

// ====== K3: depthwise conv (into LDS) + bc|lambda GEMM, 64-row panels ======
// grid 384 (1-D): bm = (bid&63)*64, bn = (bid>>6)*64 (6 bn tiles).
__global__ __launch_bounds__(256) void convbclam(
    const ushort_t* __restrict__ praw, const float* __restrict__ cw,
    const float* __restrict__ cb,
    const ushort_t* __restrict__ wbcb, const ushort_t* __restrict__ wlb,
    const float* __restrict__ b_bc, const float* __restrict__ b_lam,
    const float* __restrict__ Avec,
    ushort_t* __restrict__ bcbf, float* __restrict__ lamb,
    ushort_t* __restrict__ uwb) {
  __shared__ __align__(16) ushort_t Us[64][264];    // 33.8 KB
  __shared__ __align__(16) ushort_t Ws[64][72];     // 9.2 KB
  const int tid = threadIdx.x;
  const int lane = tid & 63;
  const int w = tid >> 6;
  const int wm = w >> 1;
  const int wn = w & 1;
  const int bid = blockIdx.x;
  const int bm = (bid & 63) * 64;
  const int bn = (bid >> 6) * 64;    // 0..5 tiles

  // ---- conv: thread d handles column d over rows bm..bm+63 ----
  {
    const int d = tid;
    const float4 w4 = *reinterpret_cast<const float4*>(&cw[d * 4]);
    const float bias = cb[d];
    const bool edge = (bm & 2047) == 0;   // batch boundary
    float p0 = edge ? 0.f : bf2f(praw[(size_t)(bm - 3) * 256 + d]);
    float p1 = edge ? 0.f : bf2f(praw[(size_t)(bm - 2) * 256 + d]);
    float p2 = edge ? 0.f : bf2f(praw[(size_t)(bm - 1) * 256 + d]);
    #pragma unroll 8
    for (int r = 0; r < 64; ++r) {
      float p3 = bf2f(praw[(size_t)(bm + r) * 256 + d]);
      float u = bias + w4.x * p0 + w4.y * p1 + w4.z * p2 + w4.w * p3;
      Us[r][d] = f2bf(u);
      p0 = p1; p1 = p2; p2 = p3;
    }
  }
  __syncthreads();

  const ushort_t* Wsrc = (bn < 128) ? (wbcb + (size_t)bn * 256)
                                    : (wlb + (size_t)(bn - 128) * 256);
  const int r0 = tid >> 3;
  const int c8 = (tid & 7) * 8;
  const int row16 = lane & 15;

  f32x4 acc[2][2];
  #pragma unroll
  for (int i = 0; i < 2; ++i)
    #pragma unroll
    for (int j = 0; j < 2; ++j)
      acc[i][j] = (f32x4){0.f, 0.f, 0.f, 0.f};

  for (int k0 = 0; k0 < 256; k0 += 64) {
    #pragma unroll
    for (int p = 0; p < 2; ++p) {
      int r = r0 + p * 32;
      uint4 v = *reinterpret_cast<const uint4*>(&Wsrc[(size_t)r * 256 + k0 + c8]);
      *reinterpret_cast<uint4*>(&Ws[r][c8]) = v;
    }
    __syncthreads();
    #pragma unroll
    for (int ks = 0; ks < 2; ++ks) {
      const int ko = ks * 32 + (lane >> 4) * 8;
      bf16x8 af[2], bfr[2];
      #pragma unroll
      for (int i = 0; i < 2; ++i)
        af[i] = *reinterpret_cast<const bf16x8*>(&Us[wm * 32 + i * 16 + row16][k0 + ko]);
      #pragma unroll
      for (int j = 0; j < 2; ++j)
        bfr[j] = *reinterpret_cast<const bf16x8*>(&Ws[wn * 32 + j * 16 + row16][ko]);
      #pragma unroll
      for (int i = 0; i < 2; ++i)
        #pragma unroll
        for (int j = 0; j < 2; ++j)
          acc[i][j] = __builtin_amdgcn_mfma_f32_16x16x32_bf16(af[i], bfr[j], acc[i][j], 0, 0, 0);
    }
    __syncthreads();
  }

  const int cl = lane & 15;
  const int rg = lane >> 4;
  #pragma unroll
  for (int j = 0; j < 2; ++j) {
    const int col = bn + wn * 32 + j * 16 + cl;
    if (col < 128) {
      const float bv = b_bc[col];
      #pragma unroll
      for (int i = 0; i < 2; ++i) {
        const int rbase = bm + wm * 32 + i * 16 + rg * 4;
        #pragma unroll
        for (int rr = 0; rr < 4; ++rr)
          bcbf[(size_t)(rbase + rr) * 128 + col] = f2bf(acc[i][j][rr] + bv);
      }
    } else {
      const int dd = col - 128;
      const float bv = b_lam[dd];
      const float adg = -8.f * log1pf(__expf(Avec[dd]));
      #pragma unroll
      for (int i = 0; i < 2; ++i) {
        const int rbase = bm + wm * 32 + i * 16 + rg * 4;
        #pragma unroll
        for (int rr = 0; rr < 4; ++rr) {
          const int row = rbase + rr;
          float v = acc[i][j][rr] + bv;
          float s = 1.f / (1.f + __expf(-v));
          float lam = __expf(s * adg);
          float wq = sqrtf(1.f + 1e-6f - lam * lam);
          float u = bf2f(Us[row - bm][dd]);
          lamb[(size_t)row * 256 + dd] = lam;
          uwb[(size_t)row * 256 + dd] = f2bf(u * wq);
        }
      }
    }
  }
}

// ====== K4: chunk-local scan via MFMA (chunked linear attention) ===========
__global__ __launch_bounds__(256) void passA_mfma(
    const float* __restrict__ lamb, const ushort_t* __restrict__ uwb,
    const ushort_t* __restrict__ bcbf, float* __restrict__ Pc,
    ushort_t* __restrict__ Hc, ushort_t* __restrict__ ylocal) {
  const int bx = blockIdx.x;
  const int dq = bx & 3;
  const int c = (bx >> 2) & (NC - 1);
  const int b = bx >> 8;
  const int tid = threadIdx.x;
  const int lane = tid & 63;
  const int w = tid >> 6;
  const int row16 = lane & 15;
  const int cl = lane & 15;
  const int rg = lane >> 4;

  __shared__ __align__(16) ushort_t bcs[CL][136];  // [t][0..63]=b, [64..127]=c
  __shared__ __align__(16) float    Ls[CL][68];    // lam -> cumprod (in place)
  __shared__ __align__(16) ushort_t uws[CL][72];
  __shared__ __align__(16) ushort_t VT[64][40];    // V^T[d][tau]
  __shared__ __align__(16) ushort_t bT[64][40];    // b^T[n][tau]
  __shared__ __align__(16) ushort_t GL[CL][40];    // tril(G)[t][tau]

  {
    const int r = tid >> 3;
    const int q = tid & 7;
    const ushort_t* src = bcbf + (size_t)(b * L_SEQ + c * CL + r) * 128;
    *reinterpret_cast<uint4*>(&bcs[r][q * 16]) =
        *reinterpret_cast<const uint4*>(src + q * 16);
    *reinterpret_cast<uint4*>(&bcs[r][q * 16 + 8]) =
        *reinterpret_cast<const uint4*>(src + q * 16 + 8);
    size_t rowb = (size_t)(b * L_SEQ + c * CL + r) * 256 + dq * 64 + q * 8;
    *reinterpret_cast<float4*>(&Ls[r][q * 8]) =
        *reinterpret_cast<const float4*>(&lamb[rowb]);
    *reinterpret_cast<float4*>(&Ls[r][q * 8 + 4]) =
        *reinterpret_cast<const float4*>(&lamb[rowb + 4]);
    *reinterpret_cast<uint4*>(&uws[r][q * 8]) =
        *reinterpret_cast<const uint4*>(uwb + rowb);
  }
  __syncthreads();

  {
    const int ti = w >> 1;
    const int tj = w & 1;
    f32x4 g = (f32x4){0.f, 0.f, 0.f, 0.f};
    #pragma unroll
    for (int ks = 0; ks < 2; ++ks) {
      const int ko = ks * 32 + rg * 8;
      bf16x8 aC = *reinterpret_cast<const bf16x8*>(&bcs[ti * 16 + row16][64 + ko]);
      bf16x8 bB = *reinterpret_cast<const bf16x8*>(&bcs[tj * 16 + row16][ko]);
      g = __builtin_amdgcn_mfma_f32_16x16x32_bf16(aC, bB, g, 0, 0, 0);
    }
    #pragma unroll
    for (int r = 0; r < 4; ++r) {
      const int t = ti * 16 + rg * 4 + r;
      const int tau = tj * 16 + cl;
      GL[t][tau] = (tau <= t) ? f2bf(g[r]) : (ushort_t)0;
    }
  }
  {
    #pragma unroll
    for (int k = 0; k < 8; ++k) {
      int el = tid * 8 + k;            // 0..2047
      int n = el >> 5;
      int tau = el & 31;
      bT[n][tau] = bcs[tau][n];
    }
  }
  if (tid < 64) {
    const int d = tid;
    float L = 1.f;
    #pragma unroll 8
    for (int t = 0; t < CL; ++t) {
      L *= Ls[t][d];
      Ls[t][d] = L;
      VT[d][t] = f2bf(bf2f(uws[t][d]) / L);
    }
  }
  __syncthreads();

  {
    const int ti = w & 1;
    #pragma unroll
    for (int p = 0; p < 2; ++p) {
      const int dj = (w >> 1) + p * 2;
      bf16x8 aG = *reinterpret_cast<const bf16x8*>(&GL[ti * 16 + row16][rg * 8]);
      bf16x8 bV = *reinterpret_cast<const bf16x8*>(&VT[dj * 16 + row16][rg * 8]);
      f32x4 y = __builtin_amdgcn_mfma_f32_16x16x32_bf16(aG, bV,
                  (f32x4){0.f, 0.f, 0.f, 0.f}, 0, 0, 0);
      #pragma unroll
      for (int r = 0; r < 4; ++r) {
        const int t = ti * 16 + rg * 4 + r;
        const int dcol = dj * 16 + cl;
        ylocal[(size_t)(b * L_SEQ + c * CL + t) * 256 + dq * 64 + dcol] =
            f2bf(Ls[t][dcol] * y[r]);
      }
    }
  }
  {
    const int ni = w;
    bf16x8 aB = *reinterpret_cast<const bf16x8*>(&bT[ni * 16 + row16][rg * 8]);
    #pragma unroll
    for (int dj = 0; dj < 4; ++dj) {
      bf16x8 bV = *reinterpret_cast<const bf16x8*>(&VT[dj * 16 + row16][rg * 8]);
      f32x4 h = __builtin_amdgcn_mfma_f32_16x16x32_bf16(aB, bV,
                  (f32x4){0.f, 0.f, 0.f, 0.f}, 0, 0, 0);
      #pragma unroll
      for (int r = 0; r < 4; ++r) {
        const int n = ni * 16 + rg * 4 + r;
        const int dcol = dj * 16 + cl;
        Hc[((size_t)(b * NC + c) * 64 + n) * 256 + dq * 64 + dcol] =
            f2bf(Ls[CL - 1][dcol] * h[r]);
      }
    }
  }
  if (tid < 64)
    Pc[(size_t)(b * NC + c) * 256 + dq * 64 + tid] = Ls[CL - 1][tid];
}

// ---- K5: sequential chunk scan over NC=64, pipelined unroll-16 ------------
__global__ __launch_bounds__(128) void chunkscan(
    const float* __restrict__ Pc, ushort_t* __restrict__ Hc) {
  int tid = blockIdx.x * 128 + threadIdx.x;   // 32768 = B*N*D
  int d = tid & 255;
  int j = (tid >> 8) & 63;
  int b = tid >> 14;
  const size_t hstride = (size_t)N_DIM * 256;
  const size_t ihb = ((size_t)(b * NC) * 64 + j) * 256 + d;
  const size_t ipb = (size_t)(b * NC) * 256 + d;
  float h = 0.f;
  float Hv[16], Pv[16];
  #pragma unroll
  for (int q = 0; q < 16; ++q) {
    Hv[q] = bf2f(Hc[ihb + (size_t)q * hstride]);
    Pv[q] = Pc[ipb + (size_t)q * 256];
  }
  #pragma unroll 1
  for (int c0 = 0; c0 < NC; c0 += 16) {
    float Hn[16], Pn[16];
    if (c0 + 16 < NC) {
      #pragma unroll
      for (int q = 0; q < 16; ++q) {
        Hn[q] = bf2f(Hc[ihb + (size_t)(c0 + 16 + q) * hstride]);
        Pn[q] = Pc[ipb + (size_t)(c0 + 16 + q) * 256];
      }
    }
    #pragma unroll
    for (int q = 0; q < 16; ++q) {
      Hc[ihb + (size_t)(c0 + q) * hstride] = f2bf(h);
      h = fmaf(Pv[q], h, Hv[q]);
    }
    #pragma unroll
    for (int q = 0; q < 16; ++q) { Hv[q] = Hn[q]; Pv[q] = Pn[q]; }
  }
}

// ====== K6: cross-chunk correction via MFMA + GELU gate ====================
__global__ __launch_bounds__(256) void passB_mfma(
    const float* __restrict__ lamb, const ushort_t* __restrict__ bcbf,
    const ushort_t* __restrict__ hin, const ushort_t* __restrict__ skipb,
    const ushort_t* __restrict__ ylocal, ushort_t* __restrict__ gbf) {
  const int bx = blockIdx.x;
  const int dq = bx & 3;
  const int c = (bx >> 2) & (NC - 1);
  const int b = bx >> 8;
  const int tid = threadIdx.x;
  const int lane = tid & 63;
  const int w = tid >> 6;
  const int row16 = lane & 15;
  const int cl = lane & 15;
  const int rg = lane >> 4;

  __shared__ __align__(16) ushort_t cs[CL][72];   // c[t][n]
  __shared__ __align__(16) float    Ls[CL][68];   // lam -> cumprod
  __shared__ __align__(16) ushort_t HT[64][72];   // Hin^T[d][n]

  {
    const int r = tid >> 3;
    const int q = tid & 7;
    *reinterpret_cast<uint4*>(&cs[r][q * 8]) =
        *reinterpret_cast<const uint4*>(
            bcbf + (size_t)(b * L_SEQ + c * CL + r) * 128 + 64 + q * 8);
    size_t rowb = (size_t)(b * L_SEQ + c * CL + r) * 256 + dq * 64 + q * 8;
    *reinterpret_cast<float4*>(&Ls[r][q * 8]) =
        *reinterpret_cast<const float4*>(&lamb[rowb]);
    *reinterpret_cast<float4*>(&Ls[r][q * 8 + 4]) =
        *reinterpret_cast<const float4*>(&lamb[rowb + 4]);
    #pragma unroll
    for (int nn = 0; nn < 2; ++nn) {
      const int n = (tid >> 3) + nn * 32;
      bf16x8 hv = *reinterpret_cast<const bf16x8*>(
          hin + ((size_t)(b * NC + c) * 64 + n) * 256 + dq * 64 + q * 8);
      #pragma unroll
      for (int k = 0; k < 8; ++k)
        HT[q * 8 + k][n] = (ushort_t)hv[k];
    }
  }
  __syncthreads();
  if (tid < 64) {
    const int d = tid;
    float L = 1.f;
    #pragma unroll 8
    for (int t = 0; t < CL; ++t) {
      L *= Ls[t][d];
      Ls[t][d] = L;
    }
  }
  __syncthreads();

  const int ti = w & 1;
  #pragma unroll
  for (int p = 0; p < 2; ++p) {
    const int dj = (w >> 1) + p * 2;
    f32x4 acc = (f32x4){0.f, 0.f, 0.f, 0.f};
    #pragma unroll
    for (int ks = 0; ks < 2; ++ks) {
      const int ko = ks * 32 + rg * 8;
      bf16x8 aC = *reinterpret_cast<const bf16x8*>(&cs[ti * 16 + row16][ko]);
      bf16x8 bH = *reinterpret_cast<const bf16x8*>(&HT[dj * 16 + row16][ko]);
      acc = __builtin_amdgcn_mfma_f32_16x16x32_bf16(aC, bH, acc, 0, 0, 0);
    }
    #pragma unroll
    for (int r = 0; r < 4; ++r) {
      const int t = ti * 16 + rg * 4 + r;
      const int dcol = dj * 16 + cl;
      size_t gi = (size_t)(b * L_SEQ + c * CL + t) * 256 + dq * 64 + dcol;
      float y = bf2f(ylocal[gi]) + Ls[t][dcol] * acc[r];
      float sk = bf2f(skipb[gi]);
      float g = 0.5f * sk * (1.f + erff(sk * 0.70710678118f));
      gbf[gi] = f2bf(g * y);
    }
  }
}

// ====== K7: out = g @ W_out^T, 64x64 tiles, XCD-swizzled ===================
__global__ __launch_bounds__(256) void mgemm64(
    const ushort_t* __restrict__ Ag, const ushort_t* __restrict__ Wg,
    float* __restrict__ C) {
  __shared__ __align__(16) ushort_t As[64][72];
  __shared__ __align__(16) ushort_t Ws[64][72];
  const int tid = threadIdx.x;
  const int lane = tid & 63;
  const int w = tid >> 6;
  const int wm = w >> 1;
  const int wn = w & 1;
  const int bid = blockIdx.x;
  const int bm = (bid & 63) * 64;
  const int bn = (bid >> 6) * 64;
  const int r0 = tid >> 3;
  const int c8 = (tid & 7) * 8;
  const int row16 = lane & 15;

  f32x4 acc[2][2];
  #pragma unroll
  for (int i = 0; i < 2; ++i)
    #pragma unroll
    for (int j = 0; j < 2; ++j)
      acc[i][j] = (f32x4){0.f, 0.f, 0.f, 0.f};

  for (int k0 = 0; k0 < 256; k0 += 64) {
    #pragma unroll
    for (int p = 0; p < 2; ++p) {
      int r = r0 + p * 32;
      *reinterpret_cast<uint4*>(&As[r][c8]) =
          *reinterpret_cast<const uint4*>(&Ag[(size_t)(bm + r) * 256 + k0 + c8]);
      *reinterpret_cast<uint4*>(&Ws[r][c8]) =
          *reinterpret_cast<const uint4*>(&Wg[(size_t)(bn + r) * 256 + k0 + c8]);
    }
    __syncthreads();
    #pragma unroll
    for (int ks = 0; ks < 2; ++ks) {
      const int ko = ks * 32 + (lane >> 4) * 8;
      bf16x8 af[2], bfr[2];
      #pragma unroll
      for (int i = 0; i < 2; ++i)
        af[i] = *reinterpret_cast<const bf16x8*>(&As[wm * 32 + i * 16 + row16][ko]);
      #pragma unroll
      for (int j = 0; j < 2; ++j)
        bfr[j] = *reinterpret_cast<const bf16x8*>(&Ws[wn * 32 + j * 16 + row16][ko]);
      #pragma unroll
      for (int i = 0; i < 2; ++i)
        #pragma unroll
        for (int j = 0; j < 2; ++j)
          acc[i][j] = __builtin_amdgcn_mfma_f32_16x16x32_bf16(af[i], bfr[j], acc[i][j], 0, 0, 0);
    }
    __syncthreads();
  }

  const int cl = lane & 15;
  const int rg = lane >> 4;
  #pragma unroll
  for (int j = 0; j < 2; ++j) {
    const int col = bn + wn * 32 + j * 16 + cl;
    #pragma unroll
    for (int i = 0; i < 2; ++i) {
      const int rbase = bm + wm * 32 + i * 16 + rg * 4;
      #pragma unroll
      for (int rr = 0; rr < 4; ++rr)
        C[(size_t)(rbase + rr) * 256 + col] = acc[i][j][rr];
    }
  }
}

extern "C" void kernel_launch(void* const* d_in, const int* in_sizes, int n_in,
                              void* d_out, int out_size, void* d_ws, size_t ws_size,
                              hipStream_t stream) {
  const float* x      = (const float*)d_in[0];
  const float* W_in   = (const float*)d_in[1];
  const float* conv_w = (const float*)d_in[2];
  const float* conv_b = (const float*)d_in[3];
  const float* W_bc   = (const float*)d_in[4];
  const float* b_bc   = (const float*)d_in[5];
  const float* W_lam  = (const float*)d_in[6];
  const float* b_lam  = (const float*)d_in[7];
  const float* A      = (const float*)d_in[8];
  const float* W_out  = (const float*)d_in[9];
  float* out = (float*)d_out;

  float* ws = (float*)d_ws;
  ushort_t* skipb  = (ushort_t*)(ws + 0);        // 1,048,576 sh
  ushort_t* praw   = (ushort_t*)(ws + 524288);   // 1,048,576 sh
  float*    lamb   = ws + 1048576;               // 1,048,576 f
  ushort_t* uwb    = (ushort_t*)(ws + 2097152);  // 1,048,576 sh
  ushort_t* bcbf   = (ushort_t*)(ws + 2621440);  //   524,288 sh
  ushort_t* ylocal = (ushort_t*)(ws + 2883584);  // 1,048,576 sh
  float*    Pc     = ws + 3407872;               //    32,768 f
  ushort_t* Hc     = (ushort_t*)(ws + 3440640);  // 2,097,152 sh
  ushort_t* wbcb   = (ushort_t*)(ws + 4489216);  //    32,768 sh
  ushort_t* wlb    = (ushort_t*)(ws + 4505600);  //    65,536 sh
  ushort_t* wob    = (ushort_t*)(ws + 4538368);  //    65,536 sh
  ushort_t* gbf    = (ushort_t*)(ws + 4571136);  // 1,048,576 sh
  ushort_t* xbf    = (ushort_t*)(ws + 5095424);  // 1,048,576 sh
  ushort_t* wib    = (ushort_t*)(ws + 5619712);  //   131,072 sh
  // end: 5,685,248 floats ~ 22.7 MB

  // 1) one-time f32 -> bf16 conversion of x and all GEMM weights
  cvt6<<<dim3(1312), dim3(256), 0, stream>>>(
      x, W_in, W_bc, W_lam, W_out, xbf, wib, wbcb, wlb, wob);
  // 2) proj = x @ W_in^T -> skipb | praw (bf16, 64x64 tiles, 512 blocks)
  projgemm<<<dim3(512), dim3(256), 0, stream>>>(xbf, wib, skipb, praw);
  // 3) conv (LDS) + fused bc|lambda GEMM (64-row panels, 384 blocks)
  convbclam<<<dim3(384), dim3(256), 0, stream>>>(
      praw, conv_w, conv_b, wbcb, wlb, b_bc, b_lam, A, bcbf, lamb, uwb);
  // 4) chunk-local scan via MFMA
  passA_mfma<<<dim3(B_DIM * NC * 4), dim3(256), 0, stream>>>(
      lamb, uwb, bcbf, Pc, Hc, ylocal);
  // 5) chunk-prefix scan
  chunkscan<<<dim3(256), dim3(128), 0, stream>>>(Pc, Hc);
  // 6) cross-chunk correction via MFMA + gelu gate -> bf16 g
  passB_mfma<<<dim3(B_DIM * NC * 4), dim3(256), 0, stream>>>(
      lamb, bcbf, Hc, skipb, ylocal, gbf);
  // 7) out = g @ W_out^T (64x64 tiles, XCD-swizzled)
  mgemm64<<<dim3(256), dim3(256), 0, stream>>>(gbf, wob, out);
}

// Round 15
// 47.344 us; speedup vs baseline: 10.0192x; 1.1014x over previous
//
#include <hip/hip_runtime.h>
#include <hip/hip_bf16.h>
#include <math.h>

// Problem constants
#define B_DIM 2
#define L_SEQ 2048
#define D_DIM 256
#define N_DIM 64
#define K_CONV 4
#define M_ROWS (B_DIM * L_SEQ)   // 4096
#define NC 64                     // number of scan chunks
#define CL (L_SEQ / NC)           // 32 steps per chunk

typedef __attribute__((ext_vector_type(8))) short bf16x8;
typedef __attribute__((ext_vector_type(4))) float f32x4;
typedef unsigned short ushort_t;

static __device__ __forceinline__ unsigned short f2bf(float f) {
  unsigned int u = __float_as_uint(f);
  unsigned int r = u + 0x7FFF + ((u >> 16) & 1);   // round-to-nearest-even
  return (unsigned short)(r >> 16);
}
static __device__ __forceinline__ float bf2f(ushort_t s) {
  return __uint_as_float(((unsigned int)s) << 16);
}
static __device__ __forceinline__ unsigned int pack2(float a, float b) {
  return (unsigned int)f2bf(a) | ((unsigned int)f2bf(b) << 16);
}

// ====== K1: proj = x @ W_in^T (inline f32->bf16 staging) + weight cvt ======
// blocks 0..511: 64x64 GEMM tiles, XCD-swizzled (bm = bid&63 -> same-panel
// blocks share an XCD). blocks 512..671: convert W_bc/W_lam/W_out to bf16.
__global__ __launch_bounds__(256) void projcvt64(
    const float* __restrict__ x, const float* __restrict__ wi,
    const float* __restrict__ wbc, const float* __restrict__ wl,
    const float* __restrict__ wo,
    ushort_t* __restrict__ wbcb, ushort_t* __restrict__ wlb,
    ushort_t* __restrict__ wob,
    ushort_t* __restrict__ skipb, ushort_t* __restrict__ praw) {
  const int bid = blockIdx.x;
  const int tid = threadIdx.x;
  if (bid >= 512) {                 // ---- converter blocks ----
    int vb = bid - 512;
    const float* src; ushort_t* dst; int off;
    if (vb < 32)      { src = wbc; dst = wbcb; off = vb; }
    else if (vb < 96) { src = wl;  dst = wlb;  off = vb - 32; }
    else              { src = wo;  dst = wob;  off = vb - 96; }
    size_t i = (size_t)off * 1024 + tid * 4;
    float4 v = *reinterpret_cast<const float4*>(&src[i]);
    ushort4 o;
    o.x = f2bf(v.x); o.y = f2bf(v.y); o.z = f2bf(v.z); o.w = f2bf(v.w);
    *reinterpret_cast<ushort4*>(&dst[i]) = o;
    return;
  }
  // ---- GEMM block ----
  __shared__ __align__(16) ushort_t As[64][72];
  __shared__ __align__(16) ushort_t Ws[64][72];
  const int lane = tid & 63;
  const int w = tid >> 6;
  const int wm = w >> 1;
  const int wn = w & 1;
  const int bm = (bid & 63) * 64;
  const int bn = (bid >> 6) * 64;
  const int r0 = tid >> 3;          // 0..31
  const int c8 = (tid & 7) * 8;
  const int row16 = lane & 15;

  f32x4 acc[2][2];
  #pragma unroll
  for (int i = 0; i < 2; ++i)
    #pragma unroll
    for (int j = 0; j < 2; ++j)
      acc[i][j] = (f32x4){0.f, 0.f, 0.f, 0.f};

  for (int k0 = 0; k0 < 256; k0 += 64) {
    #pragma unroll
    for (int p = 0; p < 2; ++p) {
      int r = r0 + p * 32;
      const float* src = &x[(size_t)(bm + r) * 256 + k0 + c8];
      float4 v0 = *reinterpret_cast<const float4*>(src);
      float4 v1 = *reinterpret_cast<const float4*>(src + 4);
      uint4 o;
      o.x = pack2(v0.x, v0.y); o.y = pack2(v0.z, v0.w);
      o.z = pack2(v1.x, v1.y); o.w = pack2(v1.z, v1.w);
      *reinterpret_cast<uint4*>(&As[r][c8]) = o;
      const float* srcw = &wi[(size_t)(bn + r) * 256 + k0 + c8];
      float4 w0 = *reinterpret_cast<const float4*>(srcw);
      float4 w1 = *reinterpret_cast<const float4*>(srcw + 4);
      uint4 ow;
      ow.x = pack2(w0.x, w0.y); ow.y = pack2(w0.z, w0.w);
      ow.z = pack2(w1.x, w1.y); ow.w = pack2(w1.z, w1.w);
      *reinterpret_cast<uint4*>(&Ws[r][c8]) = ow;
    }
    __syncthreads();
    #pragma unroll
    for (int ks = 0; ks < 2; ++ks) {
      const int ko = ks * 32 + (lane >> 4) * 8;
      bf16x8 af[2], bfr[2];
      #pragma unroll
      for (int i = 0; i < 2; ++i)
        af[i] = *reinterpret_cast<const bf16x8*>(&As[wm * 32 + i * 16 + row16][ko]);
      #pragma unroll
      for (int j = 0; j < 2; ++j)
        bfr[j] = *reinterpret_cast<const bf16x8*>(&Ws[wn * 32 + j * 16 + row16][ko]);
      #pragma unroll
      for (int i = 0; i < 2; ++i)
        #pragma unroll
        for (int j = 0; j < 2; ++j)
          acc[i][j] = __builtin_amdgcn_mfma_f32_16x16x32_bf16(af[i], bfr[j], acc[i][j], 0, 0, 0);
    }
    __syncthreads();
  }

  const int cl = lane & 15;
  const int rg = lane >> 4;
  #pragma unroll
  for (int j = 0; j < 2; ++j) {
    const int col = bn + wn * 32 + j * 16 + cl;
    ushort_t* dst = (col < 256) ? skipb : praw;
    const int cc = col & 255;
    #pragma unroll
    for (int i = 0; i < 2; ++i) {
      const int rbase = bm + wm * 32 + i * 16 + rg * 4;
      #pragma unroll
      for (int rr = 0; rr < 4; ++rr)
        dst[(size_t)(rbase + rr) * 256 + cc] = f2bf(acc[i][j][rr]);
    }
  }
}

// ====== K2: depthwise conv (into LDS) + bc|lambda GEMM, 64-row panels ======
__global__ __launch_bounds__(256) void convbclam(
    const ushort_t* __restrict__ praw, const float* __restrict__ cw,
    const float* __restrict__ cb,
    const ushort_t* __restrict__ wbcb, const ushort_t* __restrict__ wlb,
    const float* __restrict__ b_bc, const float* __restrict__ b_lam,
    const float* __restrict__ Avec,
    ushort_t* __restrict__ bcbf, float* __restrict__ lamb,
    ushort_t* __restrict__ uwb) {
  __shared__ __align__(16) ushort_t Us[64][264];    // 33.8 KB
  __shared__ __align__(16) ushort_t Ws[64][72];     // 9.2 KB
  const int tid = threadIdx.x;
  const int lane = tid & 63;
  const int w = tid >> 6;
  const int wm = w >> 1;
  const int wn = w & 1;
  const int bid = blockIdx.x;
  const int bm = (bid & 63) * 64;
  const int bn = (bid >> 6) * 64;    // 0..5 tiles

  {
    const int d = tid;
    const float4 w4 = *reinterpret_cast<const float4*>(&cw[d * 4]);
    const float bias = cb[d];
    const bool edge = (bm & 2047) == 0;   // batch boundary
    float p0 = edge ? 0.f : bf2f(praw[(size_t)(bm - 3) * 256 + d]);
    float p1 = edge ? 0.f : bf2f(praw[(size_t)(bm - 2) * 256 + d]);
    float p2 = edge ? 0.f : bf2f(praw[(size_t)(bm - 1) * 256 + d]);
    #pragma unroll 8
    for (int r = 0; r < 64; ++r) {
      float p3 = bf2f(praw[(size_t)(bm + r) * 256 + d]);
      float u = bias + w4.x * p0 + w4.y * p1 + w4.z * p2 + w4.w * p3;
      Us[r][d] = f2bf(u);
      p0 = p1; p1 = p2; p2 = p3;
    }
  }
  __syncthreads();

  const ushort_t* Wsrc = (bn < 128) ? (wbcb + (size_t)bn * 256)
                                    : (wlb + (size_t)(bn - 128) * 256);
  const int r0 = tid >> 3;
  const int c8 = (tid & 7) * 8;
  const int row16 = lane & 15;

  f32x4 acc[2][2];
  #pragma unroll
  for (int i = 0; i < 2; ++i)
    #pragma unroll
    for (int j = 0; j < 2; ++j)
      acc[i][j] = (f32x4){0.f, 0.f, 0.f, 0.f};

  for (int k0 = 0; k0 < 256; k0 += 64) {
    #pragma unroll
    for (int p = 0; p < 2; ++p) {
      int r = r0 + p * 32;
      uint4 v = *reinterpret_cast<const uint4*>(&Wsrc[(size_t)r * 256 + k0 + c8]);
      *reinterpret_cast<uint4*>(&Ws[r][c8]) = v;
    }
    __syncthreads();
    #pragma unroll
    for (int ks = 0; ks < 2; ++ks) {
      const int ko = ks * 32 + (lane >> 4) * 8;
      bf16x8 af[2], bfr[2];
      #pragma unroll
      for (int i = 0; i < 2; ++i)
        af[i] = *reinterpret_cast<const bf16x8*>(&Us[wm * 32 + i * 16 + row16][k0 + ko]);
      #pragma unroll
      for (int j = 0; j < 2; ++j)
        bfr[j] = *reinterpret_cast<const bf16x8*>(&Ws[wn * 32 + j * 16 + row16][ko]);
      #pragma unroll
      for (int i = 0; i < 2; ++i)
        #pragma unroll
        for (int j = 0; j < 2; ++j)
          acc[i][j] = __builtin_amdgcn_mfma_f32_16x16x32_bf16(af[i], bfr[j], acc[i][j], 0, 0, 0);
    }
    __syncthreads();
  }

  const int cl = lane & 15;
  const int rg = lane >> 4;
  #pragma unroll
  for (int j = 0; j < 2; ++j) {
    const int col = bn + wn * 32 + j * 16 + cl;
    if (col < 128) {
      const float bv = b_bc[col];
      #pragma unroll
      for (int i = 0; i < 2; ++i) {
        const int rbase = bm + wm * 32 + i * 16 + rg * 4;
        #pragma unroll
        for (int rr = 0; rr < 4; ++rr)
          bcbf[(size_t)(rbase + rr) * 128 + col] = f2bf(acc[i][j][rr] + bv);
      }
    } else {
      const int dd = col - 128;
      const float bv = b_lam[dd];
      const float adg = -8.f * log1pf(__expf(Avec[dd]));
      #pragma unroll
      for (int i = 0; i < 2; ++i) {
        const int rbase = bm + wm * 32 + i * 16 + rg * 4;
        #pragma unroll
        for (int rr = 0; rr < 4; ++rr) {
          const int row = rbase + rr;
          float v = acc[i][j][rr] + bv;
          float s = 1.f / (1.f + __expf(-v));
          float lam = __expf(s * adg);
          float wq = sqrtf(1.f + 1e-6f - lam * lam);
          float u = bf2f(Us[row - bm][dd]);
          lamb[(size_t)row * 256 + dd] = lam;
          uwb[(size_t)row * 256 + dd] = f2bf(u * wq);
        }
      }
    }
  }
}

// ====== K3: chunk-local scan via MFMA (chunked linear attention) ===========
__global__ __launch_bounds__(256) void passA_mfma(
    const float* __restrict__ lamb, const ushort_t* __restrict__ uwb,
    const ushort_t* __restrict__ bcbf, float* __restrict__ Pc,
    ushort_t* __restrict__ Hc, ushort_t* __restrict__ ylocal) {
  const int bx = blockIdx.x;
  const int dq = bx & 3;
  const int c = (bx >> 2) & (NC - 1);
  const int b = bx >> 8;
  const int tid = threadIdx.x;
  const int lane = tid & 63;
  const int w = tid >> 6;
  const int row16 = lane & 15;
  const int cl = lane & 15;
  const int rg = lane >> 4;

  __shared__ __align__(16) ushort_t bcs[CL][136];  // [t][0..63]=b, [64..127]=c
  __shared__ __align__(16) float    Ls[CL][68];    // lam -> cumprod (in place)
  __shared__ __align__(16) ushort_t uws[CL][72];
  __shared__ __align__(16) ushort_t VT[64][40];    // V^T[d][tau]
  __shared__ __align__(16) ushort_t bT[64][40];    // b^T[n][tau]
  __shared__ __align__(16) ushort_t GL[CL][40];    // tril(G)[t][tau]
  __shared__ float segp[4][68];

  {
    const int r = tid >> 3;
    const int q = tid & 7;
    const ushort_t* src = bcbf + (size_t)(b * L_SEQ + c * CL + r) * 128;
    *reinterpret_cast<uint4*>(&bcs[r][q * 16]) =
        *reinterpret_cast<const uint4*>(src + q * 16);
    *reinterpret_cast<uint4*>(&bcs[r][q * 16 + 8]) =
        *reinterpret_cast<const uint4*>(src + q * 16 + 8);
    size_t rowb = (size_t)(b * L_SEQ + c * CL + r) * 256 + dq * 64 + q * 8;
    *reinterpret_cast<float4*>(&Ls[r][q * 8]) =
        *reinterpret_cast<const float4*>(&lamb[rowb]);
    *reinterpret_cast<float4*>(&Ls[r][q * 8 + 4]) =
        *reinterpret_cast<const float4*>(&lamb[rowb + 4]);
    *reinterpret_cast<uint4*>(&uws[r][q * 8]) =
        *reinterpret_cast<const uint4*>(uwb + rowb);
  }
  __syncthreads();

  // ---- G = C.B^T (4 tiles, 1/wave), mask tril, store bf16 ----
  {
    const int ti = w >> 1;
    const int tj = w & 1;
    f32x4 g = (f32x4){0.f, 0.f, 0.f, 0.f};
    #pragma unroll
    for (int ks = 0; ks < 2; ++ks) {
      const int ko = ks * 32 + rg * 8;
      bf16x8 aC = *reinterpret_cast<const bf16x8*>(&bcs[ti * 16 + row16][64 + ko]);
      bf16x8 bB = *reinterpret_cast<const bf16x8*>(&bcs[tj * 16 + row16][ko]);
      g = __builtin_amdgcn_mfma_f32_16x16x32_bf16(aC, bB, g, 0, 0, 0);
    }
    #pragma unroll
    for (int r = 0; r < 4; ++r) {
      const int t = ti * 16 + rg * 4 + r;
      const int tau = tj * 16 + cl;
      GL[t][tau] = (tau <= t) ? f2bf(g[r]) : (ushort_t)0;
    }
  }
  // ---- b^T build (all threads; reads bcs only) ----
  {
    #pragma unroll
    for (int k = 0; k < 8; ++k) {
      int el = tid * 8 + k;            // 0..2047
      int n = el >> 5;
      int tau = el & 31;
      bT[n][tau] = bcs[tau][n];
    }
  }
  // ---- cumprod L (4-segment parallel scan, all 256 threads) ----
  {
    const int d = tid & 63;
    const int seg = tid >> 6;
    float local = 1.f;
    #pragma unroll
    for (int k = 0; k < 8; ++k) {
      local *= Ls[seg * 8 + k][d];
      Ls[seg * 8 + k][d] = local;
    }
    segp[seg][d] = local;
  }
  __syncthreads();
  {
    const int d = tid & 63;
    const int seg = tid >> 6;
    float pre = 1.f;
    #pragma unroll
    for (int s = 0; s < 3; ++s)
      if (s < seg) pre *= segp[s][d];
    #pragma unroll
    for (int k = 0; k < 8; ++k) {
      const int t = seg * 8 + k;
      float L = Ls[t][d] * pre;
      Ls[t][d] = L;
      VT[d][t] = f2bf(bf2f(uws[t][d]) / L);
    }
  }
  __syncthreads();

  // ---- Y1 = tril(G).V, y_local = L .* Y1 (8 tiles, 2/wave) ----
  {
    const int ti = w & 1;
    #pragma unroll
    for (int p = 0; p < 2; ++p) {
      const int dj = (w >> 1) + p * 2;
      bf16x8 aG = *reinterpret_cast<const bf16x8*>(&GL[ti * 16 + row16][rg * 8]);
      bf16x8 bV = *reinterpret_cast<const bf16x8*>(&VT[dj * 16 + row16][rg * 8]);
      f32x4 y = __builtin_amdgcn_mfma_f32_16x16x32_bf16(aG, bV,
                  (f32x4){0.f, 0.f, 0.f, 0.f}, 0, 0, 0);
      #pragma unroll
      for (int r = 0; r < 4; ++r) {
        const int t = ti * 16 + rg * 4 + r;
        const int dcol = dj * 16 + cl;
        ylocal[(size_t)(b * L_SEQ + c * CL + t) * 256 + dq * 64 + dcol] =
            f2bf(Ls[t][dcol] * y[r]);
      }
    }
  }
  // ---- H_end = L_end .* (B^T.V) (16 tiles, 4/wave) ----
  {
    const int ni = w;
    bf16x8 aB = *reinterpret_cast<const bf16x8*>(&bT[ni * 16 + row16][rg * 8]);
    #pragma unroll
    for (int dj = 0; dj < 4; ++dj) {
      bf16x8 bV = *reinterpret_cast<const bf16x8*>(&VT[dj * 16 + row16][rg * 8]);
      f32x4 h = __builtin_amdgcn_mfma_f32_16x16x32_bf16(aB, bV,
                  (f32x4){0.f, 0.f, 0.f, 0.f}, 0, 0, 0);
      #pragma unroll
      for (int r = 0; r < 4; ++r) {
        const int n = ni * 16 + rg * 4 + r;
        const int dcol = dj * 16 + cl;
        Hc[((size_t)(b * NC + c) * 64 + n) * 256 + dq * 64 + dcol] =
            f2bf(Ls[CL - 1][dcol] * h[r]);
      }
    }
  }
  if (tid < 64)
    Pc[(size_t)(b * NC + c) * 256 + dq * 64 + tid] = Ls[CL - 1][tid];
}

// ---- K4: sequential chunk scan over NC=64, pipelined unroll-16 ------------
__global__ __launch_bounds__(128) void chunkscan(
    const float* __restrict__ Pc, ushort_t* __restrict__ Hc) {
  int tid = blockIdx.x * 128 + threadIdx.x;   // 32768 = B*N*D
  int d = tid & 255;
  int j = (tid >> 8) & 63;
  int b = tid >> 14;
  const size_t hstride = (size_t)N_DIM * 256;
  const size_t ihb = ((size_t)(b * NC) * 64 + j) * 256 + d;
  const size_t ipb = (size_t)(b * NC) * 256 + d;
  float h = 0.f;
  float Hv[16], Pv[16];
  #pragma unroll
  for (int q = 0; q < 16; ++q) {
    Hv[q] = bf2f(Hc[ihb + (size_t)q * hstride]);
    Pv[q] = Pc[ipb + (size_t)q * 256];
  }
  #pragma unroll 1
  for (int c0 = 0; c0 < NC; c0 += 16) {
    float Hn[16], Pn[16];
    if (c0 + 16 < NC) {
      #pragma unroll
      for (int q = 0; q < 16; ++q) {
        Hn[q] = bf2f(Hc[ihb + (size_t)(c0 + 16 + q) * hstride]);
        Pn[q] = Pc[ipb + (size_t)(c0 + 16 + q) * 256];
      }
    }
    #pragma unroll
    for (int q = 0; q < 16; ++q) {
      Hc[ihb + (size_t)(c0 + q) * hstride] = f2bf(h);
      h = fmaf(Pv[q], h, Hv[q]);
    }
    #pragma unroll
    for (int q = 0; q < 16; ++q) { Hv[q] = Hn[q]; Pv[q] = Pn[q]; }
  }
}

// ====== K5: cross-chunk correction via MFMA + GELU gate ====================
__global__ __launch_bounds__(256) void passB_mfma(
    const float* __restrict__ lamb, const ushort_t* __restrict__ bcbf,
    const ushort_t* __restrict__ hin, const ushort_t* __restrict__ skipb,
    const ushort_t* __restrict__ ylocal, ushort_t* __restrict__ gbf) {
  const int bx = blockIdx.x;
  const int dq = bx & 3;
  const int c = (bx >> 2) & (NC - 1);
  const int b = bx >> 8;
  const int tid = threadIdx.x;
  const int lane = tid & 63;
  const int w = tid >> 6;
  const int row16 = lane & 15;
  const int cl = lane & 15;
  const int rg = lane >> 4;

  __shared__ __align__(16) ushort_t cs[CL][72];   // c[t][n]
  __shared__ __align__(16) float    Ls[CL][68];   // lam -> cumprod
  __shared__ __align__(16) ushort_t HT[64][72];   // Hin^T[d][n]
  __shared__ float segp[4][68];

  {
    const int r = tid >> 3;
    const int q = tid & 7;
    *reinterpret_cast<uint4*>(&cs[r][q * 8]) =
        *reinterpret_cast<const uint4*>(
            bcbf + (size_t)(b * L_SEQ + c * CL + r) * 128 + 64 + q * 8);
    size_t rowb = (size_t)(b * L_SEQ + c * CL + r) * 256 + dq * 64 + q * 8;
    *reinterpret_cast<float4*>(&Ls[r][q * 8]) =
        *reinterpret_cast<const float4*>(&lamb[rowb]);
    *reinterpret_cast<float4*>(&Ls[r][q * 8 + 4]) =
        *reinterpret_cast<const float4*>(&lamb[rowb + 4]);
    #pragma unroll
    for (int nn = 0; nn < 2; ++nn) {
      const int n = (tid >> 3) + nn * 32;
      bf16x8 hv = *reinterpret_cast<const bf16x8*>(
          hin + ((size_t)(b * NC + c) * 64 + n) * 256 + dq * 64 + q * 8);
      #pragma unroll
      for (int k = 0; k < 8; ++k)
        HT[q * 8 + k][n] = (ushort_t)hv[k];
    }
  }
  __syncthreads();
  // ---- cumprod L (4-segment parallel scan) ----
  {
    const int d = tid & 63;
    const int seg = tid >> 6;
    float local = 1.f;
    #pragma unroll
    for (int k = 0; k < 8; ++k) {
      local *= Ls[seg * 8 + k][d];
      Ls[seg * 8 + k][d] = local;
    }
    segp[seg][d] = local;
  }
  __syncthreads();
  {
    const int d = tid & 63;
    const int seg = tid >> 6;
    float pre = 1.f;
    #pragma unroll
    for (int s = 0; s < 3; ++s)
      if (s < seg) pre *= segp[s][d];
    #pragma unroll
    for (int k = 0; k < 8; ++k) {
      const int t = seg * 8 + k;
      Ls[t][d] = Ls[t][d] * pre;
    }
  }
  __syncthreads();

  const int ti = w & 1;
  #pragma unroll
  for (int p = 0; p < 2; ++p) {
    const int dj = (w >> 1) + p * 2;
    f32x4 acc = (f32x4){0.f, 0.f, 0.f, 0.f};
    #pragma unroll
    for (int ks = 0; ks < 2; ++ks) {
      const int ko = ks * 32 + rg * 8;
      bf16x8 aC = *reinterpret_cast<const bf16x8*>(&cs[ti * 16 + row16][ko]);
      bf16x8 bH = *reinterpret_cast<const bf16x8*>(&HT[dj * 16 + row16][ko]);
      acc = __builtin_amdgcn_mfma_f32_16x16x32_bf16(aC, bH, acc, 0, 0, 0);
    }
    #pragma unroll
    for (int r = 0; r < 4; ++r) {
      const int t = ti * 16 + rg * 4 + r;
      const int dcol = dj * 16 + cl;
      size_t gi = (size_t)(b * L_SEQ + c * CL + t) * 256 + dq * 64 + dcol;
      float y = bf2f(ylocal[gi]) + Ls[t][dcol] * acc[r];
      float sk = bf2f(skipb[gi]);
      float g = 0.5f * sk * (1.f + erff(sk * 0.70710678118f));
      gbf[gi] = f2bf(g * y);
    }
  }
}

// ====== K6: out = g @ W_out^T, 64x64 tiles, XCD-swizzled ===================
__global__ __launch_bounds__(256) void mgemm64(
    const ushort_t* __restrict__ Ag, const ushort_t* __restrict__ Wg,
    float* __restrict__ C) {
  __shared__ __align__(16) ushort_t As[64][72];
  __shared__ __align__(16) ushort_t Ws[64][72];
  const int tid = threadIdx.x;
  const int lane = tid & 63;
  const int w = tid >> 6;
  const int wm = w >> 1;
  const int wn = w & 1;
  const int bid = blockIdx.x;
  const int bm = (bid & 63) * 64;
  const int bn = (bid >> 6) * 64;
  const int r0 = tid >> 3;
  const int c8 = (tid & 7) * 8;
  const int row16 = lane & 15;

  f32x4 acc[2][2];
  #pragma unroll
  for (int i = 0; i < 2; ++i)
    #pragma unroll
    for (int j = 0; j < 2; ++j)
      acc[i][j] = (f32x4){0.f, 0.f, 0.f, 0.f};

  for (int k0 = 0; k0 < 256; k0 += 64) {
    #pragma unroll
    for (int p = 0; p < 2; ++p) {
      int r = r0 + p * 32;
      *reinterpret_cast<uint4*>(&As[r][c8]) =
          *reinterpret_cast<const uint4*>(&Ag[(size_t)(bm + r) * 256 + k0 + c8]);
      *reinterpret_cast<uint4*>(&Ws[r][c8]) =
          *reinterpret_cast<const uint4*>(&Wg[(size_t)(bn + r) * 256 + k0 + c8]);
    }
    __syncthreads();
    #pragma unroll
    for (int ks = 0; ks < 2; ++ks) {
      const int ko = ks * 32 + (lane >> 4) * 8;
      bf16x8 af[2], bfr[2];
      #pragma unroll
      for (int i = 0; i < 2; ++i)
        af[i] = *reinterpret_cast<const bf16x8*>(&As[wm * 32 + i * 16 + row16][ko]);
      #pragma unroll
      for (int j = 0; j < 2; ++j)
        bfr[j] = *reinterpret_cast<const bf16x8*>(&Ws[wn * 32 + j * 16 + row16][ko]);
      #pragma unroll
      for (int i = 0; i < 2; ++i)
        #pragma unroll
        for (int j = 0; j < 2; ++j)
          acc[i][j] = __builtin_amdgcn_mfma_f32_16x16x32_bf16(af[i], bfr[j], acc[i][j], 0, 0, 0);
    }
    __syncthreads();
  }

  const int cl = lane & 15;
  const int rg = lane >> 4;
  #pragma unroll
  for (int j = 0; j < 2; ++j) {
    const int col = bn + wn * 32 + j * 16 + cl;
    #pragma unroll
    for (int i = 0; i < 2; ++i) {
      const int rbase = bm + wm * 32 + i * 16 + rg * 4;
      #pragma unroll
      for (int rr = 0; rr < 4; ++rr)
        C[(size_t)(rbase + rr) * 256 + col] = acc[i][j][rr];
    }
  }
}

extern "C" void kernel_launch(void* const* d_in, const int* in_sizes, int n_in,
                              void* d_out, int out_size, void* d_ws, size_t ws_size,
                              hipStream_t stream) {
  const float* x      = (const float*)d_in[0];
  const float* W_in   = (const float*)d_in[1];
  const float* conv_w = (const float*)d_in[2];
  const float* conv_b = (const float*)d_in[3];
  const float* W_bc   = (const float*)d_in[4];
  const float* b_bc   = (const float*)d_in[5];
  const float* W_lam  = (const float*)d_in[6];
  const float* b_lam  = (const float*)d_in[7];
  const float* A      = (const float*)d_in[8];
  const float* W_out  = (const float*)d_in[9];
  float* out = (float*)d_out;

  float* ws = (float*)d_ws;
  ushort_t* skipb  = (ushort_t*)(ws + 0);        // 1,048,576 sh
  ushort_t* praw   = (ushort_t*)(ws + 524288);   // 1,048,576 sh
  float*    lamb   = ws + 1048576;               // 1,048,576 f
  ushort_t* uwb    = (ushort_t*)(ws + 2097152);  // 1,048,576 sh
  ushort_t* bcbf   = (ushort_t*)(ws + 2621440);  //   524,288 sh
  ushort_t* ylocal = (ushort_t*)(ws + 2883584);  // 1,048,576 sh
  float*    Pc     = ws + 3407872;               //    32,768 f
  ushort_t* Hc     = (ushort_t*)(ws + 3440640);  // 2,097,152 sh
  ushort_t* wbcb   = (ushort_t*)(ws + 4489216);  //    32,768 sh
  ushort_t* wlb    = (ushort_t*)(ws + 4505600);  //    65,536 sh
  ushort_t* wob    = (ushort_t*)(ws + 4538368);  //    65,536 sh
  ushort_t* gbf    = (ushort_t*)(ws + 4571136);  // 1,048,576 sh
  // end: 5,095,424 floats ~ 20.4 MB

  // 1) proj = x @ W_in^T (inline cvt) + weight conversions  [672 blocks]
  projcvt64<<<dim3(672), dim3(256), 0, stream>>>(
      x, W_in, W_bc, W_lam, W_out, wbcb, wlb, wob, skipb, praw);
  // 2) conv (LDS) + fused bc|lambda GEMM (64-row panels)    [384 blocks]
  convbclam<<<dim3(384), dim3(256), 0, stream>>>(
      praw, conv_w, conv_b, wbcb, wlb, b_bc, b_lam, A, bcbf, lamb, uwb);
  // 3) chunk-local scan via MFMA                            [512 blocks]
  passA_mfma<<<dim3(B_DIM * NC * 4), dim3(256), 0, stream>>>(
      lamb, uwb, bcbf, Pc, Hc, ylocal);
  // 4) chunk-prefix scan                                    [256 blocks]
  chunkscan<<<dim3(256), dim3(128), 0, stream>>>(Pc, Hc);
  // 5) cross-chunk correction via MFMA + gelu gate          [512 blocks]
  passB_mfma<<<dim3(B_DIM * NC * 4), dim3(256), 0, stream>>>(
      lamb, bcbf, Hc, skipb, ylocal, gbf);
  // 6) out = g @ W_out^T                                    [256 blocks]
  mgemm64<<<dim3(256), dim3(256), 0, stream>>>(gbf, wob, out);
}

// Round 16
// 44.023 us; speedup vs baseline: 10.7750x; 1.0754x over previous
//
#include <hip/hip_runtime.h>
#include <hip/hip_bf16.h>
#include <math.h>

// Problem constants
#define B_DIM 2
#define L_SEQ 2048
#define D_DIM 256
#define N_DIM 64
#define K_CONV 4
#define M_ROWS (B_DIM * L_SEQ)   // 4096
#define NC 64                     // number of scan chunks
#define CL (L_SEQ / NC)           // 32 steps per chunk

typedef __attribute__((ext_vector_type(8))) short bf16x8;
typedef __attribute__((ext_vector_type(4))) float f32x4;
typedef unsigned short ushort_t;

static __device__ __forceinline__ unsigned short f2bf(float f) {
  unsigned int u = __float_as_uint(f);
  unsigned int r = u + 0x7FFF + ((u >> 16) & 1);   // round-to-nearest-even
  return (unsigned short)(r >> 16);
}
static __device__ __forceinline__ float bf2f(ushort_t s) {
  return __uint_as_float(((unsigned int)s) << 16);
}
static __device__ __forceinline__ unsigned int pack2(float a, float b) {
  return (unsigned int)f2bf(a) | ((unsigned int)f2bf(b) << 16);
}

// ====== K1: proj = x @ W_in^T (inline f32->bf16 staging) + weight cvt ======
// blocks 0..511: 64x64 GEMM tiles, XCD-swizzled (bm = bid&63 -> same-panel
// blocks share an XCD; row panel p lives on XCD p%8).
// blocks 512..671: convert W_bc/W_lam/W_out to bf16.
__global__ __launch_bounds__(256) void projcvt64(
    const float* __restrict__ x, const float* __restrict__ wi,
    const float* __restrict__ wbc, const float* __restrict__ wl,
    const float* __restrict__ wo,
    ushort_t* __restrict__ wbcb, ushort_t* __restrict__ wlb,
    ushort_t* __restrict__ wob,
    ushort_t* __restrict__ skipb, ushort_t* __restrict__ praw) {
  const int bid = blockIdx.x;
  const int tid = threadIdx.x;
  if (bid >= 512) {                 // ---- converter blocks ----
    int vb = bid - 512;
    const float* src; ushort_t* dst; int off;
    if (vb < 32)      { src = wbc; dst = wbcb; off = vb; }
    else if (vb < 96) { src = wl;  dst = wlb;  off = vb - 32; }
    else              { src = wo;  dst = wob;  off = vb - 96; }
    size_t i = (size_t)off * 1024 + tid * 4;
    float4 v = *reinterpret_cast<const float4*>(&src[i]);
    ushort4 o;
    o.x = f2bf(v.x); o.y = f2bf(v.y); o.z = f2bf(v.z); o.w = f2bf(v.w);
    *reinterpret_cast<ushort4*>(&dst[i]) = o;
    return;
  }
  // ---- GEMM block ----
  __shared__ __align__(16) ushort_t As[64][72];
  __shared__ __align__(16) ushort_t Ws[64][72];
  const int lane = tid & 63;
  const int w = tid >> 6;
  const int wm = w >> 1;
  const int wn = w & 1;
  const int bm = (bid & 63) * 64;
  const int bn = (bid >> 6) * 64;
  const int r0 = tid >> 3;          // 0..31
  const int c8 = (tid & 7) * 8;
  const int row16 = lane & 15;

  f32x4 acc[2][2];
  #pragma unroll
  for (int i = 0; i < 2; ++i)
    #pragma unroll
    for (int j = 0; j < 2; ++j)
      acc[i][j] = (f32x4){0.f, 0.f, 0.f, 0.f};

  for (int k0 = 0; k0 < 256; k0 += 64) {
    #pragma unroll
    for (int p = 0; p < 2; ++p) {
      int r = r0 + p * 32;
      const float* src = &x[(size_t)(bm + r) * 256 + k0 + c8];
      float4 v0 = *reinterpret_cast<const float4*>(src);
      float4 v1 = *reinterpret_cast<const float4*>(src + 4);
      uint4 o;
      o.x = pack2(v0.x, v0.y); o.y = pack2(v0.z, v0.w);
      o.z = pack2(v1.x, v1.y); o.w = pack2(v1.z, v1.w);
      *reinterpret_cast<uint4*>(&As[r][c8]) = o;
      const float* srcw = &wi[(size_t)(bn + r) * 256 + k0 + c8];
      float4 w0 = *reinterpret_cast<const float4*>(srcw);
      float4 w1 = *reinterpret_cast<const float4*>(srcw + 4);
      uint4 ow;
      ow.x = pack2(w0.x, w0.y); ow.y = pack2(w0.z, w0.w);
      ow.z = pack2(w1.x, w1.y); ow.w = pack2(w1.z, w1.w);
      *reinterpret_cast<uint4*>(&Ws[r][c8]) = ow;
    }
    __syncthreads();
    #pragma unroll
    for (int ks = 0; ks < 2; ++ks) {
      const int ko = ks * 32 + (lane >> 4) * 8;
      bf16x8 af[2], bfr[2];
      #pragma unroll
      for (int i = 0; i < 2; ++i)
        af[i] = *reinterpret_cast<const bf16x8*>(&As[wm * 32 + i * 16 + row16][ko]);
      #pragma unroll
      for (int j = 0; j < 2; ++j)
        bfr[j] = *reinterpret_cast<const bf16x8*>(&Ws[wn * 32 + j * 16 + row16][ko]);
      #pragma unroll
      for (int i = 0; i < 2; ++i)
        #pragma unroll
        for (int j = 0; j < 2; ++j)
          acc[i][j] = __builtin_amdgcn_mfma_f32_16x16x32_bf16(af[i], bfr[j], acc[i][j], 0, 0, 0);
    }
    __syncthreads();
  }

  const int cl = lane & 15;
  const int rg = lane >> 4;
  #pragma unroll
  for (int j = 0; j < 2; ++j) {
    const int col = bn + wn * 32 + j * 16 + cl;
    ushort_t* dst = (col < 256) ? skipb : praw;
    const int cc = col & 255;
    #pragma unroll
    for (int i = 0; i < 2; ++i) {
      const int rbase = bm + wm * 32 + i * 16 + rg * 4;
      #pragma unroll
      for (int rr = 0; rr < 4; ++rr)
        dst[(size_t)(rbase + rr) * 256 + cc] = f2bf(acc[i][j][rr]);
    }
  }
}

// ====== K2: depthwise conv (into LDS) + bc|lambda GEMM, 64-row panels ======
// bm = (bid&63)*64 -> row panel bid&63 stays on XCD (bid&63)%8 = producer's.
__global__ __launch_bounds__(256) void convbclam(
    const ushort_t* __restrict__ praw, const float* __restrict__ cw,
    const float* __restrict__ cb,
    const ushort_t* __restrict__ wbcb, const ushort_t* __restrict__ wlb,
    const float* __restrict__ b_bc, const float* __restrict__ b_lam,
    const float* __restrict__ Avec,
    ushort_t* __restrict__ bcbf, float* __restrict__ lamb,
    ushort_t* __restrict__ uwb) {
  __shared__ __align__(16) ushort_t Us[64][264];    // 33.8 KB
  __shared__ __align__(16) ushort_t Ws[64][72];     // 9.2 KB
  const int tid = threadIdx.x;
  const int lane = tid & 63;
  const int w = tid >> 6;
  const int wm = w >> 1;
  const int wn = w & 1;
  const int bid = blockIdx.x;
  const int bm = (bid & 63) * 64;
  const int bn = (bid >> 6) * 64;    // 0..5 tiles

  {
    const int d = tid;
    const float4 w4 = *reinterpret_cast<const float4*>(&cw[d * 4]);
    const float bias = cb[d];
    const bool edge = (bm & 2047) == 0;   // batch boundary
    float p0 = edge ? 0.f : bf2f(praw[(size_t)(bm - 3) * 256 + d]);
    float p1 = edge ? 0.f : bf2f(praw[(size_t)(bm - 2) * 256 + d]);
    float p2 = edge ? 0.f : bf2f(praw[(size_t)(bm - 1) * 256 + d]);
    #pragma unroll 8
    for (int r = 0; r < 64; ++r) {
      float p3 = bf2f(praw[(size_t)(bm + r) * 256 + d]);
      float u = bias + w4.x * p0 + w4.y * p1 + w4.z * p2 + w4.w * p3;
      Us[r][d] = f2bf(u);
      p0 = p1; p1 = p2; p2 = p3;
    }
  }
  __syncthreads();

  const ushort_t* Wsrc = (bn < 128) ? (wbcb + (size_t)bn * 256)
                                    : (wlb + (size_t)(bn - 128) * 256);
  const int r0 = tid >> 3;
  const int c8 = (tid & 7) * 8;
  const int row16 = lane & 15;

  f32x4 acc[2][2];
  #pragma unroll
  for (int i = 0; i < 2; ++i)
    #pragma unroll
    for (int j = 0; j < 2; ++j)
      acc[i][j] = (f32x4){0.f, 0.f, 0.f, 0.f};

  for (int k0 = 0; k0 < 256; k0 += 64) {
    #pragma unroll
    for (int p = 0; p < 2; ++p) {
      int r = r0 + p * 32;
      uint4 v = *reinterpret_cast<const uint4*>(&Wsrc[(size_t)r * 256 + k0 + c8]);
      *reinterpret_cast<uint4*>(&Ws[r][c8]) = v;
    }
    __syncthreads();
    #pragma unroll
    for (int ks = 0; ks < 2; ++ks) {
      const int ko = ks * 32 + (lane >> 4) * 8;
      bf16x8 af[2], bfr[2];
      #pragma unroll
      for (int i = 0; i < 2; ++i)
        af[i] = *reinterpret_cast<const bf16x8*>(&Us[wm * 32 + i * 16 + row16][k0 + ko]);
      #pragma unroll
      for (int j = 0; j < 2; ++j)
        bfr[j] = *reinterpret_cast<const bf16x8*>(&Ws[wn * 32 + j * 16 + row16][ko]);
      #pragma unroll
      for (int i = 0; i < 2; ++i)
        #pragma unroll
        for (int j = 0; j < 2; ++j)
          acc[i][j] = __builtin_amdgcn_mfma_f32_16x16x32_bf16(af[i], bfr[j], acc[i][j], 0, 0, 0);
    }
    __syncthreads();
  }

  const int cl = lane & 15;
  const int rg = lane >> 4;
  #pragma unroll
  for (int j = 0; j < 2; ++j) {
    const int col = bn + wn * 32 + j * 16 + cl;
    if (col < 128) {
      const float bv = b_bc[col];
      #pragma unroll
      for (int i = 0; i < 2; ++i) {
        const int rbase = bm + wm * 32 + i * 16 + rg * 4;
        #pragma unroll
        for (int rr = 0; rr < 4; ++rr)
          bcbf[(size_t)(rbase + rr) * 128 + col] = f2bf(acc[i][j][rr] + bv);
      }
    } else {
      const int dd = col - 128;
      const float bv = b_lam[dd];
      const float adg = -8.f * log1pf(__expf(Avec[dd]));
      #pragma unroll
      for (int i = 0; i < 2; ++i) {
        const int rbase = bm + wm * 32 + i * 16 + rg * 4;
        #pragma unroll
        for (int rr = 0; rr < 4; ++rr) {
          const int row = rbase + rr;
          float v = acc[i][j][rr] + bv;
          float s = 1.f / (1.f + __expf(-v));
          float lam = __expf(s * adg);
          float wq = sqrtf(1.f + 1e-6f - lam * lam);
          float u = bf2f(Us[row - bm][dd]);
          lamb[(size_t)row * 256 + dd] = lam;
          uwb[(size_t)row * 256 + dd] = f2bf(u * wq);
        }
      }
    }
  }
}

// ---- producer-aligned decode for the scan kernels -------------------------
// Chunk c occupies row panel c/2, produced on XCD (c/2)%8. Map blocks so
// chunk c runs on XCD (c/2)%8: xcd = bid&7, c = 2*(xcd + 8*pair) + parity.
static __device__ __forceinline__ void scan_decode(
    int bid, int& b, int& c, int& dq) {
  const int xcd = bid & 7;
  const int idx = bid >> 3;      // 0..63
  b = idx >> 5;                  // 0..1
  const int rem = idx & 31;      // 0..31
  c = 2 * (xcd + 8 * (rem & 3)) + ((rem >> 2) & 1);
  dq = (rem >> 3) & 3;
}

// ====== K3: chunk-local scan via MFMA (chunked linear attention) ===========
__global__ __launch_bounds__(256) void passA_mfma(
    const float* __restrict__ lamb, const ushort_t* __restrict__ uwb,
    const ushort_t* __restrict__ bcbf, float* __restrict__ Pc,
    ushort_t* __restrict__ Hc, ushort_t* __restrict__ ylocal) {
  int b, c, dq;
  scan_decode(blockIdx.x, b, c, dq);
  const int tid = threadIdx.x;
  const int lane = tid & 63;
  const int w = tid >> 6;
  const int row16 = lane & 15;
  const int cl = lane & 15;
  const int rg = lane >> 4;

  __shared__ __align__(16) ushort_t bcs[CL][136];  // [t][0..63]=b, [64..127]=c
  __shared__ __align__(16) float    Ls[CL][68];    // lam -> cumprod (in place)
  __shared__ __align__(16) ushort_t uws[CL][72];
  __shared__ __align__(16) ushort_t VT[64][40];    // V^T[d][tau]
  __shared__ __align__(16) ushort_t bT[64][40];    // b^T[n][tau]
  __shared__ __align__(16) ushort_t GL[CL][40];    // tril(G)[t][tau]
  __shared__ float segp[4][68];

  {
    const int r = tid >> 3;
    const int q = tid & 7;
    const ushort_t* src = bcbf + (size_t)(b * L_SEQ + c * CL + r) * 128;
    *reinterpret_cast<uint4*>(&bcs[r][q * 16]) =
        *reinterpret_cast<const uint4*>(src + q * 16);
    *reinterpret_cast<uint4*>(&bcs[r][q * 16 + 8]) =
        *reinterpret_cast<const uint4*>(src + q * 16 + 8);
    size_t rowb = (size_t)(b * L_SEQ + c * CL + r) * 256 + dq * 64 + q * 8;
    *reinterpret_cast<float4*>(&Ls[r][q * 8]) =
        *reinterpret_cast<const float4*>(&lamb[rowb]);
    *reinterpret_cast<float4*>(&Ls[r][q * 8 + 4]) =
        *reinterpret_cast<const float4*>(&lamb[rowb + 4]);
    *reinterpret_cast<uint4*>(&uws[r][q * 8]) =
        *reinterpret_cast<const uint4*>(uwb + rowb);
  }
  __syncthreads();

  // ---- G = C.B^T (4 tiles, 1/wave), mask tril, store bf16 ----
  {
    const int ti = w >> 1;
    const int tj = w & 1;
    f32x4 g = (f32x4){0.f, 0.f, 0.f, 0.f};
    #pragma unroll
    for (int ks = 0; ks < 2; ++ks) {
      const int ko = ks * 32 + rg * 8;
      bf16x8 aC = *reinterpret_cast<const bf16x8*>(&bcs[ti * 16 + row16][64 + ko]);
      bf16x8 bB = *reinterpret_cast<const bf16x8*>(&bcs[tj * 16 + row16][ko]);
      g = __builtin_amdgcn_mfma_f32_16x16x32_bf16(aC, bB, g, 0, 0, 0);
    }
    #pragma unroll
    for (int r = 0; r < 4; ++r) {
      const int t = ti * 16 + rg * 4 + r;
      const int tau = tj * 16 + cl;
      GL[t][tau] = (tau <= t) ? f2bf(g[r]) : (ushort_t)0;
    }
  }
  // ---- b^T build (all threads; reads bcs only) ----
  {
    #pragma unroll
    for (int k = 0; k < 8; ++k) {
      int el = tid * 8 + k;            // 0..2047
      int n = el >> 5;
      int tau = el & 31;
      bT[n][tau] = bcs[tau][n];
    }
  }
  // ---- cumprod L (4-segment parallel scan, all 256 threads) ----
  {
    const int d = tid & 63;
    const int seg = tid >> 6;
    float local = 1.f;
    #pragma unroll
    for (int k = 0; k < 8; ++k) {
      local *= Ls[seg * 8 + k][d];
      Ls[seg * 8 + k][d] = local;
    }
    segp[seg][d] = local;
  }
  __syncthreads();
  {
    const int d = tid & 63;
    const int seg = tid >> 6;
    float pre = 1.f;
    #pragma unroll
    for (int s = 0; s < 3; ++s)
      if (s < seg) pre *= segp[s][d];
    #pragma unroll
    for (int k = 0; k < 8; ++k) {
      const int t = seg * 8 + k;
      float L = Ls[t][d] * pre;
      Ls[t][d] = L;
      VT[d][t] = f2bf(bf2f(uws[t][d]) / L);
    }
  }
  __syncthreads();

  // ---- Y1 = tril(G).V, y_local = L .* Y1 (8 tiles, 2/wave) ----
  {
    const int ti = w & 1;
    #pragma unroll
    for (int p = 0; p < 2; ++p) {
      const int dj = (w >> 1) + p * 2;
      bf16x8 aG = *reinterpret_cast<const bf16x8*>(&GL[ti * 16 + row16][rg * 8]);
      bf16x8 bV = *reinterpret_cast<const bf16x8*>(&VT[dj * 16 + row16][rg * 8]);
      f32x4 y = __builtin_amdgcn_mfma_f32_16x16x32_bf16(aG, bV,
                  (f32x4){0.f, 0.f, 0.f, 0.f}, 0, 0, 0);
      #pragma unroll
      for (int r = 0; r < 4; ++r) {
        const int t = ti * 16 + rg * 4 + r;
        const int dcol = dj * 16 + cl;
        ylocal[(size_t)(b * L_SEQ + c * CL + t) * 256 + dq * 64 + dcol] =
            f2bf(Ls[t][dcol] * y[r]);
      }
    }
  }
  // ---- H_end = L_end .* (B^T.V) (16 tiles, 4/wave) ----
  {
    const int ni = w;
    bf16x8 aB = *reinterpret_cast<const bf16x8*>(&bT[ni * 16 + row16][rg * 8]);
    #pragma unroll
    for (int dj = 0; dj < 4; ++dj) {
      bf16x8 bV = *reinterpret_cast<const bf16x8*>(&VT[dj * 16 + row16][rg * 8]);
      f32x4 h = __builtin_amdgcn_mfma_f32_16x16x32_bf16(aB, bV,
                  (f32x4){0.f, 0.f, 0.f, 0.f}, 0, 0, 0);
      #pragma unroll
      for (int r = 0; r < 4; ++r) {
        const int n = ni * 16 + rg * 4 + r;
        const int dcol = dj * 16 + cl;
        Hc[((size_t)(b * NC + c) * 64 + n) * 256 + dq * 64 + dcol] =
            f2bf(Ls[CL - 1][dcol] * h[r]);
      }
    }
  }
  if (tid < 64)
    Pc[(size_t)(b * NC + c) * 256 + dq * 64 + tid] = Ls[CL - 1][tid];
}

// ---- K4: sequential chunk scan over NC=64, pipelined unroll-16 ------------
__global__ __launch_bounds__(128) void chunkscan(
    const float* __restrict__ Pc, ushort_t* __restrict__ Hc) {
  int tid = blockIdx.x * 128 + threadIdx.x;   // 32768 = B*N*D
  int d = tid & 255;
  int j = (tid >> 8) & 63;
  int b = tid >> 14;
  const size_t hstride = (size_t)N_DIM * 256;
  const size_t ihb = ((size_t)(b * NC) * 64 + j) * 256 + d;
  const size_t ipb = (size_t)(b * NC) * 256 + d;
  float h = 0.f;
  float Hv[16], Pv[16];
  #pragma unroll
  for (int q = 0; q < 16; ++q) {
    Hv[q] = bf2f(Hc[ihb + (size_t)q * hstride]);
    Pv[q] = Pc[ipb + (size_t)q * 256];
  }
  #pragma unroll 1
  for (int c0 = 0; c0 < NC; c0 += 16) {
    float Hn[16], Pn[16];
    if (c0 + 16 < NC) {
      #pragma unroll
      for (int q = 0; q < 16; ++q) {
        Hn[q] = bf2f(Hc[ihb + (size_t)(c0 + 16 + q) * hstride]);
        Pn[q] = Pc[ipb + (size_t)(c0 + 16 + q) * 256];
      }
    }
    #pragma unroll
    for (int q = 0; q < 16; ++q) {
      Hc[ihb + (size_t)(c0 + q) * hstride] = f2bf(h);
      h = fmaf(Pv[q], h, Hv[q]);
    }
    #pragma unroll
    for (int q = 0; q < 16; ++q) { Hv[q] = Hn[q]; Pv[q] = Pn[q]; }
  }
}

// ====== K5: cross-chunk correction via MFMA + GELU gate ====================
__global__ __launch_bounds__(256) void passB_mfma(
    const float* __restrict__ lamb, const ushort_t* __restrict__ bcbf,
    const ushort_t* __restrict__ hin, const ushort_t* __restrict__ skipb,
    const ushort_t* __restrict__ ylocal, ushort_t* __restrict__ gbf) {
  int b, c, dq;
  scan_decode(blockIdx.x, b, c, dq);
  const int tid = threadIdx.x;
  const int lane = tid & 63;
  const int w = tid >> 6;
  const int row16 = lane & 15;
  const int cl = lane & 15;
  const int rg = lane >> 4;

  __shared__ __align__(16) ushort_t cs[CL][72];   // c[t][n]
  __shared__ __align__(16) float    Ls[CL][68];   // lam -> cumprod
  __shared__ __align__(16) ushort_t HT[64][72];   // Hin^T[d][n]
  __shared__ float segp[4][68];

  {
    const int r = tid >> 3;
    const int q = tid & 7;
    *reinterpret_cast<uint4*>(&cs[r][q * 8]) =
        *reinterpret_cast<const uint4*>(
            bcbf + (size_t)(b * L_SEQ + c * CL + r) * 128 + 64 + q * 8);
    size_t rowb = (size_t)(b * L_SEQ + c * CL + r) * 256 + dq * 64 + q * 8;
    *reinterpret_cast<float4*>(&Ls[r][q * 8]) =
        *reinterpret_cast<const float4*>(&lamb[rowb]);
    *reinterpret_cast<float4*>(&Ls[r][q * 8 + 4]) =
        *reinterpret_cast<const float4*>(&lamb[rowb + 4]);
    #pragma unroll
    for (int nn = 0; nn < 2; ++nn) {
      const int n = (tid >> 3) + nn * 32;
      bf16x8 hv = *reinterpret_cast<const bf16x8*>(
          hin + ((size_t)(b * NC + c) * 64 + n) * 256 + dq * 64 + q * 8);
      #pragma unroll
      for (int k = 0; k < 8; ++k)
        HT[q * 8 + k][n] = (ushort_t)hv[k];
    }
  }
  __syncthreads();
  // ---- cumprod L (4-segment parallel scan) ----
  {
    const int d = tid & 63;
    const int seg = tid >> 6;
    float local = 1.f;
    #pragma unroll
    for (int k = 0; k < 8; ++k) {
      local *= Ls[seg * 8 + k][d];
      Ls[seg * 8 + k][d] = local;
    }
    segp[seg][d] = local;
  }
  __syncthreads();
  {
    const int d = tid & 63;
    const int seg = tid >> 6;
    float pre = 1.f;
    #pragma unroll
    for (int s = 0; s < 3; ++s)
      if (s < seg) pre *= segp[s][d];
    #pragma unroll
    for (int k = 0; k < 8; ++k) {
      const int t = seg * 8 + k;
      Ls[t][d] = Ls[t][d] * pre;
    }
  }
  __syncthreads();

  const int ti = w & 1;
  #pragma unroll
  for (int p = 0; p < 2; ++p) {
    const int dj = (w >> 1) + p * 2;
    f32x4 acc = (f32x4){0.f, 0.f, 0.f, 0.f};
    #pragma unroll
    for (int ks = 0; ks < 2; ++ks) {
      const int ko = ks * 32 + rg * 8;
      bf16x8 aC = *reinterpret_cast<const bf16x8*>(&cs[ti * 16 + row16][ko]);
      bf16x8 bH = *reinterpret_cast<const bf16x8*>(&HT[dj * 16 + row16][ko]);
      acc = __builtin_amdgcn_mfma_f32_16x16x32_bf16(aC, bH, acc, 0, 0, 0);
    }
    #pragma unroll
    for (int r = 0; r < 4; ++r) {
      const int t = ti * 16 + rg * 4 + r;
      const int dcol = dj * 16 + cl;
      size_t gi = (size_t)(b * L_SEQ + c * CL + t) * 256 + dq * 64 + dcol;
      float y = bf2f(ylocal[gi]) + Ls[t][dcol] * acc[r];
      float sk = bf2f(skipb[gi]);
      float g = 0.5f * sk * (1.f + erff(sk * 0.70710678118f));
      gbf[gi] = f2bf(g * y);
    }
  }
}

// ====== K6: out = g @ W_out^T, 64x64 tiles, XCD-swizzled ===================
__global__ __launch_bounds__(256) void mgemm64(
    const ushort_t* __restrict__ Ag, const ushort_t* __restrict__ Wg,
    float* __restrict__ C) {
  __shared__ __align__(16) ushort_t As[64][72];
  __shared__ __align__(16) ushort_t Ws[64][72];
  const int tid = threadIdx.x;
  const int lane = tid & 63;
  const int w = tid >> 6;
  const int wm = w >> 1;
  const int wn = w & 1;
  const int bid = blockIdx.x;
  const int bm = (bid & 63) * 64;
  const int bn = (bid >> 6) * 64;
  const int r0 = tid >> 3;
  const int c8 = (tid & 7) * 8;
  const int row16 = lane & 15;

  f32x4 acc[2][2];
  #pragma unroll
  for (int i = 0; i < 2; ++i)
    #pragma unroll
    for (int j = 0; j < 2; ++j)
      acc[i][j] = (f32x4){0.f, 0.f, 0.f, 0.f};

  for (int k0 = 0; k0 < 256; k0 += 64) {
    #pragma unroll
    for (int p = 0; p < 2; ++p) {
      int r = r0 + p * 32;
      *reinterpret_cast<uint4*>(&As[r][c8]) =
          *reinterpret_cast<const uint4*>(&Ag[(size_t)(bm + r) * 256 + k0 + c8]);
      *reinterpret_cast<uint4*>(&Ws[r][c8]) =
          *reinterpret_cast<const uint4*>(&Wg[(size_t)(bn + r) * 256 + k0 + c8]);
    }
    __syncthreads();
    #pragma unroll
    for (int ks = 0; ks < 2; ++ks) {
      const int ko = ks * 32 + (lane >> 4) * 8;
      bf16x8 af[2], bfr[2];
      #pragma unroll
      for (int i = 0; i < 2; ++i)
        af[i] = *reinterpret_cast<const bf16x8*>(&As[wm * 32 + i * 16 + row16][ko]);
      #pragma unroll
      for (int j = 0; j < 2; ++j)
        bfr[j] = *reinterpret_cast<const bf16x8*>(&Ws[wn * 32 + j * 16 + row16][ko]);
      #pragma unroll
      for (int i = 0; i < 2; ++i)
        #pragma unroll
        for (int j = 0; j < 2; ++j)
          acc[i][j] = __builtin_amdgcn_mfma_f32_16x16x32_bf16(af[i], bfr[j], acc[i][j], 0, 0, 0);
    }
    __syncthreads();
  }

  const int cl = lane & 15;
  const int rg = lane >> 4;
  #pragma unroll
  for (int j = 0; j < 2; ++j) {
    const int col = bn + wn * 32 + j * 16 + cl;
    #pragma unroll
    for (int i = 0; i < 2; ++i) {
      const int rbase = bm + wm * 32 + i * 16 + rg * 4;
      #pragma unroll
      for (int rr = 0; rr < 4; ++rr)
        C[(size_t)(rbase + rr) * 256 + col] = acc[i][j][rr];
    }
  }
}

extern "C" void kernel_launch(void* const* d_in, const int* in_sizes, int n_in,
                              void* d_out, int out_size, void* d_ws, size_t ws_size,
                              hipStream_t stream) {
  const float* x      = (const float*)d_in[0];
  const float* W_in   = (const float*)d_in[1];
  const float* conv_w = (const float*)d_in[2];
  const float* conv_b = (const float*)d_in[3];
  const float* W_bc   = (const float*)d_in[4];
  const float* b_bc   = (const float*)d_in[5];
  const float* W_lam  = (const float*)d_in[6];
  const float* b_lam  = (const float*)d_in[7];
  const float* A      = (const float*)d_in[8];
  const float* W_out  = (const float*)d_in[9];
  float* out = (float*)d_out;

  float* ws = (float*)d_ws;
  ushort_t* skipb  = (ushort_t*)(ws + 0);        // 1,048,576 sh
  ushort_t* praw   = (ushort_t*)(ws + 524288);   // 1,048,576 sh
  float*    lamb   = ws + 1048576;               // 1,048,576 f
  ushort_t* uwb    = (ushort_t*)(ws + 2097152);  // 1,048,576 sh
  ushort_t* bcbf   = (ushort_t*)(ws + 2621440);  //   524,288 sh
  ushort_t* ylocal = (ushort_t*)(ws + 2883584);  // 1,048,576 sh
  float*    Pc     = ws + 3407872;               //    32,768 f
  ushort_t* Hc     = (ushort_t*)(ws + 3440640);  // 2,097,152 sh
  ushort_t* wbcb   = (ushort_t*)(ws + 4489216);  //    32,768 sh
  ushort_t* wlb    = (ushort_t*)(ws + 4505600);  //    65,536 sh
  ushort_t* wob    = (ushort_t*)(ws + 4538368);  //    65,536 sh
  ushort_t* gbf    = (ushort_t*)(ws + 4571136);  // 1,048,576 sh
  // end: 5,095,424 floats ~ 20.4 MB

  // 1) proj = x @ W_in^T (inline cvt) + weight conversions  [672 blocks]
  projcvt64<<<dim3(672), dim3(256), 0, stream>>>(
      x, W_in, W_bc, W_lam, W_out, wbcb, wlb, wob, skipb, praw);
  // 2) conv (LDS) + fused bc|lambda GEMM (64-row panels)    [384 blocks]
  convbclam<<<dim3(384), dim3(256), 0, stream>>>(
      praw, conv_w, conv_b, wbcb, wlb, b_bc, b_lam, A, bcbf, lamb, uwb);
  // 3) chunk-local scan via MFMA (producer-aligned XCD map) [512 blocks]
  passA_mfma<<<dim3(B_DIM * NC * 4), dim3(256), 0, stream>>>(
      lamb, uwb, bcbf, Pc, Hc, ylocal);
  // 4) chunk-prefix scan                                    [256 blocks]
  chunkscan<<<dim3(256), dim3(128), 0, stream>>>(Pc, Hc);
  // 5) cross-chunk correction + gelu (producer-aligned)     [512 blocks]
  passB_mfma<<<dim3(B_DIM * NC * 4), dim3(256), 0, stream>>>(
      lamb, bcbf, Hc, skipb, ylocal, gbf);
  // 6) out = g @ W_out^T                                    [256 blocks]
  mgemm64<<<dim3(256), dim3(256), 0, stream>>>(gbf, wob, out);
}